// Round 13
// baseline (456.582 us; speedup 1.0000x reference)
//
#include <hip/hip_runtime.h>
#include <math.h>

namespace {

constexpr int NSMP = 131072;   // n_samples
constexpr int NEV  = 128;      // B*E events
constexpr int NPAIR = NEV/2;   // packed complex pipelines
constexpr int MFT  = 262144;   // 2*NS FFT size = 512*512
constexpr int COLS = 8;        // cols per pass A/C block
constexpr int ROWS = 8;        // rows per pass B block
constexpr int RST  = 576;      // padded row stride (pass B): pidx(511)=574 < 576
constexpr int CST  = 578;      // padded col stride (pass A/C)

typedef __attribute__((ext_vector_type(8))) short short8;
typedef __attribute__((ext_vector_type(4))) float f32x4;

__device__ __forceinline__ float2 cadd(float2 a, float2 b){ return make_float2(a.x+b.x, a.y+b.y); }
__device__ __forceinline__ float2 csub(float2 a, float2 b){ return make_float2(a.x-b.x, a.y-b.y); }
__device__ __forceinline__ float2 cmul(float2 a, float2 b){ return make_float2(a.x*b.x - a.y*b.y, a.x*b.y + a.y*b.x); }
__device__ __forceinline__ float2 cmulc(float2 a, float2 b){ return make_float2(a.x*b.x + a.y*b.y, a.y*b.x - a.x*b.y); }
__device__ __forceinline__ int rev3(int x){ return ((x&7)<<6) | (x&56) | (x>>6); }  // base-8 digit reversal, 9 bits
// bank-conflict-breaking pad: one extra float2 per 8 (stage3 32-way -> 4-way)
__device__ __forceinline__ int pidx(int i){ return i + (i>>3); }

// computed big twiddle: W_MFT^idx = (cos, sin) of -2*pi*idx/MFT — replaces the
// uncoalesced wbig gather (64 distinct cache lines per wave) with 2 trans ops.
__device__ __forceinline__ float2 wtw(int idx) {
  float ang = (float)idx * (-6.283185307179586f / (float)MFT);
  float sn, cs;
  __sincosf(ang, &sn, &cs);
  return make_float2(cs, sn);
}

// round-to-nearest-even f32 -> bf16 (values here are always finite)
__device__ __forceinline__ unsigned short f2bf(float x) {
  unsigned u = __float_as_uint(x);
  unsigned r = (u + 0x7FFFu + ((u >> 16) & 1u)) >> 16;
  return (unsigned short)r;
}
__device__ __forceinline__ float bf2f(unsigned short h) {
  return __uint_as_float(((unsigned)h) << 16);
}

// 8-point DFT: out[k] = sum_j in[j] * exp(SGN*2*pi*i*j*k/8)
template<int SGN>
__device__ __forceinline__ void fft8v(float2* u) {
  const float S2 = 0.70710678118654752440f;
  float2 a0 = cadd(u[0], u[4]), a1 = csub(u[0], u[4]);
  float2 a2 = cadd(u[2], u[6]), a3 = csub(u[2], u[6]);
  float2 b0 = cadd(u[1], u[5]), b1 = csub(u[1], u[5]);
  float2 b2 = cadd(u[3], u[7]), b3 = csub(u[3], u[7]);
  float2 a3r = (SGN < 0) ? make_float2(a3.y, -a3.x) : make_float2(-a3.y, a3.x);
  float2 b3r = (SGN < 0) ? make_float2(b3.y, -b3.x) : make_float2(-b3.y, b3.x);
  float2 E0 = cadd(a0, a2), E2 = csub(a0, a2);
  float2 E1 = cadd(a1, a3r), E3 = csub(a1, a3r);
  float2 O0 = cadd(b0, b2), O2 = csub(b0, b2);
  float2 O1 = cadd(b1, b3r), O3 = csub(b1, b3r);
  const float sg = (SGN < 0) ? -1.f : 1.f;
  O1 = cmul(O1, make_float2(S2, sg*S2));
  O2 = (SGN < 0) ? make_float2(O2.y, -O2.x) : make_float2(-O2.y, O2.x);
  O3 = cmul(O3, make_float2(-S2, sg*S2));
  u[0] = cadd(E0, O0); u[4] = csub(E0, O0);
  u[1] = cadd(E1, O1); u[5] = csub(E1, O1);
  u[2] = cadd(E2, O2); u[6] = csub(E2, O2);
  u[3] = cadd(E3, O3); u[7] = csub(E3, O3);
}

// Stages 2+3 of the forward 512-pt DIF (shared by full and zero-padded heads).
__device__ __forceinline__ void fft512_fwd_tail(float2* X, int lane, const float2* w512) {
  float2 u[8];
  {
    int b = (lane>>3)<<6, m = lane&7;
    #pragma unroll
    for (int j = 0; j < 8; ++j) u[j] = X[pidx(b + (j<<3) + m)];
    fft8v<-1>(u);
    #pragma unroll
    for (int r = 1; r < 8; ++r) u[r] = cmul(u[r], w512[((m*r)<<3) & 511]);
    #pragma unroll
    for (int r = 0; r < 8; ++r) X[pidx(b + (r<<3) + m)] = u[r];
  }
  {
    int c = lane<<3;
    #pragma unroll
    for (int j = 0; j < 8; ++j) u[j] = X[pidx(c + j)];
    fft8v<-1>(u);
    #pragma unroll
    for (int r = 0; r < 8; ++r) X[pidx(c + r)] = u[r];
  }
}

// In-place 512-pt forward DIF (natural in -> base-8 digit-reversed out).
// X points at a contiguous padded transform: element i lives at X[pidx(i)].
// One wave (lane 0..63) per transform. The transform's LDS region is
// WAVE-PRIVATE: same-wave LDS ops are processed in order (lgkmcnt), so NO
// barriers are needed inside — callers barrier only at cross-wave phases.
__device__ void fft512_fwd(float2* X, int lane, const float2* w512) {
  float2 u[8];
  #pragma unroll
  for (int j = 0; j < 8; ++j) u[j] = X[pidx((j<<6) + lane)];
  fft8v<-1>(u);
  #pragma unroll
  for (int r = 1; r < 8; ++r) u[r] = cmul(u[r], w512[(lane*r) & 511]);
  #pragma unroll
  for (int r = 0; r < 8; ++r) X[pidx((r<<6) + lane)] = u[r];
  fft512_fwd_tail(X, lane, w512);
}

// Zero-padded variant: elements 256..511 are known zero (never read — callers
// stage only the lower half). Stage-1 butterfly specialized for u[4..7] == 0.
__device__ void fft512_fwd_zpad(float2* X, int lane, const float2* w512) {
  const float S2 = 0.70710678118654752440f;
  float2 u[8];
  #pragma unroll
  for (int j = 0; j < 4; ++j) u[j] = X[pidx((j<<6) + lane)];
  {
    float2 a0 = u[0], a1 = u[0], a2 = u[2], a3 = u[2];
    float2 b0 = u[1], b1 = u[1], b2 = u[3], b3 = u[3];
    float2 a3r = make_float2(a3.y, -a3.x);
    float2 b3r = make_float2(b3.y, -b3.x);
    float2 E0 = cadd(a0, a2), E2 = csub(a0, a2);
    float2 E1 = cadd(a1, a3r), E3 = csub(a1, a3r);
    float2 O0 = cadd(b0, b2), O2 = csub(b0, b2);
    float2 O1 = cadd(b1, b3r), O3 = csub(b1, b3r);
    O1 = cmul(O1, make_float2(S2, -S2));
    O2 = make_float2(O2.y, -O2.x);
    O3 = cmul(O3, make_float2(-S2, -S2));
    u[0] = cadd(E0, O0); u[4] = csub(E0, O0);
    u[1] = cadd(E1, O1); u[5] = csub(E1, O1);
    u[2] = cadd(E2, O2); u[6] = csub(E2, O2);
    u[3] = cadd(E3, O3); u[7] = csub(E3, O3);
  }
  #pragma unroll
  for (int r = 1; r < 8; ++r) u[r] = cmul(u[r], w512[(lane*r) & 511]);
  #pragma unroll
  for (int r = 0; r < 8; ++r) X[pidx((r<<6) + lane)] = u[r];
  fft512_fwd_tail(X, lane, w512);
}

// Stages 1+2 of the inverse (shared by full and truncated-output variants).
__device__ __forceinline__ void fft512_inv_head(float2* X, int lane, const float2* w512) {
  float2 u[8];
  {
    int c = lane<<3;
    #pragma unroll
    for (int r = 0; r < 8; ++r) u[r] = X[pidx(c + r)];
    fft8v<1>(u);
    #pragma unroll
    for (int j = 0; j < 8; ++j) X[pidx(c + j)] = u[j];
  }
  {
    int b = (lane>>3)<<6, m = lane&7;
    #pragma unroll
    for (int r = 0; r < 8; ++r) u[r] = X[pidx(b + (r<<3) + m)];
    #pragma unroll
    for (int r = 1; r < 8; ++r) u[r] = cmulc(u[r], w512[((m*r)<<3) & 511]);
    fft8v<1>(u);
    #pragma unroll
    for (int j = 0; j < 8; ++j) X[pidx(b + (j<<3) + m)] = u[j];
  }
}

// In-place 512-pt inverse (transpose-conjugate of fwd): digit-reversed in -> natural out.
// Unnormalized. Barrier-free (wave-private region), as above.
__device__ void fft512_inv(float2* X, int lane, const float2* w512) {
  fft512_inv_head(X, lane, w512);
  float2 u[8];
  #pragma unroll
  for (int r = 0; r < 8; ++r) u[r] = X[pidx((r<<6) + lane)];
  #pragma unroll
  for (int r = 1; r < 8; ++r) u[r] = cmulc(u[r], w512[(lane*r) & 511]);
  fft8v<1>(u);
  #pragma unroll
  for (int j = 0; j < 8; ++j) X[pidx((j<<6) + lane)] = u[j];
}

// Truncated-output variant: only natural outputs 0..255 are consumed (pass C
// keeps n2 < 256); skip the upper-half final stores.
__device__ void fft512_inv_trunc(float2* X, int lane, const float2* w512) {
  fft512_inv_head(X, lane, w512);
  float2 u[8];
  #pragma unroll
  for (int r = 0; r < 8; ++r) u[r] = X[pidx((r<<6) + lane)];
  #pragma unroll
  for (int r = 1; r < 8; ++r) u[r] = cmulc(u[r], w512[(lane*r) & 511]);
  fft8v<1>(u);
  #pragma unroll
  for (int j = 0; j < 4; ++j) X[pidx((j<<6) + lane)] = u[j];
}

// -------- per-event scalar params (argmaxes, softmax mix, |amp|) --------
__global__ void k_params(const float* __restrict__ voice, const float* __restrict__ cpc,
                         const float* __restrict__ amps, const float* __restrict__ room,
                         const float* __restrict__ rmix, const float* __restrict__ times,
                         int* __restrict__ vidx, int* __restrict__ cpidx, int* __restrict__ ridx,
                         int* __restrict__ shiftA, float* __restrict__ m0, float* __restrict__ m1,
                         float* __restrict__ amp) {
  int n = blockIdx.x, t = threadIdx.x;
  if (t == 0) {
    const float* p = voice + n*8; int bi = 0; float bv = p[0];
    for (int i = 1; i < 8; ++i) if (p[i] > bv) { bv = p[i]; bi = i; }
    vidx[n] = bi;
  } else if (t == 1) {
    const float* p = cpc + n*512; int bi = 0; float bv = p[0];
    for (int i = 1; i < 512; ++i) if (p[i] > bv) { bv = p[i]; bi = i; }
    cpidx[n] = bi;
  } else if (t == 2) {
    const float* p = room + n*16; int bi = 0; float bv = p[0];
    for (int i = 1; i < 16; ++i) if (p[i] > bv) { bv = p[i]; bi = i; }
    ridx[n] = bi;
  } else if (t == 3) {
    const float* p = times + n*128; int bi = 0; float bv = p[0];
    for (int i = 1; i < 128; ++i) if (p[i] > bv) { bv = p[i]; bi = i; }
    shiftA[n] = bi * 1024;
  } else if (t == 4) {
    float a = rmix[n*2], b = rmix[n*2+1];
    float mx = fmaxf(a, b);
    float ea = __expf(a - mx), eb = __expf(b - mx);
    float inv = 1.f / (ea + eb);
    m0[n] = ea * inv; m1[n] = eb * inv;
    amp[n] = fabsf(amps[n]);
  }
}

// -------- compact 512-pt twiddle table: w512g[i] = exp(-2 pi i/512 * i) --------
// (identical double-precision math to the old wbig[i*512] entries)
__global__ void k_w512(float2* __restrict__ w512g) {
  int i = blockIdx.x * blockDim.x + threadIdx.x;
  if (i < 512) {
    double a = -2.0 * 3.14159265358979323846 * (double)(i * 512) / (double)MFT;
    w512g[i] = make_float2((float)cos(a), (float)sin(a));
  }
}

// -------- M[v] = w_ih[v] @ w_in[v]  -> [8][128][16] --------
__global__ void k_mred(const float* __restrict__ w_ih, const float* __restrict__ w_in,
                       float* __restrict__ mred) {
  int h = blockIdx.x, v = blockIdx.y, t = threadIdx.x;
  const float* ih = w_ih + ((size_t)v*128 + h)*1024;
  const float* wi = w_in + (size_t)v*1024*16;
  float acc[16];
  #pragma unroll
  for (int c = 0; c < 16; ++c) acc[c] = 0.f;
  for (int w = t; w < 1024; w += 64) {
    float a = ih[w];
    const float4* wr = (const float4*)(wi + (size_t)w*16);
    float4 q0 = wr[0], q1 = wr[1], q2 = wr[2], q3 = wr[3];
    acc[0] += a*q0.x; acc[1] += a*q0.y; acc[2] += a*q0.z; acc[3] += a*q0.w;
    acc[4] += a*q1.x; acc[5] += a*q1.y; acc[6] += a*q1.z; acc[7] += a*q1.w;
    acc[8] += a*q2.x; acc[9] += a*q2.y; acc[10]+= a*q2.z; acc[11]+= a*q2.w;
    acc[12]+= a*q3.x; acc[13]+= a*q3.y; acc[14]+= a*q3.z; acc[15]+= a*q3.w;
  }
  #pragma unroll
  for (int c = 0; c < 16; ++c) {
    float s = acc[c];
    for (int o = 32; o > 0; o >>= 1) s += __shfl_down(s, o);
    if (t == 0) mred[((size_t)v*128 + h)*16 + c] = s;
  }
}

// -------- exact top-128 of selected cp_table row (2048 vals), relu, ties by lowest index --------
__global__ __launch_bounds__(256) void k_topk(const float* __restrict__ cp_table,
                                              const int* __restrict__ cpidx,
                                              float* __restrict__ ctrl) {
  __shared__ int redw[4];
  __shared__ int scanbuf[256];
  int n = blockIdx.x, t = threadIdx.x;
  const float* row = cp_table + (size_t)cpidx[n]*2048;
  float f[8]; unsigned v[8];
  #pragma unroll
  for (int i = 0; i < 8; ++i) { f[i] = row[t*8 + i]; v[i] = __float_as_uint(f[i]); }
  int lane = t & 63, wid = t >> 6;
  unsigned thr = 0;
  for (int b = 31; b >= 0; --b) {  // values are >=0, bit pattern is order-preserving
    unsigned cand = thr | (1u << b);
    int c = 0;
    #pragma unroll
    for (int i = 0; i < 8; ++i) c += (v[i] >= cand);
    for (int o = 32; o > 0; o >>= 1) c += __shfl_down(c, o);
    if (lane == 0) redw[wid] = c;
    __syncthreads();
    int tot = redw[0] + redw[1] + redw[2] + redw[3];
    if (tot >= 128) thr = cand;
    __syncthreads();
  }
  int g = 0, eq = 0;
  #pragma unroll
  for (int i = 0; i < 8; ++i) { g += (v[i] > thr); eq += (v[i] == thr); }
  int gw = g;
  for (int o = 32; o > 0; o >>= 1) gw += __shfl_down(gw, o);
  if (lane == 0) redw[wid] = gw;
  scanbuf[t] = eq;
  __syncthreads();
  int G = redw[0] + redw[1] + redw[2] + redw[3];
  int extra = 128 - G;
  int incl = eq;
  for (int o = 1; o < 256; o <<= 1) {
    int add = (t >= o) ? scanbuf[t - o] : 0;
    __syncthreads();
    incl += add;
    scanbuf[t] = incl;
    __syncthreads();
  }
  int rank = incl - eq;
  float* outp = ctrl + (size_t)n*2048;
  #pragma unroll
  for (int i = 0; i < 8; ++i) {
    bool keep = (v[i] > thr) || ((v[i] == thr) && (rank < extra));
    if (v[i] == thr) rank++;
    outp[t*8 + i] = keep ? fmaxf(f[i], 0.f) : 0.f;
  }
}

// -------- 128-step tanh RNN, one block per event --------
// 512 threads: thread (i = t>>2, s = t&3) owns Whh[i][32s:32s+32] in VGPRs.
// Global hs stores are register-buffered over 8 steps so the per-barrier
// s_waitcnt vmcnt(0) drain is paid once per 8 steps, not every step.
__global__ __launch_bounds__(512) void k_rnn(const float* __restrict__ ctrl,
                                             const float* __restrict__ mred,
                                             const float* __restrict__ w_hh,
                                             const int* __restrict__ vidx,
                                             unsigned short* __restrict__ hs_hi,
                                             unsigned short* __restrict__ hs_lo) {
  __shared__ __align__(16) float h_s[2][128];
  __shared__ float ctrl_s[2048];
  __shared__ float cin_s[128*128];   // cin[st][i] = sum_c M[i][c]*ctrl[c][st]
  int n = blockIdx.x, t = threadIdx.x;
  int i = t >> 2, s = t & 3;
  int v = vidx[n];

  // Whh quarter into VGPRs
  const float4* whhrow = (const float4*)(w_hh + ((size_t)v*128 + i)*128 + 32*s);
  float4 whh[8];
  #pragma unroll
  for (int j = 0; j < 8; ++j) whh[j] = whhrow[j];

  for (int k = t; k < 2048; k += 512) ctrl_s[k] = ctrl[(size_t)n*2048 + k];
  if (s == 0) { h_s[0][i] = 0.f; }
  __syncthreads();

  // precompute cin[st][i] for all steps (parallel, off the critical path)
  {
    int ii = t & 127, stq = t >> 7;   // thread -> output ii, step-quarter stq
    const float4* mrow = (const float4*)(mred + ((size_t)v*128 + ii)*16);
    float4 m0q = mrow[0], m1q = mrow[1], m2q = mrow[2], m3q = mrow[3];
    #pragma unroll 4
    for (int st0 = 0; st0 < 32; ++st0) {
      int st = stq*32 + st0;
      float a = 0.f, b = 0.f;
      a += m0q.x*ctrl_s[(0<<7)+st];  b += m0q.y*ctrl_s[(1<<7)+st];
      a += m0q.z*ctrl_s[(2<<7)+st];  b += m0q.w*ctrl_s[(3<<7)+st];
      a += m1q.x*ctrl_s[(4<<7)+st];  b += m1q.y*ctrl_s[(5<<7)+st];
      a += m1q.z*ctrl_s[(6<<7)+st];  b += m1q.w*ctrl_s[(7<<7)+st];
      a += m2q.x*ctrl_s[(8<<7)+st];  b += m2q.y*ctrl_s[(9<<7)+st];
      a += m2q.z*ctrl_s[(10<<7)+st]; b += m2q.w*ctrl_s[(11<<7)+st];
      a += m3q.x*ctrl_s[(12<<7)+st]; b += m3q.y*ctrl_s[(13<<7)+st];
      a += m3q.z*ctrl_s[(14<<7)+st]; b += m3q.w*ctrl_s[(15<<7)+st];
      cin_s[(st<<7) + ii] = a + b;
    }
  }
  __syncthreads();

  unsigned short* hi_out = hs_hi + (size_t)n*16384;
  unsigned short* lo_out = hs_lo + (size_t)n*16384;
  int p = 0;
  for (int grp = 0; grp < 16; ++grp) {
    unsigned short hbuf[8];
    #pragma unroll
    for (int k = 0; k < 8; ++k) {
      int st = grp*8 + k;
      const float4* hp = (const float4*)(&h_s[p][0]) + 8*s;
      float4 h0 = hp[0], h1 = hp[1], h2 = hp[2], h3 = hp[3];
      float4 h4 = hp[4], h5 = hp[5], h6 = hp[6], h7 = hp[7];
      float cin = cin_s[(st<<7) + i];
      float a0, a1;
      a0  = whh[0].x*h0.x + whh[0].y*h0.y + whh[0].z*h0.z + whh[0].w*h0.w;
      a1  = whh[1].x*h1.x + whh[1].y*h1.y + whh[1].z*h1.z + whh[1].w*h1.w;
      a0 += whh[2].x*h2.x + whh[2].y*h2.y + whh[2].z*h2.z + whh[2].w*h2.w;
      a1 += whh[3].x*h3.x + whh[3].y*h3.y + whh[3].z*h3.z + whh[3].w*h3.w;
      a0 += whh[4].x*h4.x + whh[4].y*h4.y + whh[4].z*h4.z + whh[4].w*h4.w;
      a1 += whh[5].x*h5.x + whh[5].y*h5.y + whh[5].z*h5.z + whh[5].w*h5.w;
      a0 += whh[6].x*h6.x + whh[6].y*h6.y + whh[6].z*h6.z + whh[6].w*h6.w;
      a1 += whh[7].x*h7.x + whh[7].y*h7.y + whh[7].z*h7.z + whh[7].w*h7.w;
      float acc = a0 + a1;
      acc += __shfl_xor(acc, 1);
      acc += __shfl_xor(acc, 2);
      acc += cin;
      float ax = fabsf(acc);
      float e = __expf(2.f*ax);
      float hn = copysignf(1.f - 2.f/(e + 1.f), acc);  // tanh, stable both tails
      unsigned short h = f2bf(hn);
      if (s == 0) {
        h_s[p^1][i] = hn;
        hbuf[k] = h;
      } else if (s == 1) {
        hbuf[k] = f2bf(hn - bf2f(h));
      }
      __syncthreads();
      p ^= 1;
    }
    // batched global stores — drained at the next group's first barrier
    if (s == 0) {
      #pragma unroll
      for (int k = 0; k < 8; ++k) hi_out[((grp*8 + k)<<7) + i] = hbuf[k];
    } else if (s == 1) {
      #pragma unroll
      for (int k = 0; k < 8; ++k) lo_out[((grp*8 + k)<<7) + i] = hbuf[k];
    }
  }
}

// -------- split w_out into bf16 hi/lo --------
__global__ void k_wsplit(const float* __restrict__ w, unsigned short* __restrict__ hi,
                         unsigned short* __restrict__ lo, int nelem) {
  int i = blockIdx.x * blockDim.x + threadIdx.x;
  if (i < nelem) {
    float x = w[i];
    unsigned short h = f2bf(x);
    hi[i] = h;
    lo[i] = f2bf(x - bf2f(h));
  }
}

// -------- sig = sin(hs @ w_out^T) via split-bf16 MFMA --------
__global__ __launch_bounds__(256) void k_gemm_mfma(
    const unsigned short* __restrict__ hs_hi, const unsigned short* __restrict__ hs_lo,
    const unsigned short* __restrict__ wo_hi, const unsigned short* __restrict__ wo_lo,
    const int* __restrict__ vidx, float* __restrict__ sig) {
  int n = blockIdx.y;
  int v = vidx[n];
  int t = threadIdx.x;
  int lane = t & 63, wave = t >> 6;
  int wm = wave >> 1, wn = wave & 1;
  int m_base = wm * 64;
  int n_base = blockIdx.x * 128 + wn * 64;
  int lrow = lane & 15;
  int lk = (lane >> 4) << 3;

  const unsigned short* Ah = hs_hi + (size_t)n * 16384;
  const unsigned short* Al = hs_lo + (size_t)n * 16384;
  const unsigned short* Bh = wo_hi + (size_t)v * 131072;
  const unsigned short* Bl = wo_lo + (size_t)v * 131072;

  f32x4 acc[4][4];
  #pragma unroll
  for (int i = 0; i < 4; ++i)
    #pragma unroll
    for (int j = 0; j < 4; ++j) acc[i][j] = (f32x4){0.f, 0.f, 0.f, 0.f};

  #pragma unroll
  for (int ks = 0; ks < 128; ks += 32) {
    short8 ah[4], al[4], bh[4], bl[4];
    #pragma unroll
    for (int mt = 0; mt < 4; ++mt) {
      size_t o = (size_t)(m_base + mt*16 + lrow) * 128 + ks + lk;
      ah[mt] = *(const short8*)(Ah + o);
      al[mt] = *(const short8*)(Al + o);
    }
    #pragma unroll
    for (int nt = 0; nt < 4; ++nt) {
      size_t o = (size_t)(n_base + nt*16 + lrow) * 128 + ks + lk;
      bh[nt] = *(const short8*)(Bh + o);
      bl[nt] = *(const short8*)(Bl + o);
    }
    #pragma unroll
    for (int mt = 0; mt < 4; ++mt)
      #pragma unroll
      for (int nt = 0; nt < 4; ++nt) {
        acc[mt][nt] = __builtin_amdgcn_mfma_f32_16x16x32_bf16(ah[mt], bh[nt], acc[mt][nt], 0, 0, 0);
        acc[mt][nt] = __builtin_amdgcn_mfma_f32_16x16x32_bf16(ah[mt], bl[nt], acc[mt][nt], 0, 0, 0);
        acc[mt][nt] = __builtin_amdgcn_mfma_f32_16x16x32_bf16(al[mt], bh[nt], acc[mt][nt], 0, 0, 0);
      }
  }

  // C/D layout: col = lane&15, row = (lane>>4)*4 + reg
  float* dst = sig + (size_t)n * NSMP;
  int drow = (lane >> 4) << 2, dcol = lane & 15;
  #pragma unroll
  for (int mt = 0; mt < 4; ++mt)
    #pragma unroll
    for (int nt = 0; nt < 4; ++nt)
      #pragma unroll
      for (int r = 0; r < 4; ++r) {
        int m = m_base + mt*16 + drow + r;
        int nn = n_base + nt*16 + dcol;
        dst[(size_t)m * 1024 + nn] = __sinf(acc[mt][nt][r]);
      }
}

// -------- FFT pass A (real, unpacked — verbs): column FFT-512 over n2 --------
__global__ __launch_bounds__(256) void k_passA(const float* __restrict__ in,
                                               float2* __restrict__ outb,
                                               const float2* __restrict__ w512g) {
  __shared__ float2 w512[512];
  __shared__ float2 tile[COLS*CST];
  int t = threadIdx.x;
  for (int i = t; i < 512; i += 256) w512[i] = w512g[i];
  const float* src = in + (size_t)blockIdx.y * NSMP;
  float2* dst = outb + (size_t)blockIdx.y * MFT;
  int c0 = blockIdx.x * COLS;
  for (int i = t; i < 256*COLS; i += 256) {   // stage only nonzero lower half
    int cc = i & (COLS-1), n2 = i >> 3;
    tile[cc*CST + pidx(n2)] = make_float2(src[c0 + cc + (n2<<9)], 0.f);
  }
  __syncthreads();
  int wid = t >> 6, lane = t & 63;
  #pragma unroll
  for (int g = 0; g < COLS/4; ++g)
    fft512_fwd_zpad(&tile[((g<<2) + wid)*CST], lane, w512);
  __syncthreads();
  for (int i = t; i < 512*COLS; i += 256) {
    int cc = i & (COLS-1), q = i >> 3;
    dst[c0 + cc + (q<<9)] = tile[cc*CST + pidx(q)];
  }
}

// -------- FFT pass B forward-only (verb spectra) --------
__global__ __launch_bounds__(256) void k_passBv(float2* __restrict__ Xb,
                                                const float2* __restrict__ w512g) {
  __shared__ float2 w512[512];
  __shared__ float2 rows[ROWS*RST];
  int t = threadIdx.x;
  for (int i = t; i < 512; i += 256) w512[i] = w512g[i];
  float2* Xe = Xb + (size_t)blockIdx.y * MFT;
  int q0 = blockIdx.x * ROWS;
  for (int i = t; i < ROWS*512; i += 256) {
    int r = i >> 9, n1 = i & 511;
    int q = q0 + r;
    int k2 = rev3(q);
    rows[r*RST + pidx(n1)] = cmul(Xe[(size_t)q*512 + n1], wtw((n1*k2) & (MFT-1)));
  }
  __syncthreads();
  int wid = t >> 6, lane = t & 63;
  #pragma unroll
  for (int g = 0; g < ROWS/4; ++g)
    fft512_fwd(&rows[((g<<2)+wid)*RST], lane, w512);
  __syncthreads();
  for (int i = t; i < ROWS*512; i += 256) {
    int r = i >> 9, n1 = i & 511;
    Xe[(size_t)(q0 + r)*512 + n1] = rows[r*RST + pidx(n1)];
  }
}

// ======== packed (2 real events per complex FFT) conv pipeline ========

// pass A: z = sig[2p] + i*sig[2p+1], column FFT-512 (upper half zero-padded)
__global__ __launch_bounds__(256) void k_passA2(const float* __restrict__ in,
                                                float2* __restrict__ outb,
                                                const float2* __restrict__ w512g) {
  __shared__ float2 w512[512];
  __shared__ float2 tile[COLS*CST];
  int t = threadIdx.x;
  for (int i = t; i < 512; i += 256) w512[i] = w512g[i];
  const float* src = in + (size_t)blockIdx.y * 2 * NSMP;
  float2* dst = outb + (size_t)blockIdx.y * MFT;
  int c0 = blockIdx.x * COLS;
  for (int i = t; i < 256*COLS; i += 256) {   // stage only nonzero lower half
    int cc = i & (COLS-1), n2 = i >> 3;
    int o = c0 + cc + (n2<<9);
    tile[cc*CST + pidx(n2)] = make_float2(src[o], src[o + NSMP]);
  }
  __syncthreads();
  int wid = t >> 6, lane = t & 63;
  #pragma unroll
  for (int g = 0; g < COLS/4; ++g)
    fft512_fwd_zpad(&tile[((g<<2) + wid)*CST], lane, w512);
  __syncthreads();
  for (int i = t; i < 512*COLS; i += 256) {
    int cc = i & (COLS-1), q = i >> 3;
    dst[c0 + cc + (q<<9)] = tile[cc*CST + pidx(q)];
  }
}

// pass B: row FFT of conjugate-paired rows, Hermitian split, per-event reverb
// multiply, recombine, inverse row FFT. Block = 4 row-pair slots.
// slot j (global): j<255 -> k2A=j+1, k2B=511-j; j==255 -> self rows k2=0 and k2=256.
// Within rows (k2!=0): partner position of p is p^511; row k2=0: rev3((512-rev3(p))&511).
__global__ __launch_bounds__(256) void k_passB2(float2* __restrict__ Xb,
                                                const float2* __restrict__ spec,
                                                const float2* __restrict__ w512g,
                                                const int* __restrict__ ridx,
                                                const float* __restrict__ m0a,
                                                const float* __restrict__ m1a,
                                                const float* __restrict__ ampa,
                                                int e0) {
  __shared__ float2 w512[512];
  __shared__ float2 rows[ROWS*RST];
  int t = threadIdx.x;
  for (int i = t; i < 512; i += 256) w512[i] = w512g[i];
  float2* Xe = Xb + (size_t)blockIdx.y * MFT;
  int bx = blockIdx.x;
  bool last = (bx == 63);

  // load + forward twiddle (computed — no uncoalesced global gather)
  for (int i = t; i < ROWS*512; i += 256) {
    int r = i >> 9, n1 = i & 511;
    int s = r >> 1, which = r & 1;
    int j = bx*4 + s;
    int k2 = (j == 255) ? (which ? 256 : 0) : (which ? 511 - j : j + 1);
    int q = rev3(k2);
    rows[r*RST + pidx(n1)] = cmul(Xe[(size_t)q*512 + n1], wtw((n1*k2) & (MFT-1)));
  }
  __syncthreads();
  int wid = t >> 6, lane = t & 63;
  #pragma unroll
  for (int g = 0; g < ROWS/4; ++g)
    fft512_fwd(&rows[((g<<2)+wid)*RST], lane, w512);
  __syncthreads();

  // per-event reverb responses
  int na = e0 + 2*blockIdx.y, nb = na + 1;
  float inv = 1.f/(float)MFT;
  float sa0 = ampa[na]*m0a[na]*inv, sa1 = ampa[na]*m1a[na]*inv;
  float sb0 = ampa[nb]*m0a[nb]*inv, sb1 = ampa[nb]*m1a[nb]*inv;
  const float2* spa = spec + (size_t)ridx[na]*MFT;
  const float2* spb = spec + (size_t)ridx[nb]*MFT;

  auto combine = [&](int rA, int pA, int rB, int pB, int qA) {
    float2 P = rows[rA*RST + pidx(pA)];
    float2 Q = rows[rB*RST + pidx(pB)];
    float2 A = make_float2(0.5f*(P.x + Q.x), 0.5f*(P.y - Q.y));   // spectrum of event a at k
    float2 Bv = make_float2(0.5f*(P.y + Q.y), 0.5f*(Q.x - P.x));  // spectrum of event b at k
    float2 Va = spa[(size_t)qA*512 + pA];
    float2 Vb = spb[(size_t)qA*512 + pA];
    float2 Ga = make_float2(sa0*Va.x + sa1, sa0*Va.y);
    float2 Gb = make_float2(sb0*Vb.x + sb1, sb0*Vb.y);
    float2 Ya = cmul(A, Ga);
    float2 Yb = cmul(Bv, Gb);
    rows[rA*RST + pidx(pA)] = make_float2(Ya.x - Yb.y, Ya.y + Yb.x);    // Zout(k)  = Ya + i*Yb
    rows[rB*RST + pidx(pB)] = make_float2(Ya.x + Yb.y, Yb.x - Ya.y);    // Zout(-k) = conj(Ya)+i*conj(Yb)
  };

  int ncomb = last ? 1536 : 2048;
  for (int i = t; i < ncomb; i += 256) {
    int s = i >> 9, p = i & 511;
    int j = bx*4 + s;
    combine(2*s, p, 2*s + 1, p ^ 511, rev3(j + 1));
  }
  if (last) {
    // row 6: k2=0 (q=0), self-paired with pperm = rev3((512-rev3(p))&511)
    for (int p = t; p < 512; p += 256) {
      int pp = rev3((512 - rev3(p)) & 511);
      if (p <= pp) combine(6, p, 6, pp, 0);
    }
    // row 7: k2=256 (q=4), self-paired with pperm = p^511
    if (t < 256) combine(7, t, 7, t ^ 511, 4);
  }
  __syncthreads();

  #pragma unroll
  for (int g = 0; g < ROWS/4; ++g)
    fft512_inv(&rows[((g<<2)+wid)*RST], lane, w512);
  __syncthreads();
  for (int i = t; i < ROWS*512; i += 256) {
    int r = i >> 9, n1 = i & 511;
    int s = r >> 1, which = r & 1;
    int j = bx*4 + s;
    int k2 = (j == 255) ? (which ? 256 : 0) : (which ? 511 - j : j + 1);
    int q = rev3(k2);
    Xe[(size_t)q*512 + n1] = cmulc(rows[r*RST + pidx(n1)], wtw((n1*k2) & (MFT-1)));
  }
}

// pass C: inverse column FFT (truncated — only n2<256 consumed);
// Re -> event 2p (shift a), Im -> event 2p+1 (shift b)
__global__ __launch_bounds__(256) void k_passC2(const float2* __restrict__ Xb,
                                                float* __restrict__ dout,
                                                const float2* __restrict__ w512g,
                                                const int* __restrict__ shiftA,
                                                int e0) {
  __shared__ float2 w512[512];
  __shared__ float2 tile[COLS*CST];
  int t = threadIdx.x;
  for (int i = t; i < 512; i += 256) w512[i] = w512g[i];
  const float2* Xe = Xb + (size_t)blockIdx.y * MFT;
  int c0 = blockIdx.x * COLS;
  for (int i = t; i < 512*COLS; i += 256) {
    int cc = i & (COLS-1), q = i >> 3;
    tile[cc*CST + pidx(q)] = Xe[c0 + cc + ((size_t)q<<9)];
  }
  __syncthreads();
  int wid = t >> 6, lane = t & 63;
  #pragma unroll
  for (int g = 0; g < COLS/4; ++g)
    fft512_inv_trunc(&tile[((g<<2) + wid)*CST], lane, w512);
  __syncthreads();
  int na = e0 + 2*blockIdx.y, nb = na + 1;
  int sha = shiftA[na], shb = shiftA[nb];
  float* dpa = dout + (size_t)na*NSMP;
  float* dpb = dout + (size_t)nb*NSMP;
  for (int i = t; i < 256*COLS; i += 256) {   // only p < NS needed (n2 < 256)
    int cc = i & (COLS-1), n2 = i >> 3;
    int p = c0 + cc + (n2<<9);
    float2 y = tile[cc*CST + pidx(n2)];
    int oa = p + sha;
    if (oa < NSMP) dpa[oa] = y.x;
    int ob = p + shb;
    if (ob < NSMP) dpb[ob] = y.y;
  }
}

} // namespace

extern "C" void kernel_launch(void* const* d_in, const int* in_sizes, int n_in,
                              void* d_out, int out_size, void* d_ws, size_t ws_size,
                              hipStream_t stream) {
  (void)in_sizes; (void)n_in;
  const float* voice  = (const float*)d_in[0];
  const float* cpc    = (const float*)d_in[1];
  const float* amps   = (const float*)d_in[2];
  const float* room   = (const float*)d_in[3];
  const float* rmix   = (const float*)d_in[4];
  const float* times  = (const float*)d_in[5];
  const float* cp_tab = (const float*)d_in[6];
  const float* verbs  = (const float*)d_in[7];
  const float* w_in   = (const float*)d_in[8];
  const float* w_ih   = (const float*)d_in[9];
  const float* w_hh   = (const float*)d_in[10];
  const float* w_out  = (const float*)d_in[11];
  float* out = (float*)d_out;

  char* base = (char*)d_ws;
  size_t off = 0;
  auto carve = [&](size_t bytes) -> void* {
    void* p = base + off;
    off = (off + bytes + 255) & ~(size_t)255;
    return p;
  };
  float*  sig   = (float*) carve((size_t)NEV*NSMP*4);     // 64 MB
  float2* w512g = (float2*)carve((size_t)512*8);          // 4 KB compact twiddles
  float2* spec  = (float2*)carve((size_t)16*MFT*8);       // 32 MB (verb spectra)
  int*   vidx  = (int*)  carve(NEV*4);
  int*   cpidx = (int*)  carve(NEV*4);
  int*   ridx  = (int*)  carve(NEV*4);
  int*   shf   = (int*)  carve(NEV*4);
  float* m0    = (float*)carve(NEV*4);
  float* m1    = (float*)carve(NEV*4);
  float* amp   = (float*)carve(NEV*4);

  // GEMM-phase temporaries alias the spec region (13.3 MB < 32 MB); verb
  // spectra are computed AFTER k_gemm_mfma, when these are all dead.
  size_t toff = (size_t)((char*)spec - base);
  auto carveT = [&](size_t bytes) -> void* {
    void* p = base + toff;
    toff = (toff + bytes + 255) & ~(size_t)255;
    return p;
  };
  float*          mred  = (float*)         carveT((size_t)8*128*16*4);
  float*          ctrl  = (float*)         carveT((size_t)NEV*2048*4);
  unsigned short* hs_hi = (unsigned short*)carveT((size_t)NEV*128*128*2);
  unsigned short* hs_lo = (unsigned short*)carveT((size_t)NEV*128*128*2);
  unsigned short* wo_hi = (unsigned short*)carveT((size_t)8*1024*128*2);
  unsigned short* wo_lo = (unsigned short*)carveT((size_t)8*1024*128*2);

  float2* X = (float2*)(base + off);
  size_t rem = (ws_size > off) ? (ws_size - off) : 0;
  int C = (int)(rem / ((size_t)MFT*8));     // chunk size in PAIRS
  if (C > NPAIR) C = NPAIR;
  if (C < 1) C = 1;

  hipMemsetAsync(d_out, 0, (size_t)out_size*sizeof(float), stream);

  k_params<<<NEV, 64, 0, stream>>>(voice, cpc, amps, room, rmix, times,
                                   vidx, cpidx, ridx, shf, m0, m1, amp);
  k_w512<<<2, 256, 0, stream>>>(w512g);
  k_mred<<<dim3(128, 8), 64, 0, stream>>>(w_ih, w_in, mred);
  k_topk<<<NEV, 256, 0, stream>>>(cp_tab, cpidx, ctrl);
  k_rnn<<<NEV, 512, 0, stream>>>(ctrl, mred, w_hh, vidx, hs_hi, hs_lo);
  k_wsplit<<<(8*1024*128)/256, 256, 0, stream>>>(w_out, wo_hi, wo_lo, 8*1024*128);
  k_gemm_mfma<<<dim3(8, NEV), 256, 0, stream>>>(hs_hi, hs_lo, wo_hi, wo_lo, vidx, sig);

  // verb spectra: unpacked forward pipeline (must run after k_gemm_mfma —
  // temporaries above alias this region)
  k_passA<<<dim3(64, 16), 256, 0, stream>>>(verbs, spec, w512g);
  k_passBv<<<dim3(64, 16), 256, 0, stream>>>(spec, w512g);

  // main conv: 2 real events packed per complex FFT pipeline
  for (int p0 = 0; p0 < NPAIR; p0 += C) {
    int cp = (NPAIR - p0 < C) ? (NPAIR - p0) : C;
    k_passA2<<<dim3(64, cp), 256, 0, stream>>>(sig + (size_t)p0*2*NSMP, X, w512g);
    k_passB2<<<dim3(64, cp), 256, 0, stream>>>(X, spec, w512g, ridx, m0, m1, amp, 2*p0);
    k_passC2<<<dim3(64, cp), 256, 0, stream>>>(X, out, w512g, shf, 2*p0);
  }
}

// Round 14
// 417.444 us; speedup vs baseline: 1.0938x; 1.0938x over previous
//
#include <hip/hip_runtime.h>
#include <hip/hip_fp16.h>
#include <math.h>

namespace {

constexpr int NSMP = 131072;   // n_samples
constexpr int NEV  = 128;      // B*E events
constexpr int NPAIR = NEV/2;   // packed complex pipelines
constexpr int MFT  = 262144;   // 2*NS FFT size = 512*512
constexpr int COLS = 8;        // cols per pass A/C block
constexpr int ROWS = 8;        // rows per pass B block
constexpr int RST  = 576;      // padded row stride (pass B): pidx(511)=574 < 576
constexpr int CST  = 578;      // padded col stride (pass A/C)

typedef __attribute__((ext_vector_type(8))) short short8;
typedef __attribute__((ext_vector_type(4))) float f32x4;

__device__ __forceinline__ float2 cadd(float2 a, float2 b){ return make_float2(a.x+b.x, a.y+b.y); }
__device__ __forceinline__ float2 csub(float2 a, float2 b){ return make_float2(a.x-b.x, a.y-b.y); }
__device__ __forceinline__ float2 cmul(float2 a, float2 b){ return make_float2(a.x*b.x - a.y*b.y, a.x*b.y + a.y*b.x); }
__device__ __forceinline__ float2 cmulc(float2 a, float2 b){ return make_float2(a.x*b.x + a.y*b.y, a.y*b.x - a.x*b.y); }
__device__ __forceinline__ int rev3(int x){ return ((x&7)<<6) | (x&56) | (x>>6); }  // base-8 digit reversal, 9 bits
// bank-conflict-breaking pad: one extra float2 per 8 (stage3 32-way -> 4-way)
__device__ __forceinline__ int pidx(int i){ return i + (i>>3); }

// fp16 pack/unpack for the global spectral intermediates (compute stays fp32)
__device__ __forceinline__ __half2 pkh(float2 v){ return __floats2half2_rn(v.x, v.y); }
__device__ __forceinline__ float2 uph(__half2 h){ return __half22float2(h); }

// computed big twiddle: W_MFT^idx = (cos, sin) of -2*pi*idx/MFT — replaces the
// uncoalesced wbig gather (64 distinct cache lines per wave) with 2 trans ops.
__device__ __forceinline__ float2 wtw(int idx) {
  float ang = (float)idx * (-6.283185307179586f / (float)MFT);
  float sn, cs;
  __sincosf(ang, &sn, &cs);
  return make_float2(cs, sn);
}

// round-to-nearest-even f32 -> bf16 (values here are always finite)
__device__ __forceinline__ unsigned short f2bf(float x) {
  unsigned u = __float_as_uint(x);
  unsigned r = (u + 0x7FFFu + ((u >> 16) & 1u)) >> 16;
  return (unsigned short)r;
}
__device__ __forceinline__ float bf2f(unsigned short h) {
  return __uint_as_float(((unsigned)h) << 16);
}

// 8-point DFT: out[k] = sum_j in[j] * exp(SGN*2*pi*i*j*k/8)
template<int SGN>
__device__ __forceinline__ void fft8v(float2* u) {
  const float S2 = 0.70710678118654752440f;
  float2 a0 = cadd(u[0], u[4]), a1 = csub(u[0], u[4]);
  float2 a2 = cadd(u[2], u[6]), a3 = csub(u[2], u[6]);
  float2 b0 = cadd(u[1], u[5]), b1 = csub(u[1], u[5]);
  float2 b2 = cadd(u[3], u[7]), b3 = csub(u[3], u[7]);
  float2 a3r = (SGN < 0) ? make_float2(a3.y, -a3.x) : make_float2(-a3.y, a3.x);
  float2 b3r = (SGN < 0) ? make_float2(b3.y, -b3.x) : make_float2(-b3.y, b3.x);
  float2 E0 = cadd(a0, a2), E2 = csub(a0, a2);
  float2 E1 = cadd(a1, a3r), E3 = csub(a1, a3r);
  float2 O0 = cadd(b0, b2), O2 = csub(b0, b2);
  float2 O1 = cadd(b1, b3r), O3 = csub(b1, b3r);
  const float sg = (SGN < 0) ? -1.f : 1.f;
  O1 = cmul(O1, make_float2(S2, sg*S2));
  O2 = (SGN < 0) ? make_float2(O2.y, -O2.x) : make_float2(-O2.y, O2.x);
  O3 = cmul(O3, make_float2(-S2, sg*S2));
  u[0] = cadd(E0, O0); u[4] = csub(E0, O0);
  u[1] = cadd(E1, O1); u[5] = csub(E1, O1);
  u[2] = cadd(E2, O2); u[6] = csub(E2, O2);
  u[3] = cadd(E3, O3); u[7] = csub(E3, O3);
}

// Stages 2+3 of the forward 512-pt DIF (shared by full and zero-padded heads).
__device__ __forceinline__ void fft512_fwd_tail(float2* X, int lane, const float2* w512) {
  float2 u[8];
  {
    int b = (lane>>3)<<6, m = lane&7;
    #pragma unroll
    for (int j = 0; j < 8; ++j) u[j] = X[pidx(b + (j<<3) + m)];
    fft8v<-1>(u);
    #pragma unroll
    for (int r = 1; r < 8; ++r) u[r] = cmul(u[r], w512[((m*r)<<3) & 511]);
    #pragma unroll
    for (int r = 0; r < 8; ++r) X[pidx(b + (r<<3) + m)] = u[r];
  }
  {
    int c = lane<<3;
    #pragma unroll
    for (int j = 0; j < 8; ++j) u[j] = X[pidx(c + j)];
    fft8v<-1>(u);
    #pragma unroll
    for (int r = 0; r < 8; ++r) X[pidx(c + r)] = u[r];
  }
}

// In-place 512-pt forward DIF (natural in -> base-8 digit-reversed out).
// X points at a contiguous padded transform: element i lives at X[pidx(i)].
// One wave (lane 0..63) per transform. The transform's LDS region is
// WAVE-PRIVATE: same-wave LDS ops are processed in order (lgkmcnt), so NO
// barriers are needed inside — callers barrier only at cross-wave phases.
__device__ void fft512_fwd(float2* X, int lane, const float2* w512) {
  float2 u[8];
  #pragma unroll
  for (int j = 0; j < 8; ++j) u[j] = X[pidx((j<<6) + lane)];
  fft8v<-1>(u);
  #pragma unroll
  for (int r = 1; r < 8; ++r) u[r] = cmul(u[r], w512[(lane*r) & 511]);
  #pragma unroll
  for (int r = 0; r < 8; ++r) X[pidx((r<<6) + lane)] = u[r];
  fft512_fwd_tail(X, lane, w512);
}

// Zero-padded variant: elements 256..511 are known zero (never read — callers
// stage only the lower half). Stage-1 butterfly specialized for u[4..7] == 0.
__device__ void fft512_fwd_zpad(float2* X, int lane, const float2* w512) {
  const float S2 = 0.70710678118654752440f;
  float2 u[8];
  #pragma unroll
  for (int j = 0; j < 4; ++j) u[j] = X[pidx((j<<6) + lane)];
  {
    float2 a0 = u[0], a1 = u[0], a2 = u[2], a3 = u[2];
    float2 b0 = u[1], b1 = u[1], b2 = u[3], b3 = u[3];
    float2 a3r = make_float2(a3.y, -a3.x);
    float2 b3r = make_float2(b3.y, -b3.x);
    float2 E0 = cadd(a0, a2), E2 = csub(a0, a2);
    float2 E1 = cadd(a1, a3r), E3 = csub(a1, a3r);
    float2 O0 = cadd(b0, b2), O2 = csub(b0, b2);
    float2 O1 = cadd(b1, b3r), O3 = csub(b1, b3r);
    O1 = cmul(O1, make_float2(S2, -S2));
    O2 = make_float2(O2.y, -O2.x);
    O3 = cmul(O3, make_float2(-S2, -S2));
    u[0] = cadd(E0, O0); u[4] = csub(E0, O0);
    u[1] = cadd(E1, O1); u[5] = csub(E1, O1);
    u[2] = cadd(E2, O2); u[6] = csub(E2, O2);
    u[3] = cadd(E3, O3); u[7] = csub(E3, O3);
  }
  #pragma unroll
  for (int r = 1; r < 8; ++r) u[r] = cmul(u[r], w512[(lane*r) & 511]);
  #pragma unroll
  for (int r = 0; r < 8; ++r) X[pidx((r<<6) + lane)] = u[r];
  fft512_fwd_tail(X, lane, w512);
}

// Stages 1+2 of the inverse (shared by full and truncated-output variants).
__device__ __forceinline__ void fft512_inv_head(float2* X, int lane, const float2* w512) {
  float2 u[8];
  {
    int c = lane<<3;
    #pragma unroll
    for (int r = 0; r < 8; ++r) u[r] = X[pidx(c + r)];
    fft8v<1>(u);
    #pragma unroll
    for (int j = 0; j < 8; ++j) X[pidx(c + j)] = u[j];
  }
  {
    int b = (lane>>3)<<6, m = lane&7;
    #pragma unroll
    for (int r = 0; r < 8; ++r) u[r] = X[pidx(b + (r<<3) + m)];
    #pragma unroll
    for (int r = 1; r < 8; ++r) u[r] = cmulc(u[r], w512[((m*r)<<3) & 511]);
    fft8v<1>(u);
    #pragma unroll
    for (int j = 0; j < 8; ++j) X[pidx(b + (j<<3) + m)] = u[j];
  }
}

// In-place 512-pt inverse (transpose-conjugate of fwd): digit-reversed in -> natural out.
// Unnormalized. Barrier-free (wave-private region), as above.
__device__ void fft512_inv(float2* X, int lane, const float2* w512) {
  fft512_inv_head(X, lane, w512);
  float2 u[8];
  #pragma unroll
  for (int r = 0; r < 8; ++r) u[r] = X[pidx((r<<6) + lane)];
  #pragma unroll
  for (int r = 1; r < 8; ++r) u[r] = cmulc(u[r], w512[(lane*r) & 511]);
  fft8v<1>(u);
  #pragma unroll
  for (int j = 0; j < 8; ++j) X[pidx((j<<6) + lane)] = u[j];
}

// Truncated-output variant: only natural outputs 0..255 are consumed (pass C
// keeps n2 < 256); skip the upper-half final stores.
__device__ void fft512_inv_trunc(float2* X, int lane, const float2* w512) {
  fft512_inv_head(X, lane, w512);
  float2 u[8];
  #pragma unroll
  for (int r = 0; r < 8; ++r) u[r] = X[pidx((r<<6) + lane)];
  #pragma unroll
  for (int r = 1; r < 8; ++r) u[r] = cmulc(u[r], w512[(lane*r) & 511]);
  fft8v<1>(u);
  #pragma unroll
  for (int j = 0; j < 4; ++j) X[pidx((j<<6) + lane)] = u[j];
}

// -------- per-event scalar params (argmaxes, softmax mix, |amp|) --------
__global__ void k_params(const float* __restrict__ voice, const float* __restrict__ cpc,
                         const float* __restrict__ amps, const float* __restrict__ room,
                         const float* __restrict__ rmix, const float* __restrict__ times,
                         int* __restrict__ vidx, int* __restrict__ cpidx, int* __restrict__ ridx,
                         int* __restrict__ shiftA, float* __restrict__ m0, float* __restrict__ m1,
                         float* __restrict__ amp) {
  int n = blockIdx.x, t = threadIdx.x;
  if (t == 0) {
    const float* p = voice + n*8; int bi = 0; float bv = p[0];
    for (int i = 1; i < 8; ++i) if (p[i] > bv) { bv = p[i]; bi = i; }
    vidx[n] = bi;
  } else if (t == 1) {
    const float* p = cpc + n*512; int bi = 0; float bv = p[0];
    for (int i = 1; i < 512; ++i) if (p[i] > bv) { bv = p[i]; bi = i; }
    cpidx[n] = bi;
  } else if (t == 2) {
    const float* p = room + n*16; int bi = 0; float bv = p[0];
    for (int i = 1; i < 16; ++i) if (p[i] > bv) { bv = p[i]; bi = i; }
    ridx[n] = bi;
  } else if (t == 3) {
    const float* p = times + n*128; int bi = 0; float bv = p[0];
    for (int i = 1; i < 128; ++i) if (p[i] > bv) { bv = p[i]; bi = i; }
    shiftA[n] = bi * 1024;
  } else if (t == 4) {
    float a = rmix[n*2], b = rmix[n*2+1];
    float mx = fmaxf(a, b);
    float ea = __expf(a - mx), eb = __expf(b - mx);
    float inv = 1.f / (ea + eb);
    m0[n] = ea * inv; m1[n] = eb * inv;
    amp[n] = fabsf(amps[n]);
  }
}

// -------- compact 512-pt twiddle table: w512g[i] = exp(-2 pi i/512 * i) --------
__global__ void k_w512(float2* __restrict__ w512g) {
  int i = blockIdx.x * blockDim.x + threadIdx.x;
  if (i < 512) {
    double a = -2.0 * 3.14159265358979323846 * (double)(i * 512) / (double)MFT;
    w512g[i] = make_float2((float)cos(a), (float)sin(a));
  }
}

// -------- M[v] = w_ih[v] @ w_in[v]  -> [8][128][16] --------
__global__ void k_mred(const float* __restrict__ w_ih, const float* __restrict__ w_in,
                       float* __restrict__ mred) {
  int h = blockIdx.x, v = blockIdx.y, t = threadIdx.x;
  const float* ih = w_ih + ((size_t)v*128 + h)*1024;
  const float* wi = w_in + (size_t)v*1024*16;
  float acc[16];
  #pragma unroll
  for (int c = 0; c < 16; ++c) acc[c] = 0.f;
  for (int w = t; w < 1024; w += 64) {
    float a = ih[w];
    const float4* wr = (const float4*)(wi + (size_t)w*16);
    float4 q0 = wr[0], q1 = wr[1], q2 = wr[2], q3 = wr[3];
    acc[0] += a*q0.x; acc[1] += a*q0.y; acc[2] += a*q0.z; acc[3] += a*q0.w;
    acc[4] += a*q1.x; acc[5] += a*q1.y; acc[6] += a*q1.z; acc[7] += a*q1.w;
    acc[8] += a*q2.x; acc[9] += a*q2.y; acc[10]+= a*q2.z; acc[11]+= a*q2.w;
    acc[12]+= a*q3.x; acc[13]+= a*q3.y; acc[14]+= a*q3.z; acc[15]+= a*q3.w;
  }
  #pragma unroll
  for (int c = 0; c < 16; ++c) {
    float s = acc[c];
    for (int o = 32; o > 0; o >>= 1) s += __shfl_down(s, o);
    if (t == 0) mred[((size_t)v*128 + h)*16 + c] = s;
  }
}

// -------- exact top-128 of selected cp_table row (2048 vals), relu, ties by lowest index --------
__global__ __launch_bounds__(256) void k_topk(const float* __restrict__ cp_table,
                                              const int* __restrict__ cpidx,
                                              float* __restrict__ ctrl) {
  __shared__ int redw[4];
  __shared__ int scanbuf[256];
  int n = blockIdx.x, t = threadIdx.x;
  const float* row = cp_table + (size_t)cpidx[n]*2048;
  float f[8]; unsigned v[8];
  #pragma unroll
  for (int i = 0; i < 8; ++i) { f[i] = row[t*8 + i]; v[i] = __float_as_uint(f[i]); }
  int lane = t & 63, wid = t >> 6;
  unsigned thr = 0;
  for (int b = 31; b >= 0; --b) {  // values are >=0, bit pattern is order-preserving
    unsigned cand = thr | (1u << b);
    int c = 0;
    #pragma unroll
    for (int i = 0; i < 8; ++i) c += (v[i] >= cand);
    for (int o = 32; o > 0; o >>= 1) c += __shfl_down(c, o);
    if (lane == 0) redw[wid] = c;
    __syncthreads();
    int tot = redw[0] + redw[1] + redw[2] + redw[3];
    if (tot >= 128) thr = cand;
    __syncthreads();
  }
  int g = 0, eq = 0;
  #pragma unroll
  for (int i = 0; i < 8; ++i) { g += (v[i] > thr); eq += (v[i] == thr); }
  int gw = g;
  for (int o = 32; o > 0; o >>= 1) gw += __shfl_down(gw, o);
  if (lane == 0) redw[wid] = gw;
  scanbuf[t] = eq;
  __syncthreads();
  int G = redw[0] + redw[1] + redw[2] + redw[3];
  int extra = 128 - G;
  int incl = eq;
  for (int o = 1; o < 256; o <<= 1) {
    int add = (t >= o) ? scanbuf[t - o] : 0;
    __syncthreads();
    incl += add;
    scanbuf[t] = incl;
    __syncthreads();
  }
  int rank = incl - eq;
  float* outp = ctrl + (size_t)n*2048;
  #pragma unroll
  for (int i = 0; i < 8; ++i) {
    bool keep = (v[i] > thr) || ((v[i] == thr) && (rank < extra));
    if (v[i] == thr) rank++;
    outp[t*8 + i] = keep ? fmaxf(f[i], 0.f) : 0.f;
  }
}

// -------- 128-step tanh RNN, one block per event --------
// 512 threads: thread (i = t>>2, s = t&3) owns Whh[i][32s:32s+32] in VGPRs.
__global__ __launch_bounds__(512) void k_rnn(const float* __restrict__ ctrl,
                                             const float* __restrict__ mred,
                                             const float* __restrict__ w_hh,
                                             const int* __restrict__ vidx,
                                             unsigned short* __restrict__ hs_hi,
                                             unsigned short* __restrict__ hs_lo) {
  __shared__ __align__(16) float h_s[2][128];
  __shared__ float ctrl_s[2048];
  __shared__ float cin_s[128*128];   // cin[st][i] = sum_c M[i][c]*ctrl[c][st]
  int n = blockIdx.x, t = threadIdx.x;
  int i = t >> 2, s = t & 3;
  int v = vidx[n];

  // Whh quarter into VGPRs
  const float4* whhrow = (const float4*)(w_hh + ((size_t)v*128 + i)*128 + 32*s);
  float4 whh[8];
  #pragma unroll
  for (int j = 0; j < 8; ++j) whh[j] = whhrow[j];

  for (int k = t; k < 2048; k += 512) ctrl_s[k] = ctrl[(size_t)n*2048 + k];
  if (s == 0) { h_s[0][i] = 0.f; }
  __syncthreads();

  // precompute cin[st][i] for all steps (parallel, off the critical path)
  {
    int ii = t & 127, stq = t >> 7;   // thread -> output ii, step-quarter stq
    const float4* mrow = (const float4*)(mred + ((size_t)v*128 + ii)*16);
    float4 m0q = mrow[0], m1q = mrow[1], m2q = mrow[2], m3q = mrow[3];
    #pragma unroll 4
    for (int st0 = 0; st0 < 32; ++st0) {
      int st = stq*32 + st0;
      float a = 0.f, b = 0.f;
      a += m0q.x*ctrl_s[(0<<7)+st];  b += m0q.y*ctrl_s[(1<<7)+st];
      a += m0q.z*ctrl_s[(2<<7)+st];  b += m0q.w*ctrl_s[(3<<7)+st];
      a += m1q.x*ctrl_s[(4<<7)+st];  b += m1q.y*ctrl_s[(5<<7)+st];
      a += m1q.z*ctrl_s[(6<<7)+st];  b += m1q.w*ctrl_s[(7<<7)+st];
      a += m2q.x*ctrl_s[(8<<7)+st];  b += m2q.y*ctrl_s[(9<<7)+st];
      a += m2q.z*ctrl_s[(10<<7)+st]; b += m2q.w*ctrl_s[(11<<7)+st];
      a += m3q.x*ctrl_s[(12<<7)+st]; b += m3q.y*ctrl_s[(13<<7)+st];
      a += m3q.z*ctrl_s[(14<<7)+st]; b += m3q.w*ctrl_s[(15<<7)+st];
      cin_s[(st<<7) + ii] = a + b;
    }
  }
  __syncthreads();

  unsigned short* hi_out = hs_hi + (size_t)n*16384;
  unsigned short* lo_out = hs_lo + (size_t)n*16384;
  int p = 0;
  for (int grp = 0; grp < 16; ++grp) {
    unsigned short hbuf[8];
    #pragma unroll
    for (int k = 0; k < 8; ++k) {
      int st = grp*8 + k;
      const float4* hp = (const float4*)(&h_s[p][0]) + 8*s;
      float4 h0 = hp[0], h1 = hp[1], h2 = hp[2], h3 = hp[3];
      float4 h4 = hp[4], h5 = hp[5], h6 = hp[6], h7 = hp[7];
      float cin = cin_s[(st<<7) + i];
      float a0, a1;
      a0  = whh[0].x*h0.x + whh[0].y*h0.y + whh[0].z*h0.z + whh[0].w*h0.w;
      a1  = whh[1].x*h1.x + whh[1].y*h1.y + whh[1].z*h1.z + whh[1].w*h1.w;
      a0 += whh[2].x*h2.x + whh[2].y*h2.y + whh[2].z*h2.z + whh[2].w*h2.w;
      a1 += whh[3].x*h3.x + whh[3].y*h3.y + whh[3].z*h3.z + whh[3].w*h3.w;
      a0 += whh[4].x*h4.x + whh[4].y*h4.y + whh[4].z*h4.z + whh[4].w*h4.w;
      a1 += whh[5].x*h5.x + whh[5].y*h5.y + whh[5].z*h5.z + whh[5].w*h5.w;
      a0 += whh[6].x*h6.x + whh[6].y*h6.y + whh[6].z*h6.z + whh[6].w*h6.w;
      a1 += whh[7].x*h7.x + whh[7].y*h7.y + whh[7].z*h7.z + whh[7].w*h7.w;
      float acc = a0 + a1;
      acc += __shfl_xor(acc, 1);
      acc += __shfl_xor(acc, 2);
      acc += cin;
      float ax = fabsf(acc);
      float e = __expf(2.f*ax);
      float hn = copysignf(1.f - 2.f/(e + 1.f), acc);  // tanh, stable both tails
      unsigned short h = f2bf(hn);
      if (s == 0) {
        h_s[p^1][i] = hn;
        hbuf[k] = h;
      } else if (s == 1) {
        hbuf[k] = f2bf(hn - bf2f(h));
      }
      __syncthreads();
      p ^= 1;
    }
    // batched global stores — drained at the next group's first barrier
    if (s == 0) {
      #pragma unroll
      for (int k = 0; k < 8; ++k) hi_out[((grp*8 + k)<<7) + i] = hbuf[k];
    } else if (s == 1) {
      #pragma unroll
      for (int k = 0; k < 8; ++k) lo_out[((grp*8 + k)<<7) + i] = hbuf[k];
    }
  }
}

// -------- split w_out into bf16 hi/lo --------
__global__ void k_wsplit(const float* __restrict__ w, unsigned short* __restrict__ hi,
                         unsigned short* __restrict__ lo, int nelem) {
  int i = blockIdx.x * blockDim.x + threadIdx.x;
  if (i < nelem) {
    float x = w[i];
    unsigned short h = f2bf(x);
    hi[i] = h;
    lo[i] = f2bf(x - bf2f(h));
  }
}

// -------- sig = sin(hs @ w_out^T) via split-bf16 MFMA --------
__global__ __launch_bounds__(256) void k_gemm_mfma(
    const unsigned short* __restrict__ hs_hi, const unsigned short* __restrict__ hs_lo,
    const unsigned short* __restrict__ wo_hi, const unsigned short* __restrict__ wo_lo,
    const int* __restrict__ vidx, float* __restrict__ sig) {
  int n = blockIdx.y;
  int v = vidx[n];
  int t = threadIdx.x;
  int lane = t & 63, wave = t >> 6;
  int wm = wave >> 1, wn = wave & 1;
  int m_base = wm * 64;
  int n_base = blockIdx.x * 128 + wn * 64;
  int lrow = lane & 15;
  int lk = (lane >> 4) << 3;

  const unsigned short* Ah = hs_hi + (size_t)n * 16384;
  const unsigned short* Al = hs_lo + (size_t)n * 16384;
  const unsigned short* Bh = wo_hi + (size_t)v * 131072;
  const unsigned short* Bl = wo_lo + (size_t)v * 131072;

  f32x4 acc[4][4];
  #pragma unroll
  for (int i = 0; i < 4; ++i)
    #pragma unroll
    for (int j = 0; j < 4; ++j) acc[i][j] = (f32x4){0.f, 0.f, 0.f, 0.f};

  #pragma unroll
  for (int ks = 0; ks < 128; ks += 32) {
    short8 ah[4], al[4], bh[4], bl[4];
    #pragma unroll
    for (int mt = 0; mt < 4; ++mt) {
      size_t o = (size_t)(m_base + mt*16 + lrow) * 128 + ks + lk;
      ah[mt] = *(const short8*)(Ah + o);
      al[mt] = *(const short8*)(Al + o);
    }
    #pragma unroll
    for (int nt = 0; nt < 4; ++nt) {
      size_t o = (size_t)(n_base + nt*16 + lrow) * 128 + ks + lk;
      bh[nt] = *(const short8*)(Bh + o);
      bl[nt] = *(const short8*)(Bl + o);
    }
    #pragma unroll
    for (int mt = 0; mt < 4; ++mt)
      #pragma unroll
      for (int nt = 0; nt < 4; ++nt) {
        acc[mt][nt] = __builtin_amdgcn_mfma_f32_16x16x32_bf16(ah[mt], bh[nt], acc[mt][nt], 0, 0, 0);
        acc[mt][nt] = __builtin_amdgcn_mfma_f32_16x16x32_bf16(ah[mt], bl[nt], acc[mt][nt], 0, 0, 0);
        acc[mt][nt] = __builtin_amdgcn_mfma_f32_16x16x32_bf16(al[mt], bh[nt], acc[mt][nt], 0, 0, 0);
      }
  }

  // C/D layout: col = lane&15, row = (lane>>4)*4 + reg
  float* dst = sig + (size_t)n * NSMP;
  int drow = (lane >> 4) << 2, dcol = lane & 15;
  #pragma unroll
  for (int mt = 0; mt < 4; ++mt)
    #pragma unroll
    for (int nt = 0; nt < 4; ++nt)
      #pragma unroll
      for (int r = 0; r < 4; ++r) {
        int m = m_base + mt*16 + drow + r;
        int nn = n_base + nt*16 + dcol;
        dst[(size_t)m * 1024 + nn] = __sinf(acc[mt][nt][r]);
      }
}

// -------- FFT pass A (real, unpacked — verbs): column FFT-512 over n2 --------
__global__ __launch_bounds__(256) void k_passA(const float* __restrict__ in,
                                               __half2* __restrict__ outb,
                                               const float2* __restrict__ w512g) {
  __shared__ float2 w512[512];
  __shared__ float2 tile[COLS*CST];
  int t = threadIdx.x;
  for (int i = t; i < 512; i += 256) w512[i] = w512g[i];
  const float* src = in + (size_t)blockIdx.y * NSMP;
  __half2* dst = outb + (size_t)blockIdx.y * MFT;
  int c0 = blockIdx.x * COLS;
  for (int i = t; i < 256*COLS; i += 256) {   // stage only nonzero lower half
    int cc = i & (COLS-1), n2 = i >> 3;
    tile[cc*CST + pidx(n2)] = make_float2(src[c0 + cc + (n2<<9)], 0.f);
  }
  __syncthreads();
  int wid = t >> 6, lane = t & 63;
  #pragma unroll
  for (int g = 0; g < COLS/4; ++g)
    fft512_fwd_zpad(&tile[((g<<2) + wid)*CST], lane, w512);
  __syncthreads();
  for (int i = t; i < 512*COLS; i += 256) {
    int cc = i & (COLS-1), q = i >> 3;
    dst[c0 + cc + (q<<9)] = pkh(tile[cc*CST + pidx(q)]);
  }
}

// -------- FFT pass B forward-only (verb spectra) --------
__global__ __launch_bounds__(256) void k_passBv(__half2* __restrict__ Xb,
                                                const float2* __restrict__ w512g) {
  __shared__ float2 w512[512];
  __shared__ float2 rows[ROWS*RST];
  int t = threadIdx.x;
  for (int i = t; i < 512; i += 256) w512[i] = w512g[i];
  __half2* Xe = Xb + (size_t)blockIdx.y * MFT;
  int q0 = blockIdx.x * ROWS;
  for (int i = t; i < ROWS*512; i += 256) {
    int r = i >> 9, n1 = i & 511;
    int q = q0 + r;
    int k2 = rev3(q);
    rows[r*RST + pidx(n1)] = cmul(uph(Xe[(size_t)q*512 + n1]), wtw((n1*k2) & (MFT-1)));
  }
  __syncthreads();
  int wid = t >> 6, lane = t & 63;
  #pragma unroll
  for (int g = 0; g < ROWS/4; ++g)
    fft512_fwd(&rows[((g<<2)+wid)*RST], lane, w512);
  __syncthreads();
  for (int i = t; i < ROWS*512; i += 256) {
    int r = i >> 9, n1 = i & 511;
    Xe[(size_t)(q0 + r)*512 + n1] = pkh(rows[r*RST + pidx(n1)]);
  }
}

// ======== packed (2 real events per complex FFT) conv pipeline ========

// pass A: z = sig[2p] + i*sig[2p+1], column FFT-512 (upper half zero-padded)
__global__ __launch_bounds__(256) void k_passA2(const float* __restrict__ in,
                                                __half2* __restrict__ outb,
                                                const float2* __restrict__ w512g) {
  __shared__ float2 w512[512];
  __shared__ float2 tile[COLS*CST];
  int t = threadIdx.x;
  for (int i = t; i < 512; i += 256) w512[i] = w512g[i];
  const float* src = in + (size_t)blockIdx.y * 2 * NSMP;
  __half2* dst = outb + (size_t)blockIdx.y * MFT;
  int c0 = blockIdx.x * COLS;
  for (int i = t; i < 256*COLS; i += 256) {   // stage only nonzero lower half
    int cc = i & (COLS-1), n2 = i >> 3;
    int o = c0 + cc + (n2<<9);
    tile[cc*CST + pidx(n2)] = make_float2(src[o], src[o + NSMP]);
  }
  __syncthreads();
  int wid = t >> 6, lane = t & 63;
  #pragma unroll
  for (int g = 0; g < COLS/4; ++g)
    fft512_fwd_zpad(&tile[((g<<2) + wid)*CST], lane, w512);
  __syncthreads();
  for (int i = t; i < 512*COLS; i += 256) {
    int cc = i & (COLS-1), q = i >> 3;
    dst[c0 + cc + (q<<9)] = pkh(tile[cc*CST + pidx(q)]);
  }
}

// pass B: row FFT of conjugate-paired rows, Hermitian split, per-event reverb
// multiply, recombine, inverse row FFT. Block = 4 row-pair slots.
// slot j (global): j<255 -> k2A=j+1, k2B=511-j; j==255 -> self rows k2=0 and k2=256.
// Within rows (k2!=0): partner position of p is p^511; row k2=0: rev3((512-rev3(p))&511).
__global__ __launch_bounds__(256) void k_passB2(__half2* __restrict__ Xb,
                                                const __half2* __restrict__ spec,
                                                const float2* __restrict__ w512g,
                                                const int* __restrict__ ridx,
                                                const float* __restrict__ m0a,
                                                const float* __restrict__ m1a,
                                                const float* __restrict__ ampa,
                                                int e0) {
  __shared__ float2 w512[512];
  __shared__ float2 rows[ROWS*RST];
  int t = threadIdx.x;
  for (int i = t; i < 512; i += 256) w512[i] = w512g[i];
  __half2* Xe = Xb + (size_t)blockIdx.y * MFT;
  int bx = blockIdx.x;
  bool last = (bx == 63);

  // load + forward twiddle (computed — no uncoalesced global gather)
  for (int i = t; i < ROWS*512; i += 256) {
    int r = i >> 9, n1 = i & 511;
    int s = r >> 1, which = r & 1;
    int j = bx*4 + s;
    int k2 = (j == 255) ? (which ? 256 : 0) : (which ? 511 - j : j + 1);
    int q = rev3(k2);
    rows[r*RST + pidx(n1)] = cmul(uph(Xe[(size_t)q*512 + n1]), wtw((n1*k2) & (MFT-1)));
  }
  __syncthreads();
  int wid = t >> 6, lane = t & 63;
  #pragma unroll
  for (int g = 0; g < ROWS/4; ++g)
    fft512_fwd(&rows[((g<<2)+wid)*RST], lane, w512);
  __syncthreads();

  // per-event reverb responses
  int na = e0 + 2*blockIdx.y, nb = na + 1;
  float inv = 1.f/(float)MFT;
  float sa0 = ampa[na]*m0a[na]*inv, sa1 = ampa[na]*m1a[na]*inv;
  float sb0 = ampa[nb]*m0a[nb]*inv, sb1 = ampa[nb]*m1a[nb]*inv;
  const __half2* spa = spec + (size_t)ridx[na]*MFT;
  const __half2* spb = spec + (size_t)ridx[nb]*MFT;

  auto combine = [&](int rA, int pA, int rB, int pB, int qA) {
    float2 P = rows[rA*RST + pidx(pA)];
    float2 Q = rows[rB*RST + pidx(pB)];
    float2 A = make_float2(0.5f*(P.x + Q.x), 0.5f*(P.y - Q.y));   // spectrum of event a at k
    float2 Bv = make_float2(0.5f*(P.y + Q.y), 0.5f*(Q.x - P.x));  // spectrum of event b at k
    float2 Va = uph(spa[(size_t)qA*512 + pA]);
    float2 Vb = uph(spb[(size_t)qA*512 + pA]);
    float2 Ga = make_float2(sa0*Va.x + sa1, sa0*Va.y);
    float2 Gb = make_float2(sb0*Vb.x + sb1, sb0*Vb.y);
    float2 Ya = cmul(A, Ga);
    float2 Yb = cmul(Bv, Gb);
    rows[rA*RST + pidx(pA)] = make_float2(Ya.x - Yb.y, Ya.y + Yb.x);    // Zout(k)  = Ya + i*Yb
    rows[rB*RST + pidx(pB)] = make_float2(Ya.x + Yb.y, Yb.x - Ya.y);    // Zout(-k) = conj(Ya)+i*conj(Yb)
  };

  int ncomb = last ? 1536 : 2048;
  for (int i = t; i < ncomb; i += 256) {
    int s = i >> 9, p = i & 511;
    int j = bx*4 + s;
    combine(2*s, p, 2*s + 1, p ^ 511, rev3(j + 1));
  }
  if (last) {
    // row 6: k2=0 (q=0), self-paired with pperm = rev3((512-rev3(p))&511)
    for (int p = t; p < 512; p += 256) {
      int pp = rev3((512 - rev3(p)) & 511);
      if (p <= pp) combine(6, p, 6, pp, 0);
    }
    // row 7: k2=256 (q=4), self-paired with pperm = p^511
    if (t < 256) combine(7, t, 7, t ^ 511, 4);
  }
  __syncthreads();

  #pragma unroll
  for (int g = 0; g < ROWS/4; ++g)
    fft512_inv(&rows[((g<<2)+wid)*RST], lane, w512);
  __syncthreads();
  for (int i = t; i < ROWS*512; i += 256) {
    int r = i >> 9, n1 = i & 511;
    int s = r >> 1, which = r & 1;
    int j = bx*4 + s;
    int k2 = (j == 255) ? (which ? 256 : 0) : (which ? 511 - j : j + 1);
    int q = rev3(k2);
    Xe[(size_t)q*512 + n1] = pkh(cmulc(rows[r*RST + pidx(n1)], wtw((n1*k2) & (MFT-1))));
  }
}

// pass C: inverse column FFT (truncated — only n2<256 consumed);
// Re -> event 2p (shift a), Im -> event 2p+1 (shift b)
__global__ __launch_bounds__(256) void k_passC2(const __half2* __restrict__ Xb,
                                                float* __restrict__ dout,
                                                const float2* __restrict__ w512g,
                                                const int* __restrict__ shiftA,
                                                int e0) {
  __shared__ float2 w512[512];
  __shared__ float2 tile[COLS*CST];
  int t = threadIdx.x;
  for (int i = t; i < 512; i += 256) w512[i] = w512g[i];
  const __half2* Xe = Xb + (size_t)blockIdx.y * MFT;
  int c0 = blockIdx.x * COLS;
  for (int i = t; i < 512*COLS; i += 256) {
    int cc = i & (COLS-1), q = i >> 3;
    tile[cc*CST + pidx(q)] = uph(Xe[c0 + cc + ((size_t)q<<9)]);
  }
  __syncthreads();
  int wid = t >> 6, lane = t & 63;
  #pragma unroll
  for (int g = 0; g < COLS/4; ++g)
    fft512_inv_trunc(&tile[((g<<2) + wid)*CST], lane, w512);
  __syncthreads();
  int na = e0 + 2*blockIdx.y, nb = na + 1;
  int sha = shiftA[na], shb = shiftA[nb];
  float* dpa = dout + (size_t)na*NSMP;
  float* dpb = dout + (size_t)nb*NSMP;
  for (int i = t; i < 256*COLS; i += 256) {   // only p < NS needed (n2 < 256)
    int cc = i & (COLS-1), n2 = i >> 3;
    int p = c0 + cc + (n2<<9);
    float2 y = tile[cc*CST + pidx(n2)];
    int oa = p + sha;
    if (oa < NSMP) dpa[oa] = y.x;
    int ob = p + shb;
    if (ob < NSMP) dpb[ob] = y.y;
  }
}

} // namespace

extern "C" void kernel_launch(void* const* d_in, const int* in_sizes, int n_in,
                              void* d_out, int out_size, void* d_ws, size_t ws_size,
                              hipStream_t stream) {
  (void)in_sizes; (void)n_in;
  const float* voice  = (const float*)d_in[0];
  const float* cpc    = (const float*)d_in[1];
  const float* amps   = (const float*)d_in[2];
  const float* room   = (const float*)d_in[3];
  const float* rmix   = (const float*)d_in[4];
  const float* times  = (const float*)d_in[5];
  const float* cp_tab = (const float*)d_in[6];
  const float* verbs  = (const float*)d_in[7];
  const float* w_in   = (const float*)d_in[8];
  const float* w_ih   = (const float*)d_in[9];
  const float* w_hh   = (const float*)d_in[10];
  const float* w_out  = (const float*)d_in[11];
  float* out = (float*)d_out;

  char* base = (char*)d_ws;
  size_t off = 0;
  auto carve = [&](size_t bytes) -> void* {
    void* p = base + off;
    off = (off + bytes + 255) & ~(size_t)255;
    return p;
  };
  float*   sig   = (float*)  carve((size_t)NEV*NSMP*4);   // 64 MB
  float2*  w512g = (float2*) carve((size_t)512*8);        // 4 KB compact twiddles
  __half2* spec  = (__half2*)carve((size_t)16*MFT*4);     // 16 MB (verb spectra, fp16)
  int*   vidx  = (int*)  carve(NEV*4);
  int*   cpidx = (int*)  carve(NEV*4);
  int*   ridx  = (int*)  carve(NEV*4);
  int*   shf   = (int*)  carve(NEV*4);
  float* m0    = (float*)carve(NEV*4);
  float* m1    = (float*)carve(NEV*4);
  float* amp   = (float*)carve(NEV*4);

  // GEMM-phase temporaries alias the spec region (13.3 MB < 16 MB); verb
  // spectra are computed AFTER k_gemm_mfma, when these are all dead.
  size_t toff = (size_t)((char*)spec - base);
  auto carveT = [&](size_t bytes) -> void* {
    void* p = base + toff;
    toff = (toff + bytes + 255) & ~(size_t)255;
    return p;
  };
  float*          mred  = (float*)         carveT((size_t)8*128*16*4);
  float*          ctrl  = (float*)         carveT((size_t)NEV*2048*4);
  unsigned short* hs_hi = (unsigned short*)carveT((size_t)NEV*128*128*2);
  unsigned short* hs_lo = (unsigned short*)carveT((size_t)NEV*128*128*2);
  unsigned short* wo_hi = (unsigned short*)carveT((size_t)8*1024*128*2);
  unsigned short* wo_lo = (unsigned short*)carveT((size_t)8*1024*128*2);

  __half2* X = (__half2*)(base + off);
  size_t rem = (ws_size > off) ? (ws_size - off) : 0;
  int C = (int)(rem / ((size_t)MFT*4));     // chunk size in PAIRS (fp16 X)
  if (C > NPAIR) C = NPAIR;
  if (C < 1) C = 1;

  hipMemsetAsync(d_out, 0, (size_t)out_size*sizeof(float), stream);

  k_params<<<NEV, 64, 0, stream>>>(voice, cpc, amps, room, rmix, times,
                                   vidx, cpidx, ridx, shf, m0, m1, amp);
  k_w512<<<2, 256, 0, stream>>>(w512g);
  k_mred<<<dim3(128, 8), 64, 0, stream>>>(w_ih, w_in, mred);
  k_topk<<<NEV, 256, 0, stream>>>(cp_tab, cpidx, ctrl);
  k_rnn<<<NEV, 512, 0, stream>>>(ctrl, mred, w_hh, vidx, hs_hi, hs_lo);
  k_wsplit<<<(8*1024*128)/256, 256, 0, stream>>>(w_out, wo_hi, wo_lo, 8*1024*128);
  k_gemm_mfma<<<dim3(8, NEV), 256, 0, stream>>>(hs_hi, hs_lo, wo_hi, wo_lo, vidx, sig);

  // verb spectra: unpacked forward pipeline (must run after k_gemm_mfma —
  // temporaries above alias this region)
  k_passA<<<dim3(64, 16), 256, 0, stream>>>(verbs, spec, w512g);
  k_passBv<<<dim3(64, 16), 256, 0, stream>>>(spec, w512g);

  // main conv: 2 real events packed per complex FFT pipeline
  for (int p0 = 0; p0 < NPAIR; p0 += C) {
    int cp = (NPAIR - p0 < C) ? (NPAIR - p0) : C;
    k_passA2<<<dim3(64, cp), 256, 0, stream>>>(sig + (size_t)p0*2*NSMP, X, w512g);
    k_passB2<<<dim3(64, cp), 256, 0, stream>>>(X, spec, w512g, ridx, m0, m1, amp, 2*p0);
    k_passC2<<<dim3(64, cp), 256, 0, stream>>>(X, out, w512g, shf, 2*p0);
  }
}

// Round 15
// 414.998 us; speedup vs baseline: 1.1002x; 1.0059x over previous
//
#include <hip/hip_runtime.h>
#include <hip/hip_fp16.h>
#include <math.h>

namespace {

constexpr int NSMP = 131072;   // n_samples
constexpr int NEV  = 128;      // B*E events
constexpr int NPAIR = NEV/2;   // packed complex pipelines
constexpr int MFT  = 262144;   // 2*NS FFT size = 512*512
constexpr int COLS = 8;        // cols per pass A/C block
constexpr int ROWS = 8;        // rows per pass B block
constexpr int RST  = 576;      // padded row stride (pass B): pidx(511)=574 < 576
constexpr int CST  = 578;      // padded col stride (pass A/C)

typedef __attribute__((ext_vector_type(8))) short short8;
typedef __attribute__((ext_vector_type(4))) float f32x4;

__device__ __forceinline__ float2 cadd(float2 a, float2 b){ return make_float2(a.x+b.x, a.y+b.y); }
__device__ __forceinline__ float2 csub(float2 a, float2 b){ return make_float2(a.x-b.x, a.y-b.y); }
__device__ __forceinline__ float2 cmul(float2 a, float2 b){ return make_float2(a.x*b.x - a.y*b.y, a.x*b.y + a.y*b.x); }
__device__ __forceinline__ float2 cmulc(float2 a, float2 b){ return make_float2(a.x*b.x + a.y*b.y, a.y*b.x - a.x*b.y); }
__device__ __forceinline__ int rev3(int x){ return ((x&7)<<6) | (x&56) | (x>>6); }  // base-8 digit reversal, 9 bits
// bank-conflict-breaking pad: one extra float2 per 8 (stage3 32-way -> 4-way)
__device__ __forceinline__ int pidx(int i){ return i + (i>>3); }

// fp16 pack/unpack for the global spectral intermediates (compute stays fp32)
__device__ __forceinline__ __half2 pkh(float2 v){ return __floats2half2_rn(v.x, v.y); }
__device__ __forceinline__ float2 uph(__half2 h){ return __half22float2(h); }

// computed big twiddle: W_MFT^idx = (cos, sin) of -2*pi*idx/MFT — replaces the
// uncoalesced wbig gather (64 distinct cache lines per wave) with 2 trans ops.
__device__ __forceinline__ float2 wtw(int idx) {
  float ang = (float)idx * (-6.283185307179586f / (float)MFT);
  float sn, cs;
  __sincosf(ang, &sn, &cs);
  return make_float2(cs, sn);
}

// round-to-nearest-even f32 -> bf16 (values here are always finite)
__device__ __forceinline__ unsigned short f2bf(float x) {
  unsigned u = __float_as_uint(x);
  unsigned r = (u + 0x7FFFu + ((u >> 16) & 1u)) >> 16;
  return (unsigned short)r;
}
__device__ __forceinline__ float bf2f(unsigned short h) {
  return __uint_as_float(((unsigned)h) << 16);
}

// 8-point DFT: out[k] = sum_j in[j] * exp(SGN*2*pi*i*j*k/8)
template<int SGN>
__device__ __forceinline__ void fft8v(float2* u) {
  const float S2 = 0.70710678118654752440f;
  float2 a0 = cadd(u[0], u[4]), a1 = csub(u[0], u[4]);
  float2 a2 = cadd(u[2], u[6]), a3 = csub(u[2], u[6]);
  float2 b0 = cadd(u[1], u[5]), b1 = csub(u[1], u[5]);
  float2 b2 = cadd(u[3], u[7]), b3 = csub(u[3], u[7]);
  float2 a3r = (SGN < 0) ? make_float2(a3.y, -a3.x) : make_float2(-a3.y, a3.x);
  float2 b3r = (SGN < 0) ? make_float2(b3.y, -b3.x) : make_float2(-b3.y, b3.x);
  float2 E0 = cadd(a0, a2), E2 = csub(a0, a2);
  float2 E1 = cadd(a1, a3r), E3 = csub(a1, a3r);
  float2 O0 = cadd(b0, b2), O2 = csub(b0, b2);
  float2 O1 = cadd(b1, b3r), O3 = csub(b1, b3r);
  const float sg = (SGN < 0) ? -1.f : 1.f;
  O1 = cmul(O1, make_float2(S2, sg*S2));
  O2 = (SGN < 0) ? make_float2(O2.y, -O2.x) : make_float2(-O2.y, O2.x);
  O3 = cmul(O3, make_float2(-S2, sg*S2));
  u[0] = cadd(E0, O0); u[4] = csub(E0, O0);
  u[1] = cadd(E1, O1); u[5] = csub(E1, O1);
  u[2] = cadd(E2, O2); u[6] = csub(E2, O2);
  u[3] = cadd(E3, O3); u[7] = csub(E3, O3);
}

// Stages 2+3 of the forward 512-pt DIF (shared by full and zero-padded heads).
__device__ __forceinline__ void fft512_fwd_tail(float2* X, int lane, const float2* w512) {
  float2 u[8];
  {
    int b = (lane>>3)<<6, m = lane&7;
    #pragma unroll
    for (int j = 0; j < 8; ++j) u[j] = X[pidx(b + (j<<3) + m)];
    fft8v<-1>(u);
    #pragma unroll
    for (int r = 1; r < 8; ++r) u[r] = cmul(u[r], w512[((m*r)<<3) & 511]);
    #pragma unroll
    for (int r = 0; r < 8; ++r) X[pidx(b + (r<<3) + m)] = u[r];
  }
  {
    int c = lane<<3;
    #pragma unroll
    for (int j = 0; j < 8; ++j) u[j] = X[pidx(c + j)];
    fft8v<-1>(u);
    #pragma unroll
    for (int r = 0; r < 8; ++r) X[pidx(c + r)] = u[r];
  }
}

// In-place 512-pt forward DIF (natural in -> base-8 digit-reversed out).
// X points at a contiguous padded transform: element i lives at X[pidx(i)].
// One wave (lane 0..63) per transform. The transform's LDS region is
// WAVE-PRIVATE: same-wave LDS ops are processed in order (lgkmcnt), so NO
// barriers are needed inside — callers barrier only at cross-wave phases.
__device__ void fft512_fwd(float2* X, int lane, const float2* w512) {
  float2 u[8];
  #pragma unroll
  for (int j = 0; j < 8; ++j) u[j] = X[pidx((j<<6) + lane)];
  fft8v<-1>(u);
  #pragma unroll
  for (int r = 1; r < 8; ++r) u[r] = cmul(u[r], w512[(lane*r) & 511]);
  #pragma unroll
  for (int r = 0; r < 8; ++r) X[pidx((r<<6) + lane)] = u[r];
  fft512_fwd_tail(X, lane, w512);
}

// Zero-padded variant: elements 256..511 are known zero (never read — callers
// stage only the lower half). Stage-1 butterfly specialized for u[4..7] == 0.
__device__ void fft512_fwd_zpad(float2* X, int lane, const float2* w512) {
  const float S2 = 0.70710678118654752440f;
  float2 u[8];
  #pragma unroll
  for (int j = 0; j < 4; ++j) u[j] = X[pidx((j<<6) + lane)];
  {
    float2 a0 = u[0], a1 = u[0], a2 = u[2], a3 = u[2];
    float2 b0 = u[1], b1 = u[1], b2 = u[3], b3 = u[3];
    float2 a3r = make_float2(a3.y, -a3.x);
    float2 b3r = make_float2(b3.y, -b3.x);
    float2 E0 = cadd(a0, a2), E2 = csub(a0, a2);
    float2 E1 = cadd(a1, a3r), E3 = csub(a1, a3r);
    float2 O0 = cadd(b0, b2), O2 = csub(b0, b2);
    float2 O1 = cadd(b1, b3r), O3 = csub(b1, b3r);
    O1 = cmul(O1, make_float2(S2, -S2));
    O2 = make_float2(O2.y, -O2.x);
    O3 = cmul(O3, make_float2(-S2, -S2));
    u[0] = cadd(E0, O0); u[4] = csub(E0, O0);
    u[1] = cadd(E1, O1); u[5] = csub(E1, O1);
    u[2] = cadd(E2, O2); u[6] = csub(E2, O2);
    u[3] = cadd(E3, O3); u[7] = csub(E3, O3);
  }
  #pragma unroll
  for (int r = 1; r < 8; ++r) u[r] = cmul(u[r], w512[(lane*r) & 511]);
  #pragma unroll
  for (int r = 0; r < 8; ++r) X[pidx((r<<6) + lane)] = u[r];
  fft512_fwd_tail(X, lane, w512);
}

// Stages 1+2 of the inverse (shared by full and truncated-output variants).
__device__ __forceinline__ void fft512_inv_head(float2* X, int lane, const float2* w512) {
  float2 u[8];
  {
    int c = lane<<3;
    #pragma unroll
    for (int r = 0; r < 8; ++r) u[r] = X[pidx(c + r)];
    fft8v<1>(u);
    #pragma unroll
    for (int j = 0; j < 8; ++j) X[pidx(c + j)] = u[j];
  }
  {
    int b = (lane>>3)<<6, m = lane&7;
    #pragma unroll
    for (int r = 0; r < 8; ++r) u[r] = X[pidx(b + (r<<3) + m)];
    #pragma unroll
    for (int r = 1; r < 8; ++r) u[r] = cmulc(u[r], w512[((m*r)<<3) & 511]);
    fft8v<1>(u);
    #pragma unroll
    for (int j = 0; j < 8; ++j) X[pidx(b + (j<<3) + m)] = u[j];
  }
}

// In-place 512-pt inverse (transpose-conjugate of fwd): digit-reversed in -> natural out.
// Unnormalized. Barrier-free (wave-private region), as above.
__device__ void fft512_inv(float2* X, int lane, const float2* w512) {
  fft512_inv_head(X, lane, w512);
  float2 u[8];
  #pragma unroll
  for (int r = 0; r < 8; ++r) u[r] = X[pidx((r<<6) + lane)];
  #pragma unroll
  for (int r = 1; r < 8; ++r) u[r] = cmulc(u[r], w512[(lane*r) & 511]);
  fft8v<1>(u);
  #pragma unroll
  for (int j = 0; j < 8; ++j) X[pidx((j<<6) + lane)] = u[j];
}

// Truncated-output variant: only natural outputs 0..255 are consumed (pass C
// keeps n2 < 256); skip the upper-half final stores.
__device__ void fft512_inv_trunc(float2* X, int lane, const float2* w512) {
  fft512_inv_head(X, lane, w512);
  float2 u[8];
  #pragma unroll
  for (int r = 0; r < 8; ++r) u[r] = X[pidx((r<<6) + lane)];
  #pragma unroll
  for (int r = 1; r < 8; ++r) u[r] = cmulc(u[r], w512[(lane*r) & 511]);
  fft8v<1>(u);
  #pragma unroll
  for (int j = 0; j < 4; ++j) X[pidx((j<<6) + lane)] = u[j];
}

// -------- per-event scalar params (argmaxes, softmax mix, |amp|) --------
__global__ void k_params(const float* __restrict__ voice, const float* __restrict__ cpc,
                         const float* __restrict__ amps, const float* __restrict__ room,
                         const float* __restrict__ rmix, const float* __restrict__ times,
                         int* __restrict__ vidx, int* __restrict__ cpidx, int* __restrict__ ridx,
                         int* __restrict__ shiftA, float* __restrict__ m0, float* __restrict__ m1,
                         float* __restrict__ amp) {
  int n = blockIdx.x, t = threadIdx.x;
  if (t == 0) {
    const float* p = voice + n*8; int bi = 0; float bv = p[0];
    for (int i = 1; i < 8; ++i) if (p[i] > bv) { bv = p[i]; bi = i; }
    vidx[n] = bi;
  } else if (t == 1) {
    const float* p = cpc + n*512; int bi = 0; float bv = p[0];
    for (int i = 1; i < 512; ++i) if (p[i] > bv) { bv = p[i]; bi = i; }
    cpidx[n] = bi;
  } else if (t == 2) {
    const float* p = room + n*16; int bi = 0; float bv = p[0];
    for (int i = 1; i < 16; ++i) if (p[i] > bv) { bv = p[i]; bi = i; }
    ridx[n] = bi;
  } else if (t == 3) {
    const float* p = times + n*128; int bi = 0; float bv = p[0];
    for (int i = 1; i < 128; ++i) if (p[i] > bv) { bv = p[i]; bi = i; }
    shiftA[n] = bi * 1024;
  } else if (t == 4) {
    float a = rmix[n*2], b = rmix[n*2+1];
    float mx = fmaxf(a, b);
    float ea = __expf(a - mx), eb = __expf(b - mx);
    float inv = 1.f / (ea + eb);
    m0[n] = ea * inv; m1[n] = eb * inv;
    amp[n] = fabsf(amps[n]);
  }
}

// -------- compact 512-pt twiddle table: w512g[i] = exp(-2 pi i/512 * i) --------
__global__ void k_w512(float2* __restrict__ w512g) {
  int i = blockIdx.x * blockDim.x + threadIdx.x;
  if (i < 512) {
    double a = -2.0 * 3.14159265358979323846 * (double)(i * 512) / (double)MFT;
    w512g[i] = make_float2((float)cos(a), (float)sin(a));
  }
}

// -------- M[v] = w_ih[v] @ w_in[v]  -> [8][128][16] --------
__global__ void k_mred(const float* __restrict__ w_ih, const float* __restrict__ w_in,
                       float* __restrict__ mred) {
  int h = blockIdx.x, v = blockIdx.y, t = threadIdx.x;
  const float* ih = w_ih + ((size_t)v*128 + h)*1024;
  const float* wi = w_in + (size_t)v*1024*16;
  float acc[16];
  #pragma unroll
  for (int c = 0; c < 16; ++c) acc[c] = 0.f;
  for (int w = t; w < 1024; w += 64) {
    float a = ih[w];
    const float4* wr = (const float4*)(wi + (size_t)w*16);
    float4 q0 = wr[0], q1 = wr[1], q2 = wr[2], q3 = wr[3];
    acc[0] += a*q0.x; acc[1] += a*q0.y; acc[2] += a*q0.z; acc[3] += a*q0.w;
    acc[4] += a*q1.x; acc[5] += a*q1.y; acc[6] += a*q1.z; acc[7] += a*q1.w;
    acc[8] += a*q2.x; acc[9] += a*q2.y; acc[10]+= a*q2.z; acc[11]+= a*q2.w;
    acc[12]+= a*q3.x; acc[13]+= a*q3.y; acc[14]+= a*q3.z; acc[15]+= a*q3.w;
  }
  #pragma unroll
  for (int c = 0; c < 16; ++c) {
    float s = acc[c];
    for (int o = 32; o > 0; o >>= 1) s += __shfl_down(s, o);
    if (t == 0) mred[((size_t)v*128 + h)*16 + c] = s;
  }
}

// -------- exact top-128 of selected cp_table row (2048 vals), relu, ties by lowest index --------
__global__ __launch_bounds__(256) void k_topk(const float* __restrict__ cp_table,
                                              const int* __restrict__ cpidx,
                                              float* __restrict__ ctrl) {
  __shared__ int redw[4];
  __shared__ int scanbuf[256];
  int n = blockIdx.x, t = threadIdx.x;
  const float* row = cp_table + (size_t)cpidx[n]*2048;
  float f[8]; unsigned v[8];
  #pragma unroll
  for (int i = 0; i < 8; ++i) { f[i] = row[t*8 + i]; v[i] = __float_as_uint(f[i]); }
  int lane = t & 63, wid = t >> 6;
  unsigned thr = 0;
  for (int b = 31; b >= 0; --b) {  // values are >=0, bit pattern is order-preserving
    unsigned cand = thr | (1u << b);
    int c = 0;
    #pragma unroll
    for (int i = 0; i < 8; ++i) c += (v[i] >= cand);
    for (int o = 32; o > 0; o >>= 1) c += __shfl_down(c, o);
    if (lane == 0) redw[wid] = c;
    __syncthreads();
    int tot = redw[0] + redw[1] + redw[2] + redw[3];
    if (tot >= 128) thr = cand;
    __syncthreads();
  }
  int g = 0, eq = 0;
  #pragma unroll
  for (int i = 0; i < 8; ++i) { g += (v[i] > thr); eq += (v[i] == thr); }
  int gw = g;
  for (int o = 32; o > 0; o >>= 1) gw += __shfl_down(gw, o);
  if (lane == 0) redw[wid] = gw;
  scanbuf[t] = eq;
  __syncthreads();
  int G = redw[0] + redw[1] + redw[2] + redw[3];
  int extra = 128 - G;
  int incl = eq;
  for (int o = 1; o < 256; o <<= 1) {
    int add = (t >= o) ? scanbuf[t - o] : 0;
    __syncthreads();
    incl += add;
    scanbuf[t] = incl;
    __syncthreads();
  }
  int rank = incl - eq;
  float* outp = ctrl + (size_t)n*2048;
  #pragma unroll
  for (int i = 0; i < 8; ++i) {
    bool keep = (v[i] > thr) || ((v[i] == thr) && (rank < extra));
    if (v[i] == thr) rank++;
    outp[t*8 + i] = keep ? fmaxf(f[i], 0.f) : 0.f;
  }
}

// -------- 128-step tanh RNN, one block per event --------
// 512 threads: thread (i = t>>2, s = t&3) owns Whh[i][32s:32s+32] in VGPRs.
// Per-s-quarter ROTATED read order: slot j accesses element (j+2s)&7 of the
// slice, so the 4 quarters' concurrent ds_read_b128 addresses hit DISTINCT
// bank groups (4-way same-bank replay -> conflict-free). whh is loaded
// pre-rotated so register indexing stays static.
__global__ __launch_bounds__(512) void k_rnn(const float* __restrict__ ctrl,
                                             const float* __restrict__ mred,
                                             const float* __restrict__ w_hh,
                                             const int* __restrict__ vidx,
                                             unsigned short* __restrict__ hs_hi,
                                             unsigned short* __restrict__ hs_lo) {
  __shared__ __align__(16) float h_s[2][128];
  __shared__ float ctrl_s[2048];
  __shared__ float cin_s[128*128];   // cin[st][i] = sum_c M[i][c]*ctrl[c][st]
  int n = blockIdx.x, t = threadIdx.x;
  int i = t >> 2, s = t & 3;
  int v = vidx[n];
  int rot = s << 1;

  // Whh quarter into VGPRs, pre-rotated: whh[j] pairs with h slice elem (j+rot)&7
  const float4* whhrow = (const float4*)(w_hh + ((size_t)v*128 + i)*128 + 32*s);
  float4 whh[8];
  #pragma unroll
  for (int j = 0; j < 8; ++j) whh[j] = whhrow[(j + rot) & 7];

  for (int k = t; k < 2048; k += 512) ctrl_s[k] = ctrl[(size_t)n*2048 + k];
  if (s == 0) { h_s[0][i] = 0.f; }
  __syncthreads();

  // precompute cin[st][i] for all steps (parallel, off the critical path)
  {
    int ii = t & 127, stq = t >> 7;   // thread -> output ii, step-quarter stq
    const float4* mrow = (const float4*)(mred + ((size_t)v*128 + ii)*16);
    float4 m0q = mrow[0], m1q = mrow[1], m2q = mrow[2], m3q = mrow[3];
    #pragma unroll 4
    for (int st0 = 0; st0 < 32; ++st0) {
      int st = stq*32 + st0;
      float a = 0.f, b = 0.f;
      a += m0q.x*ctrl_s[(0<<7)+st];  b += m0q.y*ctrl_s[(1<<7)+st];
      a += m0q.z*ctrl_s[(2<<7)+st];  b += m0q.w*ctrl_s[(3<<7)+st];
      a += m1q.x*ctrl_s[(4<<7)+st];  b += m1q.y*ctrl_s[(5<<7)+st];
      a += m1q.z*ctrl_s[(6<<7)+st];  b += m1q.w*ctrl_s[(7<<7)+st];
      a += m2q.x*ctrl_s[(8<<7)+st];  b += m2q.y*ctrl_s[(9<<7)+st];
      a += m2q.z*ctrl_s[(10<<7)+st]; b += m2q.w*ctrl_s[(11<<7)+st];
      a += m3q.x*ctrl_s[(12<<7)+st]; b += m3q.y*ctrl_s[(13<<7)+st];
      a += m3q.z*ctrl_s[(14<<7)+st]; b += m3q.w*ctrl_s[(15<<7)+st];
      cin_s[(st<<7) + ii] = a + b;
    }
  }
  __syncthreads();

  unsigned short* hi_out = hs_hi + (size_t)n*16384;
  unsigned short* lo_out = hs_lo + (size_t)n*16384;
  int p = 0;
  for (int grp = 0; grp < 16; ++grp) {
    unsigned short hbuf[8];
    #pragma unroll
    for (int k = 0; k < 8; ++k) {
      int st = grp*8 + k;
      const float4* hp = (const float4*)(&h_s[p][0]) + 8*s;
      float cin = cin_s[(st<<7) + i];
      float a0 = 0.f, a1 = 0.f;
      #pragma unroll
      for (int j = 0; j < 8; ++j) {
        float4 h4 = hp[(j + rot) & 7];   // rotated LDS read (conflict-free)
        float4 w4 = whh[j];              // static register index
        if (j & 1) a1 += w4.x*h4.x + w4.y*h4.y + w4.z*h4.z + w4.w*h4.w;
        else       a0 += w4.x*h4.x + w4.y*h4.y + w4.z*h4.z + w4.w*h4.w;
      }
      float acc = a0 + a1;
      acc += __shfl_xor(acc, 1);
      acc += __shfl_xor(acc, 2);
      acc += cin;
      float ax = fabsf(acc);
      float e = __expf(2.f*ax);
      float hn = copysignf(1.f - 2.f/(e + 1.f), acc);  // tanh, stable both tails
      unsigned short h = f2bf(hn);
      if (s == 0) {
        h_s[p^1][i] = hn;
        hbuf[k] = h;
      } else if (s == 1) {
        hbuf[k] = f2bf(hn - bf2f(h));
      }
      __syncthreads();
      p ^= 1;
    }
    // batched global stores — drained at the next group's first barrier
    if (s == 0) {
      #pragma unroll
      for (int k = 0; k < 8; ++k) hi_out[((grp*8 + k)<<7) + i] = hbuf[k];
    } else if (s == 1) {
      #pragma unroll
      for (int k = 0; k < 8; ++k) lo_out[((grp*8 + k)<<7) + i] = hbuf[k];
    }
  }
}

// -------- split w_out into bf16 hi/lo --------
__global__ void k_wsplit(const float* __restrict__ w, unsigned short* __restrict__ hi,
                         unsigned short* __restrict__ lo, int nelem) {
  int i = blockIdx.x * blockDim.x + threadIdx.x;
  if (i < nelem) {
    float x = w[i];
    unsigned short h = f2bf(x);
    hi[i] = h;
    lo[i] = f2bf(x - bf2f(h));
  }
}

// -------- sig = sin(hs @ w_out^T) via split-bf16 MFMA --------
__global__ __launch_bounds__(256) void k_gemm_mfma(
    const unsigned short* __restrict__ hs_hi, const unsigned short* __restrict__ hs_lo,
    const unsigned short* __restrict__ wo_hi, const unsigned short* __restrict__ wo_lo,
    const int* __restrict__ vidx, float* __restrict__ sig) {
  int n = blockIdx.y;
  int v = vidx[n];
  int t = threadIdx.x;
  int lane = t & 63, wave = t >> 6;
  int wm = wave >> 1, wn = wave & 1;
  int m_base = wm * 64;
  int n_base = blockIdx.x * 128 + wn * 64;
  int lrow = lane & 15;
  int lk = (lane >> 4) << 3;

  const unsigned short* Ah = hs_hi + (size_t)n * 16384;
  const unsigned short* Al = hs_lo + (size_t)n * 16384;
  const unsigned short* Bh = wo_hi + (size_t)v * 131072;
  const unsigned short* Bl = wo_lo + (size_t)v * 131072;

  f32x4 acc[4][4];
  #pragma unroll
  for (int i = 0; i < 4; ++i)
    #pragma unroll
    for (int j = 0; j < 4; ++j) acc[i][j] = (f32x4){0.f, 0.f, 0.f, 0.f};

  #pragma unroll
  for (int ks = 0; ks < 128; ks += 32) {
    short8 ah[4], al[4], bh[4], bl[4];
    #pragma unroll
    for (int mt = 0; mt < 4; ++mt) {
      size_t o = (size_t)(m_base + mt*16 + lrow) * 128 + ks + lk;
      ah[mt] = *(const short8*)(Ah + o);
      al[mt] = *(const short8*)(Al + o);
    }
    #pragma unroll
    for (int nt = 0; nt < 4; ++nt) {
      size_t o = (size_t)(n_base + nt*16 + lrow) * 128 + ks + lk;
      bh[nt] = *(const short8*)(Bh + o);
      bl[nt] = *(const short8*)(Bl + o);
    }
    #pragma unroll
    for (int mt = 0; mt < 4; ++mt)
      #pragma unroll
      for (int nt = 0; nt < 4; ++nt) {
        acc[mt][nt] = __builtin_amdgcn_mfma_f32_16x16x32_bf16(ah[mt], bh[nt], acc[mt][nt], 0, 0, 0);
        acc[mt][nt] = __builtin_amdgcn_mfma_f32_16x16x32_bf16(ah[mt], bl[nt], acc[mt][nt], 0, 0, 0);
        acc[mt][nt] = __builtin_amdgcn_mfma_f32_16x16x32_bf16(al[mt], bh[nt], acc[mt][nt], 0, 0, 0);
      }
  }

  // C/D layout: col = lane&15, row = (lane>>4)*4 + reg
  float* dst = sig + (size_t)n * NSMP;
  int drow = (lane >> 4) << 2, dcol = lane & 15;
  #pragma unroll
  for (int mt = 0; mt < 4; ++mt)
    #pragma unroll
    for (int nt = 0; nt < 4; ++nt)
      #pragma unroll
      for (int r = 0; r < 4; ++r) {
        int m = m_base + mt*16 + drow + r;
        int nn = n_base + nt*16 + dcol;
        dst[(size_t)m * 1024 + nn] = __sinf(acc[mt][nt][r]);
      }
}

// -------- FFT pass A (real, unpacked — verbs): column FFT-512 over n2 --------
__global__ __launch_bounds__(256) void k_passA(const float* __restrict__ in,
                                               __half2* __restrict__ outb,
                                               const float2* __restrict__ w512g) {
  __shared__ float2 w512[512];
  __shared__ float2 tile[COLS*CST];
  int t = threadIdx.x;
  for (int i = t; i < 512; i += 256) w512[i] = w512g[i];
  const float* src = in + (size_t)blockIdx.y * NSMP;
  __half2* dst = outb + (size_t)blockIdx.y * MFT;
  int c0 = blockIdx.x * COLS;
  for (int i = t; i < 256*COLS; i += 256) {   // stage only nonzero lower half
    int cc = i & (COLS-1), n2 = i >> 3;
    tile[cc*CST + pidx(n2)] = make_float2(src[c0 + cc + (n2<<9)], 0.f);
  }
  __syncthreads();
  int wid = t >> 6, lane = t & 63;
  #pragma unroll
  for (int g = 0; g < COLS/4; ++g)
    fft512_fwd_zpad(&tile[((g<<2) + wid)*CST], lane, w512);
  __syncthreads();
  for (int i = t; i < 512*COLS; i += 256) {
    int cc = i & (COLS-1), q = i >> 3;
    dst[c0 + cc + (q<<9)] = pkh(tile[cc*CST + pidx(q)]);
  }
}

// -------- FFT pass B forward-only (verb spectra) --------
__global__ __launch_bounds__(256) void k_passBv(__half2* __restrict__ Xb,
                                                const float2* __restrict__ w512g) {
  __shared__ float2 w512[512];
  __shared__ float2 rows[ROWS*RST];
  int t = threadIdx.x;
  for (int i = t; i < 512; i += 256) w512[i] = w512g[i];
  __half2* Xe = Xb + (size_t)blockIdx.y * MFT;
  int q0 = blockIdx.x * ROWS;
  for (int i = t; i < ROWS*512; i += 256) {
    int r = i >> 9, n1 = i & 511;
    int q = q0 + r;
    int k2 = rev3(q);
    rows[r*RST + pidx(n1)] = cmul(uph(Xe[(size_t)q*512 + n1]), wtw((n1*k2) & (MFT-1)));
  }
  __syncthreads();
  int wid = t >> 6, lane = t & 63;
  #pragma unroll
  for (int g = 0; g < ROWS/4; ++g)
    fft512_fwd(&rows[((g<<2)+wid)*RST], lane, w512);
  __syncthreads();
  for (int i = t; i < ROWS*512; i += 256) {
    int r = i >> 9, n1 = i & 511;
    Xe[(size_t)(q0 + r)*512 + n1] = pkh(rows[r*RST + pidx(n1)]);
  }
}

// ======== packed (2 real events per complex FFT) conv pipeline ========

// pass A: z = sig[2p] + i*sig[2p+1], column FFT-512 (upper half zero-padded)
__global__ __launch_bounds__(256) void k_passA2(const float* __restrict__ in,
                                                __half2* __restrict__ outb,
                                                const float2* __restrict__ w512g) {
  __shared__ float2 w512[512];
  __shared__ float2 tile[COLS*CST];
  int t = threadIdx.x;
  for (int i = t; i < 512; i += 256) w512[i] = w512g[i];
  const float* src = in + (size_t)blockIdx.y * 2 * NSMP;
  __half2* dst = outb + (size_t)blockIdx.y * MFT;
  int c0 = blockIdx.x * COLS;
  for (int i = t; i < 256*COLS; i += 256) {   // stage only nonzero lower half
    int cc = i & (COLS-1), n2 = i >> 3;
    int o = c0 + cc + (n2<<9);
    tile[cc*CST + pidx(n2)] = make_float2(src[o], src[o + NSMP]);
  }
  __syncthreads();
  int wid = t >> 6, lane = t & 63;
  #pragma unroll
  for (int g = 0; g < COLS/4; ++g)
    fft512_fwd_zpad(&tile[((g<<2) + wid)*CST], lane, w512);
  __syncthreads();
  for (int i = t; i < 512*COLS; i += 256) {
    int cc = i & (COLS-1), q = i >> 3;
    dst[c0 + cc + (q<<9)] = pkh(tile[cc*CST + pidx(q)]);
  }
}

// pass B: row FFT of conjugate-paired rows, Hermitian split, per-event reverb
// multiply, recombine, inverse row FFT. Block = 4 row-pair slots.
// slot j (global): j<255 -> k2A=j+1, k2B=511-j; j==255 -> self rows k2=0 and k2=256.
// Within rows (k2!=0): partner position of p is p^511; row k2=0: rev3((512-rev3(p))&511).
__global__ __launch_bounds__(256) void k_passB2(__half2* __restrict__ Xb,
                                                const __half2* __restrict__ spec,
                                                const float2* __restrict__ w512g,
                                                const int* __restrict__ ridx,
                                                const float* __restrict__ m0a,
                                                const float* __restrict__ m1a,
                                                const float* __restrict__ ampa,
                                                int e0) {
  __shared__ float2 w512[512];
  __shared__ float2 rows[ROWS*RST];
  int t = threadIdx.x;
  for (int i = t; i < 512; i += 256) w512[i] = w512g[i];
  __half2* Xe = Xb + (size_t)blockIdx.y * MFT;
  int bx = blockIdx.x;
  bool last = (bx == 63);

  // load + forward twiddle (computed — no uncoalesced global gather)
  for (int i = t; i < ROWS*512; i += 256) {
    int r = i >> 9, n1 = i & 511;
    int s = r >> 1, which = r & 1;
    int j = bx*4 + s;
    int k2 = (j == 255) ? (which ? 256 : 0) : (which ? 511 - j : j + 1);
    int q = rev3(k2);
    rows[r*RST + pidx(n1)] = cmul(uph(Xe[(size_t)q*512 + n1]), wtw((n1*k2) & (MFT-1)));
  }
  __syncthreads();
  int wid = t >> 6, lane = t & 63;
  #pragma unroll
  for (int g = 0; g < ROWS/4; ++g)
    fft512_fwd(&rows[((g<<2)+wid)*RST], lane, w512);
  __syncthreads();

  // per-event reverb responses
  int na = e0 + 2*blockIdx.y, nb = na + 1;
  float inv = 1.f/(float)MFT;
  float sa0 = ampa[na]*m0a[na]*inv, sa1 = ampa[na]*m1a[na]*inv;
  float sb0 = ampa[nb]*m0a[nb]*inv, sb1 = ampa[nb]*m1a[nb]*inv;
  const __half2* spa = spec + (size_t)ridx[na]*MFT;
  const __half2* spb = spec + (size_t)ridx[nb]*MFT;

  auto combine = [&](int rA, int pA, int rB, int pB, int qA) {
    float2 P = rows[rA*RST + pidx(pA)];
    float2 Q = rows[rB*RST + pidx(pB)];
    float2 A = make_float2(0.5f*(P.x + Q.x), 0.5f*(P.y - Q.y));   // spectrum of event a at k
    float2 Bv = make_float2(0.5f*(P.y + Q.y), 0.5f*(Q.x - P.x));  // spectrum of event b at k
    float2 Va = uph(spa[(size_t)qA*512 + pA]);
    float2 Vb = uph(spb[(size_t)qA*512 + pA]);
    float2 Ga = make_float2(sa0*Va.x + sa1, sa0*Va.y);
    float2 Gb = make_float2(sb0*Vb.x + sb1, sb0*Vb.y);
    float2 Ya = cmul(A, Ga);
    float2 Yb = cmul(Bv, Gb);
    rows[rA*RST + pidx(pA)] = make_float2(Ya.x - Yb.y, Ya.y + Yb.x);    // Zout(k)  = Ya + i*Yb
    rows[rB*RST + pidx(pB)] = make_float2(Ya.x + Yb.y, Yb.x - Ya.y);    // Zout(-k) = conj(Ya)+i*conj(Yb)
  };

  int ncomb = last ? 1536 : 2048;
  for (int i = t; i < ncomb; i += 256) {
    int s = i >> 9, p = i & 511;
    int j = bx*4 + s;
    combine(2*s, p, 2*s + 1, p ^ 511, rev3(j + 1));
  }
  if (last) {
    // row 6: k2=0 (q=0), self-paired with pperm = rev3((512-rev3(p))&511)
    for (int p = t; p < 512; p += 256) {
      int pp = rev3((512 - rev3(p)) & 511);
      if (p <= pp) combine(6, p, 6, pp, 0);
    }
    // row 7: k2=256 (q=4), self-paired with pperm = p^511
    if (t < 256) combine(7, t, 7, t ^ 511, 4);
  }
  __syncthreads();

  #pragma unroll
  for (int g = 0; g < ROWS/4; ++g)
    fft512_inv(&rows[((g<<2)+wid)*RST], lane, w512);
  __syncthreads();
  for (int i = t; i < ROWS*512; i += 256) {
    int r = i >> 9, n1 = i & 511;
    int s = r >> 1, which = r & 1;
    int j = bx*4 + s;
    int k2 = (j == 255) ? (which ? 256 : 0) : (which ? 511 - j : j + 1);
    int q = rev3(k2);
    Xe[(size_t)q*512 + n1] = pkh(cmulc(rows[r*RST + pidx(n1)], wtw((n1*k2) & (MFT-1))));
  }
}

// pass C: inverse column FFT (truncated — only n2<256 consumed);
// Re -> event 2p (shift a), Im -> event 2p+1 (shift b)
__global__ __launch_bounds__(256) void k_passC2(const __half2* __restrict__ Xb,
                                                float* __restrict__ dout,
                                                const float2* __restrict__ w512g,
                                                const int* __restrict__ shiftA,
                                                int e0) {
  __shared__ float2 w512[512];
  __shared__ float2 tile[COLS*CST];
  int t = threadIdx.x;
  for (int i = t; i < 512; i += 256) w512[i] = w512g[i];
  const __half2* Xe = Xb + (size_t)blockIdx.y * MFT;
  int c0 = blockIdx.x * COLS;
  for (int i = t; i < 512*COLS; i += 256) {
    int cc = i & (COLS-1), q = i >> 3;
    tile[cc*CST + pidx(q)] = uph(Xe[c0 + cc + ((size_t)q<<9)]);
  }
  __syncthreads();
  int wid = t >> 6, lane = t & 63;
  #pragma unroll
  for (int g = 0; g < COLS/4; ++g)
    fft512_inv_trunc(&tile[((g<<2) + wid)*CST], lane, w512);
  __syncthreads();
  int na = e0 + 2*blockIdx.y, nb = na + 1;
  int sha = shiftA[na], shb = shiftA[nb];
  float* dpa = dout + (size_t)na*NSMP;
  float* dpb = dout + (size_t)nb*NSMP;
  for (int i = t; i < 256*COLS; i += 256) {   // only p < NS needed (n2 < 256)
    int cc = i & (COLS-1), n2 = i >> 3;
    int p = c0 + cc + (n2<<9);
    float2 y = tile[cc*CST + pidx(n2)];
    int oa = p + sha;
    if (oa < NSMP) dpa[oa] = y.x;
    int ob = p + shb;
    if (ob < NSMP) dpb[ob] = y.y;
  }
}

} // namespace

extern "C" void kernel_launch(void* const* d_in, const int* in_sizes, int n_in,
                              void* d_out, int out_size, void* d_ws, size_t ws_size,
                              hipStream_t stream) {
  (void)in_sizes; (void)n_in;
  const float* voice  = (const float*)d_in[0];
  const float* cpc    = (const float*)d_in[1];
  const float* amps   = (const float*)d_in[2];
  const float* room   = (const float*)d_in[3];
  const float* rmix   = (const float*)d_in[4];
  const float* times  = (const float*)d_in[5];
  const float* cp_tab = (const float*)d_in[6];
  const float* verbs  = (const float*)d_in[7];
  const float* w_in   = (const float*)d_in[8];
  const float* w_ih   = (const float*)d_in[9];
  const float* w_hh   = (const float*)d_in[10];
  const float* w_out  = (const float*)d_in[11];
  float* out = (float*)d_out;

  char* base = (char*)d_ws;
  size_t off = 0;
  auto carve = [&](size_t bytes) -> void* {
    void* p = base + off;
    off = (off + bytes + 255) & ~(size_t)255;
    return p;
  };
  float*   sig   = (float*)  carve((size_t)NEV*NSMP*4);   // 64 MB
  float2*  w512g = (float2*) carve((size_t)512*8);        // 4 KB compact twiddles
  __half2* spec  = (__half2*)carve((size_t)16*MFT*4);     // 16 MB (verb spectra, fp16)
  int*   vidx  = (int*)  carve(NEV*4);
  int*   cpidx = (int*)  carve(NEV*4);
  int*   ridx  = (int*)  carve(NEV*4);
  int*   shf   = (int*)  carve(NEV*4);
  float* m0    = (float*)carve(NEV*4);
  float* m1    = (float*)carve(NEV*4);
  float* amp   = (float*)carve(NEV*4);

  // GEMM-phase temporaries alias the spec region (13.3 MB < 16 MB); verb
  // spectra are computed AFTER k_gemm_mfma, when these are all dead.
  size_t toff = (size_t)((char*)spec - base);
  auto carveT = [&](size_t bytes) -> void* {
    void* p = base + toff;
    toff = (toff + bytes + 255) & ~(size_t)255;
    return p;
  };
  float*          mred  = (float*)         carveT((size_t)8*128*16*4);
  float*          ctrl  = (float*)         carveT((size_t)NEV*2048*4);
  unsigned short* hs_hi = (unsigned short*)carveT((size_t)NEV*128*128*2);
  unsigned short* hs_lo = (unsigned short*)carveT((size_t)NEV*128*128*2);
  unsigned short* wo_hi = (unsigned short*)carveT((size_t)8*1024*128*2);
  unsigned short* wo_lo = (unsigned short*)carveT((size_t)8*1024*128*2);

  __half2* X = (__half2*)(base + off);
  size_t rem = (ws_size > off) ? (ws_size - off) : 0;
  int C = (int)(rem / ((size_t)MFT*4));     // chunk size in PAIRS (fp16 X)
  if (C > NPAIR) C = NPAIR;
  if (C < 1) C = 1;

  hipMemsetAsync(d_out, 0, (size_t)out_size*sizeof(float), stream);

  k_params<<<NEV, 64, 0, stream>>>(voice, cpc, amps, room, rmix, times,
                                   vidx, cpidx, ridx, shf, m0, m1, amp);
  k_w512<<<2, 256, 0, stream>>>(w512g);
  k_mred<<<dim3(128, 8), 64, 0, stream>>>(w_ih, w_in, mred);
  k_topk<<<NEV, 256, 0, stream>>>(cp_tab, cpidx, ctrl);
  k_rnn<<<NEV, 512, 0, stream>>>(ctrl, mred, w_hh, vidx, hs_hi, hs_lo);
  k_wsplit<<<(8*1024*128)/256, 256, 0, stream>>>(w_out, wo_hi, wo_lo, 8*1024*128);
  k_gemm_mfma<<<dim3(8, NEV), 256, 0, stream>>>(hs_hi, hs_lo, wo_hi, wo_lo, vidx, sig);

  // verb spectra: unpacked forward pipeline (must run after k_gemm_mfma —
  // temporaries above alias this region)
  k_passA<<<dim3(64, 16), 256, 0, stream>>>(verbs, spec, w512g);
  k_passBv<<<dim3(64, 16), 256, 0, stream>>>(spec, w512g);

  // main conv: 2 real events packed per complex FFT pipeline
  for (int p0 = 0; p0 < NPAIR; p0 += C) {
    int cp = (NPAIR - p0 < C) ? (NPAIR - p0) : C;
    k_passA2<<<dim3(64, cp), 256, 0, stream>>>(sig + (size_t)p0*2*NSMP, X, w512g);
    k_passB2<<<dim3(64, cp), 256, 0, stream>>>(X, spec, w512g, ridx, m0, m1, amp, 2*p0);
    k_passC2<<<dim3(64, cp), 256, 0, stream>>>(X, out, w512g, shf, 2*p0);
  }
}

// Round 16
// 399.416 us; speedup vs baseline: 1.1431x; 1.0390x over previous
//
#include <hip/hip_runtime.h>
#include <hip/hip_fp16.h>
#include <math.h>

namespace {

constexpr int NSMP = 131072;   // n_samples
constexpr int NEV  = 128;      // B*E events
constexpr int NPAIR = NEV/2;   // packed complex pipelines
constexpr int MFT  = 262144;   // 2*NS FFT size = 512*512
constexpr int COLS = 8;        // cols per pass A/C block
constexpr int ROWS = 8;        // rows per pass B block
constexpr int RST  = 576;      // padded row stride (pass B): pidx(511)=574 < 576
constexpr int CST  = 578;      // padded col stride (pass A/C)

typedef __attribute__((ext_vector_type(8))) short short8;
typedef __attribute__((ext_vector_type(4))) float f32x4;

__device__ __forceinline__ float2 cadd(float2 a, float2 b){ return make_float2(a.x+b.x, a.y+b.y); }
__device__ __forceinline__ float2 csub(float2 a, float2 b){ return make_float2(a.x-b.x, a.y-b.y); }
__device__ __forceinline__ float2 cmul(float2 a, float2 b){ return make_float2(a.x*b.x - a.y*b.y, a.x*b.y + a.y*b.x); }
__device__ __forceinline__ float2 cmulc(float2 a, float2 b){ return make_float2(a.x*b.x + a.y*b.y, a.y*b.x - a.x*b.y); }
__device__ __forceinline__ int rev3(int x){ return ((x&7)<<6) | (x&56) | (x>>6); }  // base-8 digit reversal, 9 bits
// bank-conflict-breaking pad: one extra float2 per 8 (stage3 32-way -> 4-way)
__device__ __forceinline__ int pidx(int i){ return i + (i>>3); }

// fp16 pack/unpack for the global spectral intermediates (compute stays fp32)
__device__ __forceinline__ __half2 pkh(float2 v){ return __floats2half2_rn(v.x, v.y); }
__device__ __forceinline__ float2 uph(__half2 h){ return __half22float2(h); }

// computed big twiddle: W_MFT^idx = (cos, sin) of -2*pi*idx/MFT
__device__ __forceinline__ float2 wtw(int idx) {
  float ang = (float)idx * (-6.283185307179586f / (float)MFT);
  float sn, cs;
  __sincosf(ang, &sn, &cs);
  return make_float2(cs, sn);
}

// round-to-nearest-even f32 -> bf16 (values here are always finite)
__device__ __forceinline__ unsigned short f2bf(float x) {
  unsigned u = __float_as_uint(x);
  unsigned r = (u + 0x7FFFu + ((u >> 16) & 1u)) >> 16;
  return (unsigned short)r;
}
__device__ __forceinline__ float bf2f(unsigned short h) {
  return __uint_as_float(((unsigned)h) << 16);
}

// 8-point DFT: out[k] = sum_j in[j] * exp(SGN*2*pi*i*j*k/8)
template<int SGN>
__device__ __forceinline__ void fft8v(float2* u) {
  const float S2 = 0.70710678118654752440f;
  float2 a0 = cadd(u[0], u[4]), a1 = csub(u[0], u[4]);
  float2 a2 = cadd(u[2], u[6]), a3 = csub(u[2], u[6]);
  float2 b0 = cadd(u[1], u[5]), b1 = csub(u[1], u[5]);
  float2 b2 = cadd(u[3], u[7]), b3 = csub(u[3], u[7]);
  float2 a3r = (SGN < 0) ? make_float2(a3.y, -a3.x) : make_float2(-a3.y, a3.x);
  float2 b3r = (SGN < 0) ? make_float2(b3.y, -b3.x) : make_float2(-b3.y, b3.x);
  float2 E0 = cadd(a0, a2), E2 = csub(a0, a2);
  float2 E1 = cadd(a1, a3r), E3 = csub(a1, a3r);
  float2 O0 = cadd(b0, b2), O2 = csub(b0, b2);
  float2 O1 = cadd(b1, b3r), O3 = csub(b1, b3r);
  const float sg = (SGN < 0) ? -1.f : 1.f;
  O1 = cmul(O1, make_float2(S2, sg*S2));
  O2 = (SGN < 0) ? make_float2(O2.y, -O2.x) : make_float2(-O2.y, O2.x);
  O3 = cmul(O3, make_float2(-S2, sg*S2));
  u[0] = cadd(E0, O0); u[4] = csub(E0, O0);
  u[1] = cadd(E1, O1); u[5] = csub(E1, O1);
  u[2] = cadd(E2, O2); u[6] = csub(E2, O2);
  u[3] = cadd(E3, O3); u[7] = csub(E3, O3);
}

// Stages 2+3 of the forward 512-pt DIF (shared by full and zero-padded heads).
__device__ __forceinline__ void fft512_fwd_tail(float2* X, int lane, const float2* w512) {
  float2 u[8];
  {
    int b = (lane>>3)<<6, m = lane&7;
    #pragma unroll
    for (int j = 0; j < 8; ++j) u[j] = X[pidx(b + (j<<3) + m)];
    fft8v<-1>(u);
    #pragma unroll
    for (int r = 1; r < 8; ++r) u[r] = cmul(u[r], w512[((m*r)<<3) & 511]);
    #pragma unroll
    for (int r = 0; r < 8; ++r) X[pidx(b + (r<<3) + m)] = u[r];
  }
  {
    int c = lane<<3;
    #pragma unroll
    for (int j = 0; j < 8; ++j) u[j] = X[pidx(c + j)];
    fft8v<-1>(u);
    #pragma unroll
    for (int r = 0; r < 8; ++r) X[pidx(c + r)] = u[r];
  }
}

// In-place 512-pt forward DIF (natural in -> base-8 digit-reversed out).
// Wave-private LDS region -> barrier-free inside.
__device__ void fft512_fwd(float2* X, int lane, const float2* w512) {
  float2 u[8];
  #pragma unroll
  for (int j = 0; j < 8; ++j) u[j] = X[pidx((j<<6) + lane)];
  fft8v<-1>(u);
  #pragma unroll
  for (int r = 1; r < 8; ++r) u[r] = cmul(u[r], w512[(lane*r) & 511]);
  #pragma unroll
  for (int r = 0; r < 8; ++r) X[pidx((r<<6) + lane)] = u[r];
  fft512_fwd_tail(X, lane, w512);
}

// Zero-padded variant: elements 256..511 are known zero (never read).
__device__ void fft512_fwd_zpad(float2* X, int lane, const float2* w512) {
  const float S2 = 0.70710678118654752440f;
  float2 u[8];
  #pragma unroll
  for (int j = 0; j < 4; ++j) u[j] = X[pidx((j<<6) + lane)];
  {
    float2 a0 = u[0], a1 = u[0], a2 = u[2], a3 = u[2];
    float2 b0 = u[1], b1 = u[1], b2 = u[3], b3 = u[3];
    float2 a3r = make_float2(a3.y, -a3.x);
    float2 b3r = make_float2(b3.y, -b3.x);
    float2 E0 = cadd(a0, a2), E2 = csub(a0, a2);
    float2 E1 = cadd(a1, a3r), E3 = csub(a1, a3r);
    float2 O0 = cadd(b0, b2), O2 = csub(b0, b2);
    float2 O1 = cadd(b1, b3r), O3 = csub(b1, b3r);
    O1 = cmul(O1, make_float2(S2, -S2));
    O2 = make_float2(O2.y, -O2.x);
    O3 = cmul(O3, make_float2(-S2, -S2));
    u[0] = cadd(E0, O0); u[4] = csub(E0, O0);
    u[1] = cadd(E1, O1); u[5] = csub(E1, O1);
    u[2] = cadd(E2, O2); u[6] = csub(E2, O2);
    u[3] = cadd(E3, O3); u[7] = csub(E3, O3);
  }
  #pragma unroll
  for (int r = 1; r < 8; ++r) u[r] = cmul(u[r], w512[(lane*r) & 511]);
  #pragma unroll
  for (int r = 0; r < 8; ++r) X[pidx((r<<6) + lane)] = u[r];
  fft512_fwd_tail(X, lane, w512);
}

// Stages 1+2 of the inverse (shared by full and truncated-output variants).
__device__ __forceinline__ void fft512_inv_head(float2* X, int lane, const float2* w512) {
  float2 u[8];
  {
    int c = lane<<3;
    #pragma unroll
    for (int r = 0; r < 8; ++r) u[r] = X[pidx(c + r)];
    fft8v<1>(u);
    #pragma unroll
    for (int j = 0; j < 8; ++j) X[pidx(c + j)] = u[j];
  }
  {
    int b = (lane>>3)<<6, m = lane&7;
    #pragma unroll
    for (int r = 0; r < 8; ++r) u[r] = X[pidx(b + (r<<3) + m)];
    #pragma unroll
    for (int r = 1; r < 8; ++r) u[r] = cmulc(u[r], w512[((m*r)<<3) & 511]);
    fft8v<1>(u);
    #pragma unroll
    for (int j = 0; j < 8; ++j) X[pidx(b + (j<<3) + m)] = u[j];
  }
}

// In-place 512-pt inverse: digit-reversed in -> natural out. Unnormalized.
__device__ void fft512_inv(float2* X, int lane, const float2* w512) {
  fft512_inv_head(X, lane, w512);
  float2 u[8];
  #pragma unroll
  for (int r = 0; r < 8; ++r) u[r] = X[pidx((r<<6) + lane)];
  #pragma unroll
  for (int r = 1; r < 8; ++r) u[r] = cmulc(u[r], w512[(lane*r) & 511]);
  fft8v<1>(u);
  #pragma unroll
  for (int j = 0; j < 8; ++j) X[pidx((j<<6) + lane)] = u[j];
}

// Truncated-output variant: only natural outputs 0..255 are consumed.
__device__ void fft512_inv_trunc(float2* X, int lane, const float2* w512) {
  fft512_inv_head(X, lane, w512);
  float2 u[8];
  #pragma unroll
  for (int r = 0; r < 8; ++r) u[r] = X[pidx((r<<6) + lane)];
  #pragma unroll
  for (int r = 1; r < 8; ++r) u[r] = cmulc(u[r], w512[(lane*r) & 511]);
  fft8v<1>(u);
  #pragma unroll
  for (int j = 0; j < 4; ++j) X[pidx((j<<6) + lane)] = u[j];
}

// -------- per-event scalar params (argmaxes, softmax mix, |amp|) --------
__global__ void k_params(const float* __restrict__ voice, const float* __restrict__ cpc,
                         const float* __restrict__ amps, const float* __restrict__ room,
                         const float* __restrict__ rmix, const float* __restrict__ times,
                         int* __restrict__ vidx, int* __restrict__ cpidx, int* __restrict__ ridx,
                         int* __restrict__ shiftA, float* __restrict__ m0, float* __restrict__ m1,
                         float* __restrict__ amp) {
  int n = blockIdx.x, t = threadIdx.x;
  if (t == 0) {
    const float* p = voice + n*8; int bi = 0; float bv = p[0];
    for (int i = 1; i < 8; ++i) if (p[i] > bv) { bv = p[i]; bi = i; }
    vidx[n] = bi;
  } else if (t == 1) {
    const float* p = cpc + n*512; int bi = 0; float bv = p[0];
    for (int i = 1; i < 512; ++i) if (p[i] > bv) { bv = p[i]; bi = i; }
    cpidx[n] = bi;
  } else if (t == 2) {
    const float* p = room + n*16; int bi = 0; float bv = p[0];
    for (int i = 1; i < 16; ++i) if (p[i] > bv) { bv = p[i]; bi = i; }
    ridx[n] = bi;
  } else if (t == 3) {
    const float* p = times + n*128; int bi = 0; float bv = p[0];
    for (int i = 1; i < 128; ++i) if (p[i] > bv) { bv = p[i]; bi = i; }
    shiftA[n] = bi * 1024;
  } else if (t == 4) {
    float a = rmix[n*2], b = rmix[n*2+1];
    float mx = fmaxf(a, b);
    float ea = __expf(a - mx), eb = __expf(b - mx);
    float inv = 1.f / (ea + eb);
    m0[n] = ea * inv; m1[n] = eb * inv;
    amp[n] = fabsf(amps[n]);
  }
}

// -------- compact 512-pt twiddle table: w512g[i] = exp(-2 pi i/512 * i) --------
__global__ void k_w512(float2* __restrict__ w512g) {
  int i = blockIdx.x * blockDim.x + threadIdx.x;
  if (i < 512) {
    double a = -2.0 * 3.14159265358979323846 * (double)(i * 512) / (double)MFT;
    w512g[i] = make_float2((float)cos(a), (float)sin(a));
  }
}

// -------- M[v] = w_ih[v] @ w_in[v]  -> [8][128][16] --------
__global__ void k_mred(const float* __restrict__ w_ih, const float* __restrict__ w_in,
                       float* __restrict__ mred) {
  int h = blockIdx.x, v = blockIdx.y, t = threadIdx.x;
  const float* ih = w_ih + ((size_t)v*128 + h)*1024;
  const float* wi = w_in + (size_t)v*1024*16;
  float acc[16];
  #pragma unroll
  for (int c = 0; c < 16; ++c) acc[c] = 0.f;
  for (int w = t; w < 1024; w += 64) {
    float a = ih[w];
    const float4* wr = (const float4*)(wi + (size_t)w*16);
    float4 q0 = wr[0], q1 = wr[1], q2 = wr[2], q3 = wr[3];
    acc[0] += a*q0.x; acc[1] += a*q0.y; acc[2] += a*q0.z; acc[3] += a*q0.w;
    acc[4] += a*q1.x; acc[5] += a*q1.y; acc[6] += a*q1.z; acc[7] += a*q1.w;
    acc[8] += a*q2.x; acc[9] += a*q2.y; acc[10]+= a*q2.z; acc[11]+= a*q2.w;
    acc[12]+= a*q3.x; acc[13]+= a*q3.y; acc[14]+= a*q3.z; acc[15]+= a*q3.w;
  }
  #pragma unroll
  for (int c = 0; c < 16; ++c) {
    float s = acc[c];
    for (int o = 32; o > 0; o >>= 1) s += __shfl_down(s, o);
    if (t == 0) mred[((size_t)v*128 + h)*16 + c] = s;
  }
}

// -------- exact top-128 of selected cp_table row (2048 vals), relu, ties by lowest index --------
__global__ __launch_bounds__(256) void k_topk(const float* __restrict__ cp_table,
                                              const int* __restrict__ cpidx,
                                              float* __restrict__ ctrl) {
  __shared__ int redw[4];
  __shared__ int scanbuf[256];
  int n = blockIdx.x, t = threadIdx.x;
  const float* row = cp_table + (size_t)cpidx[n]*2048;
  float f[8]; unsigned v[8];
  #pragma unroll
  for (int i = 0; i < 8; ++i) { f[i] = row[t*8 + i]; v[i] = __float_as_uint(f[i]); }
  int lane = t & 63, wid = t >> 6;
  unsigned thr = 0;
  for (int b = 31; b >= 0; --b) {  // values are >=0, bit pattern is order-preserving
    unsigned cand = thr | (1u << b);
    int c = 0;
    #pragma unroll
    for (int i = 0; i < 8; ++i) c += (v[i] >= cand);
    for (int o = 32; o > 0; o >>= 1) c += __shfl_down(c, o);
    if (lane == 0) redw[wid] = c;
    __syncthreads();
    int tot = redw[0] + redw[1] + redw[2] + redw[3];
    if (tot >= 128) thr = cand;
    __syncthreads();
  }
  int g = 0, eq = 0;
  #pragma unroll
  for (int i = 0; i < 8; ++i) { g += (v[i] > thr); eq += (v[i] == thr); }
  int gw = g;
  for (int o = 32; o > 0; o >>= 1) gw += __shfl_down(gw, o);
  if (lane == 0) redw[wid] = gw;
  scanbuf[t] = eq;
  __syncthreads();
  int G = redw[0] + redw[1] + redw[2] + redw[3];
  int extra = 128 - G;
  int incl = eq;
  for (int o = 1; o < 256; o <<= 1) {
    int add = (t >= o) ? scanbuf[t - o] : 0;
    __syncthreads();
    incl += add;
    scanbuf[t] = incl;
    __syncthreads();
  }
  int rank = incl - eq;
  float* outp = ctrl + (size_t)n*2048;
  #pragma unroll
  for (int i = 0; i < 8; ++i) {
    bool keep = (v[i] > thr) || ((v[i] == thr) && (rank < extra));
    if (v[i] == thr) rank++;
    outp[t*8 + i] = keep ? fmaxf(f[i], 0.f) : 0.f;
  }
}

// -------- 128-step tanh RNN, one block per event --------
__global__ __launch_bounds__(512) void k_rnn(const float* __restrict__ ctrl,
                                             const float* __restrict__ mred,
                                             const float* __restrict__ w_hh,
                                             const int* __restrict__ vidx,
                                             unsigned short* __restrict__ hs_hi,
                                             unsigned short* __restrict__ hs_lo) {
  __shared__ __align__(16) float h_s[2][128];
  __shared__ float ctrl_s[2048];
  __shared__ float cin_s[128*128];   // cin[st][i] = sum_c M[i][c]*ctrl[c][st]
  int n = blockIdx.x, t = threadIdx.x;
  int i = t >> 2, s = t & 3;
  int v = vidx[n];
  int rot = s << 1;

  // Whh quarter into VGPRs, pre-rotated: whh[j] pairs with h slice elem (j+rot)&7
  const float4* whhrow = (const float4*)(w_hh + ((size_t)v*128 + i)*128 + 32*s);
  float4 whh[8];
  #pragma unroll
  for (int j = 0; j < 8; ++j) whh[j] = whhrow[(j + rot) & 7];

  for (int k = t; k < 2048; k += 512) ctrl_s[k] = ctrl[(size_t)n*2048 + k];
  if (s == 0) { h_s[0][i] = 0.f; }
  __syncthreads();

  // precompute cin[st][i] for all steps (parallel, off the critical path)
  {
    int ii = t & 127, stq = t >> 7;   // thread -> output ii, step-quarter stq
    const float4* mrow = (const float4*)(mred + ((size_t)v*128 + ii)*16);
    float4 m0q = mrow[0], m1q = mrow[1], m2q = mrow[2], m3q = mrow[3];
    #pragma unroll 4
    for (int st0 = 0; st0 < 32; ++st0) {
      int st = stq*32 + st0;
      float a = 0.f, b = 0.f;
      a += m0q.x*ctrl_s[(0<<7)+st];  b += m0q.y*ctrl_s[(1<<7)+st];
      a += m0q.z*ctrl_s[(2<<7)+st];  b += m0q.w*ctrl_s[(3<<7)+st];
      a += m1q.x*ctrl_s[(4<<7)+st];  b += m1q.y*ctrl_s[(5<<7)+st];
      a += m1q.z*ctrl_s[(6<<7)+st];  b += m1q.w*ctrl_s[(7<<7)+st];
      a += m2q.x*ctrl_s[(8<<7)+st];  b += m2q.y*ctrl_s[(9<<7)+st];
      a += m2q.z*ctrl_s[(10<<7)+st]; b += m2q.w*ctrl_s[(11<<7)+st];
      a += m3q.x*ctrl_s[(12<<7)+st]; b += m3q.y*ctrl_s[(13<<7)+st];
      a += m3q.z*ctrl_s[(14<<7)+st]; b += m3q.w*ctrl_s[(15<<7)+st];
      cin_s[(st<<7) + ii] = a + b;
    }
  }
  __syncthreads();

  unsigned short* hi_out = hs_hi + (size_t)n*16384;
  unsigned short* lo_out = hs_lo + (size_t)n*16384;
  int p = 0;
  for (int grp = 0; grp < 16; ++grp) {
    unsigned short hbuf[8];
    #pragma unroll
    for (int k = 0; k < 8; ++k) {
      int st = grp*8 + k;
      const float4* hp = (const float4*)(&h_s[p][0]) + 8*s;
      float cin = cin_s[(st<<7) + i];
      float a0 = 0.f, a1 = 0.f;
      #pragma unroll
      for (int j = 0; j < 8; ++j) {
        float4 h4 = hp[(j + rot) & 7];   // rotated LDS read (conflict-free)
        float4 w4 = whh[j];              // static register index
        if (j & 1) a1 += w4.x*h4.x + w4.y*h4.y + w4.z*h4.z + w4.w*h4.w;
        else       a0 += w4.x*h4.x + w4.y*h4.y + w4.z*h4.z + w4.w*h4.w;
      }
      float acc = a0 + a1;
      acc += __shfl_xor(acc, 1);
      acc += __shfl_xor(acc, 2);
      acc += cin;
      float ax = fabsf(acc);
      float e = __expf(2.f*ax);
      float hn = copysignf(1.f - 2.f/(e + 1.f), acc);  // tanh, stable both tails
      unsigned short h = f2bf(hn);
      if (s == 0) {
        h_s[p^1][i] = hn;
        hbuf[k] = h;
      } else if (s == 1) {
        hbuf[k] = f2bf(hn - bf2f(h));
      }
      __syncthreads();
      p ^= 1;
    }
    // batched global stores — drained at the next group's first barrier
    if (s == 0) {
      #pragma unroll
      for (int k = 0; k < 8; ++k) hi_out[((grp*8 + k)<<7) + i] = hbuf[k];
    } else if (s == 1) {
      #pragma unroll
      for (int k = 0; k < 8; ++k) lo_out[((grp*8 + k)<<7) + i] = hbuf[k];
    }
  }
}

// -------- split w_out into bf16 hi/lo --------
__global__ void k_wsplit(const float* __restrict__ w, unsigned short* __restrict__ hi,
                         unsigned short* __restrict__ lo, int nelem) {
  int i = blockIdx.x * blockDim.x + threadIdx.x;
  if (i < nelem) {
    float x = w[i];
    unsigned short h = f2bf(x);
    hi[i] = h;
    lo[i] = f2bf(x - bf2f(h));
  }
}

// -------- sig = sin(hs @ w_out^T) via split-bf16 MFMA --------
__global__ __launch_bounds__(256) void k_gemm_mfma(
    const unsigned short* __restrict__ hs_hi, const unsigned short* __restrict__ hs_lo,
    const unsigned short* __restrict__ wo_hi, const unsigned short* __restrict__ wo_lo,
    const int* __restrict__ vidx, float* __restrict__ sig) {
  int n = blockIdx.y;
  int v = vidx[n];
  int t = threadIdx.x;
  int lane = t & 63, wave = t >> 6;
  int wm = wave >> 1, wn = wave & 1;
  int m_base = wm * 64;
  int n_base = blockIdx.x * 128 + wn * 64;
  int lrow = lane & 15;
  int lk = (lane >> 4) << 3;

  const unsigned short* Ah = hs_hi + (size_t)n * 16384;
  const unsigned short* Al = hs_lo + (size_t)n * 16384;
  const unsigned short* Bh = wo_hi + (size_t)v * 131072;
  const unsigned short* Bl = wo_lo + (size_t)v * 131072;

  f32x4 acc[4][4];
  #pragma unroll
  for (int i = 0; i < 4; ++i)
    #pragma unroll
    for (int j = 0; j < 4; ++j) acc[i][j] = (f32x4){0.f, 0.f, 0.f, 0.f};

  #pragma unroll
  for (int ks = 0; ks < 128; ks += 32) {
    short8 ah[4], al[4], bh[4], bl[4];
    #pragma unroll
    for (int mt = 0; mt < 4; ++mt) {
      size_t o = (size_t)(m_base + mt*16 + lrow) * 128 + ks + lk;
      ah[mt] = *(const short8*)(Ah + o);
      al[mt] = *(const short8*)(Al + o);
    }
    #pragma unroll
    for (int nt = 0; nt < 4; ++nt) {
      size_t o = (size_t)(n_base + nt*16 + lrow) * 128 + ks + lk;
      bh[nt] = *(const short8*)(Bh + o);
      bl[nt] = *(const short8*)(Bl + o);
    }
    #pragma unroll
    for (int mt = 0; mt < 4; ++mt)
      #pragma unroll
      for (int nt = 0; nt < 4; ++nt) {
        acc[mt][nt] = __builtin_amdgcn_mfma_f32_16x16x32_bf16(ah[mt], bh[nt], acc[mt][nt], 0, 0, 0);
        acc[mt][nt] = __builtin_amdgcn_mfma_f32_16x16x32_bf16(ah[mt], bl[nt], acc[mt][nt], 0, 0, 0);
        acc[mt][nt] = __builtin_amdgcn_mfma_f32_16x16x32_bf16(al[mt], bh[nt], acc[mt][nt], 0, 0, 0);
      }
  }

  // C/D layout: col = lane&15, row = (lane>>4)*4 + reg
  float* dst = sig + (size_t)n * NSMP;
  int drow = (lane >> 4) << 2, dcol = lane & 15;
  #pragma unroll
  for (int mt = 0; mt < 4; ++mt)
    #pragma unroll
    for (int nt = 0; nt < 4; ++nt)
      #pragma unroll
      for (int r = 0; r < 4; ++r) {
        int m = m_base + mt*16 + drow + r;
        int nn = n_base + nt*16 + dcol;
        dst[(size_t)m * 1024 + nn] = __sinf(acc[mt][nt][r]);
      }
}

// -------- FFT pass A (real, unpacked — verbs): column FFT-512 over n2 --------
__global__ __launch_bounds__(256) void k_passA(const float* __restrict__ in,
                                               __half2* __restrict__ outb,
                                               const float2* __restrict__ w512g) {
  __shared__ float2 w512[512];
  __shared__ float2 tile[COLS*CST];
  int t = threadIdx.x;
  for (int i = t; i < 512; i += 256) w512[i] = w512g[i];
  const float* src = in + (size_t)blockIdx.y * NSMP;
  __half2* dst = outb + (size_t)blockIdx.y * MFT;
  int c0 = blockIdx.x * COLS;
  for (int i = t; i < 256*COLS; i += 256) {   // stage only nonzero lower half
    int cc = i & (COLS-1), n2 = i >> 3;
    tile[cc*CST + pidx(n2)] = make_float2(src[c0 + cc + (n2<<9)], 0.f);
  }
  __syncthreads();
  int wid = t >> 6, lane = t & 63;
  #pragma unroll
  for (int g = 0; g < COLS/4; ++g)
    fft512_fwd_zpad(&tile[((g<<2) + wid)*CST], lane, w512);
  __syncthreads();
  for (int i = t; i < 512*COLS; i += 256) {
    int cc = i & (COLS-1), q = i >> 3;
    dst[c0 + cc + (q<<9)] = pkh(tile[cc*CST + pidx(q)]);
  }
}

// -------- FFT pass B forward-only (verb spectra) --------
// Twiddle by per-thread recurrence: thread owns 16 consecutive n1 of one row.
__global__ __launch_bounds__(256) void k_passBv(__half2* __restrict__ Xb,
                                                const float2* __restrict__ w512g) {
  __shared__ float2 w512[512];
  __shared__ float2 rows[ROWS*RST];
  int t = threadIdx.x;
  for (int i = t; i < 512; i += 256) w512[i] = w512g[i];
  __half2* Xe = Xb + (size_t)blockIdx.y * MFT;
  int q0 = blockIdx.x * ROWS;
  {
    int r = t >> 5, seg = t & 31;
    int q = q0 + r;
    int k2 = rev3(q);
    int n1b = seg << 4;
    float2 w = wtw((n1b * k2) & (MFT-1));
    float2 ws = wtw(k2);
    const __half2* xrow = Xe + (size_t)q*512 + n1b;
    float2* drow = rows + r*RST;
    #pragma unroll
    for (int m = 0; m < 16; ++m) {
      drow[pidx(n1b + m)] = cmul(uph(xrow[m]), w);
      w = cmul(w, ws);
    }
  }
  __syncthreads();
  int wid = t >> 6, lane = t & 63;
  #pragma unroll
  for (int g = 0; g < ROWS/4; ++g)
    fft512_fwd(&rows[((g<<2)+wid)*RST], lane, w512);
  __syncthreads();
  for (int i = t; i < ROWS*512; i += 256) {
    int r = i >> 9, n1 = i & 511;
    Xe[(size_t)(q0 + r)*512 + n1] = pkh(rows[r*RST + pidx(n1)]);
  }
}

// ======== packed (2 real events per complex FFT) conv pipeline ========

// pass A: z = sig[2p] + i*sig[2p+1], column FFT-512 (upper half zero-padded)
__global__ __launch_bounds__(256) void k_passA2(const float* __restrict__ in,
                                                __half2* __restrict__ outb,
                                                const float2* __restrict__ w512g) {
  __shared__ float2 w512[512];
  __shared__ float2 tile[COLS*CST];
  int t = threadIdx.x;
  for (int i = t; i < 512; i += 256) w512[i] = w512g[i];
  const float* src = in + (size_t)blockIdx.y * 2 * NSMP;
  __half2* dst = outb + (size_t)blockIdx.y * MFT;
  int c0 = blockIdx.x * COLS;
  for (int i = t; i < 256*COLS; i += 256) {   // stage only nonzero lower half
    int cc = i & (COLS-1), n2 = i >> 3;
    int o = c0 + cc + (n2<<9);
    tile[cc*CST + pidx(n2)] = make_float2(src[o], src[o + NSMP]);
  }
  __syncthreads();
  int wid = t >> 6, lane = t & 63;
  #pragma unroll
  for (int g = 0; g < COLS/4; ++g)
    fft512_fwd_zpad(&tile[((g<<2) + wid)*CST], lane, w512);
  __syncthreads();
  for (int i = t; i < 512*COLS; i += 256) {
    int cc = i & (COLS-1), q = i >> 3;
    dst[c0 + cc + (q<<9)] = pkh(tile[cc*CST + pidx(q)]);
  }
}

// pass B: row FFT of conjugate-paired rows, Hermitian split, per-event reverb
// multiply, recombine, inverse row FFT. Block = 4 row-pair slots.
// Twiddles via per-thread recurrence (16 consecutive n1 per thread per row).
__global__ __launch_bounds__(256) void k_passB2(__half2* __restrict__ Xb,
                                                const __half2* __restrict__ spec,
                                                const float2* __restrict__ w512g,
                                                const int* __restrict__ ridx,
                                                const float* __restrict__ m0a,
                                                const float* __restrict__ m1a,
                                                const float* __restrict__ ampa,
                                                int e0) {
  __shared__ float2 w512[512];
  __shared__ float2 rows[ROWS*RST];
  int t = threadIdx.x;
  for (int i = t; i < 512; i += 256) w512[i] = w512g[i];
  __half2* Xe = Xb + (size_t)blockIdx.y * MFT;
  int bx = blockIdx.x;
  bool last = (bx == 63);

  // row geometry for this thread (8 rows x 32 segments of 16)
  int r8 = t >> 5, seg = t & 31;
  int s8 = r8 >> 1, which8 = r8 & 1;
  int j8 = bx*4 + s8;
  int k2t = (j8 == 255) ? (which8 ? 256 : 0) : (which8 ? 511 - j8 : j8 + 1);
  int qt = rev3(k2t);
  int n1b = seg << 4;
  float2 wst = wtw(k2t);

  // load + forward twiddle (recurrence: 1 base sincos + 15 cmuls per thread)
  {
    float2 w = wtw((n1b * k2t) & (MFT-1));
    const __half2* xrow = Xe + (size_t)qt*512 + n1b;
    float2* drow = rows + r8*RST;
    #pragma unroll
    for (int m = 0; m < 16; ++m) {
      drow[pidx(n1b + m)] = cmul(uph(xrow[m]), w);
      w = cmul(w, wst);
    }
  }
  __syncthreads();
  int wid = t >> 6, lane = t & 63;
  #pragma unroll
  for (int g = 0; g < ROWS/4; ++g)
    fft512_fwd(&rows[((g<<2)+wid)*RST], lane, w512);
  __syncthreads();

  // per-event reverb responses
  int na = e0 + 2*blockIdx.y, nb = na + 1;
  float inv = 1.f/(float)MFT;
  float sa0 = ampa[na]*m0a[na]*inv, sa1 = ampa[na]*m1a[na]*inv;
  float sb0 = ampa[nb]*m0a[nb]*inv, sb1 = ampa[nb]*m1a[nb]*inv;
  const __half2* spa = spec + (size_t)ridx[na]*MFT;
  const __half2* spb = spec + (size_t)ridx[nb]*MFT;

  auto combine = [&](int rA, int pA, int rB, int pB, int qA) {
    float2 P = rows[rA*RST + pidx(pA)];
    float2 Q = rows[rB*RST + pidx(pB)];
    float2 A = make_float2(0.5f*(P.x + Q.x), 0.5f*(P.y - Q.y));   // spectrum of event a at k
    float2 Bv = make_float2(0.5f*(P.y + Q.y), 0.5f*(Q.x - P.x));  // spectrum of event b at k
    float2 Va = uph(spa[(size_t)qA*512 + pA]);
    float2 Vb = uph(spb[(size_t)qA*512 + pA]);
    float2 Ga = make_float2(sa0*Va.x + sa1, sa0*Va.y);
    float2 Gb = make_float2(sb0*Vb.x + sb1, sb0*Vb.y);
    float2 Ya = cmul(A, Ga);
    float2 Yb = cmul(Bv, Gb);
    rows[rA*RST + pidx(pA)] = make_float2(Ya.x - Yb.y, Ya.y + Yb.x);    // Zout(k)  = Ya + i*Yb
    rows[rB*RST + pidx(pB)] = make_float2(Ya.x + Yb.y, Yb.x - Ya.y);    // Zout(-k) = conj(Ya)+i*conj(Yb)
  };

  int ncomb = last ? 1536 : 2048;
  for (int i = t; i < ncomb; i += 256) {
    int s = i >> 9, p = i & 511;
    int j = bx*4 + s;
    combine(2*s, p, 2*s + 1, p ^ 511, rev3(j + 1));
  }
  if (last) {
    // row 6: k2=0 (q=0), self-paired with pperm = rev3((512-rev3(p))&511)
    for (int p = t; p < 512; p += 256) {
      int pp = rev3((512 - rev3(p)) & 511);
      if (p <= pp) combine(6, p, 6, pp, 0);
    }
    // row 7: k2=256 (q=4), self-paired with pperm = p^511
    if (t < 256) combine(7, t, 7, t ^ 511, 4);
  }
  __syncthreads();

  #pragma unroll
  for (int g = 0; g < ROWS/4; ++g)
    fft512_inv(&rows[((g<<2)+wid)*RST], lane, w512);
  __syncthreads();

  // store + conjugate twiddle (same recurrence)
  {
    float2 w = wtw((n1b * k2t) & (MFT-1));
    __half2* xrow = Xe + (size_t)qt*512 + n1b;
    const float2* srow = rows + r8*RST;
    #pragma unroll
    for (int m = 0; m < 16; ++m) {
      xrow[m] = pkh(cmulc(srow[pidx(n1b + m)], w));
      w = cmul(w, wst);
    }
  }
}

// pass C: inverse column FFT (truncated — only n2<256 consumed);
// Re -> event 2p (shift a), Im -> event 2p+1 (shift b).
// Wrapped positions (o >= NSMP) write ZERO at o-NSMP — this zero-fills
// exactly [0, shift) so no d_out memset is needed.
__global__ __launch_bounds__(256) void k_passC2(const __half2* __restrict__ Xb,
                                                float* __restrict__ dout,
                                                const float2* __restrict__ w512g,
                                                const int* __restrict__ shiftA,
                                                int e0) {
  __shared__ float2 w512[512];
  __shared__ float2 tile[COLS*CST];
  int t = threadIdx.x;
  for (int i = t; i < 512; i += 256) w512[i] = w512g[i];
  const __half2* Xe = Xb + (size_t)blockIdx.y * MFT;
  int c0 = blockIdx.x * COLS;
  for (int i = t; i < 512*COLS; i += 256) {
    int cc = i & (COLS-1), q = i >> 3;
    tile[cc*CST + pidx(q)] = uph(Xe[c0 + cc + ((size_t)q<<9)]);
  }
  __syncthreads();
  int wid = t >> 6, lane = t & 63;
  #pragma unroll
  for (int g = 0; g < COLS/4; ++g)
    fft512_inv_trunc(&tile[((g<<2) + wid)*CST], lane, w512);
  __syncthreads();
  int na = e0 + 2*blockIdx.y, nb = na + 1;
  int sha = shiftA[na], shb = shiftA[nb];
  float* dpa = dout + (size_t)na*NSMP;
  float* dpb = dout + (size_t)nb*NSMP;
  for (int i = t; i < 256*COLS; i += 256) {   // only p < NS needed (n2 < 256)
    int cc = i & (COLS-1), n2 = i >> 3;
    int p = c0 + cc + (n2<<9);
    float2 y = tile[cc*CST + pidx(n2)];
    int oa = p + sha;
    if (oa < NSMP) dpa[oa] = y.x; else dpa[oa - NSMP] = 0.f;
    int ob = p + shb;
    if (ob < NSMP) dpb[ob] = y.y; else dpb[ob - NSMP] = 0.f;
  }
}

} // namespace

extern "C" void kernel_launch(void* const* d_in, const int* in_sizes, int n_in,
                              void* d_out, int out_size, void* d_ws, size_t ws_size,
                              hipStream_t stream) {
  (void)in_sizes; (void)n_in; (void)out_size;
  const float* voice  = (const float*)d_in[0];
  const float* cpc    = (const float*)d_in[1];
  const float* amps   = (const float*)d_in[2];
  const float* room   = (const float*)d_in[3];
  const float* rmix   = (const float*)d_in[4];
  const float* times  = (const float*)d_in[5];
  const float* cp_tab = (const float*)d_in[6];
  const float* verbs  = (const float*)d_in[7];
  const float* w_in   = (const float*)d_in[8];
  const float* w_ih   = (const float*)d_in[9];
  const float* w_hh   = (const float*)d_in[10];
  const float* w_out  = (const float*)d_in[11];
  float* out = (float*)d_out;

  char* base = (char*)d_ws;
  size_t off = 0;
  auto carve = [&](size_t bytes) -> void* {
    void* p = base + off;
    off = (off + bytes + 255) & ~(size_t)255;
    return p;
  };
  float*   sig   = (float*)  carve((size_t)NEV*NSMP*4);   // 64 MB
  float2*  w512g = (float2*) carve((size_t)512*8);        // 4 KB compact twiddles
  __half2* spec  = (__half2*)carve((size_t)16*MFT*4);     // 16 MB (verb spectra, fp16)
  int*   vidx  = (int*)  carve(NEV*4);
  int*   cpidx = (int*)  carve(NEV*4);
  int*   ridx  = (int*)  carve(NEV*4);
  int*   shf   = (int*)  carve(NEV*4);
  float* m0    = (float*)carve(NEV*4);
  float* m1    = (float*)carve(NEV*4);
  float* amp   = (float*)carve(NEV*4);

  // GEMM-phase temporaries alias the spec region (13.3 MB < 16 MB); verb
  // spectra are computed AFTER k_gemm_mfma, when these are all dead.
  size_t toff = (size_t)((char*)spec - base);
  auto carveT = [&](size_t bytes) -> void* {
    void* p = base + toff;
    toff = (toff + bytes + 255) & ~(size_t)255;
    return p;
  };
  float*          mred  = (float*)         carveT((size_t)8*128*16*4);
  float*          ctrl  = (float*)         carveT((size_t)NEV*2048*4);
  unsigned short* hs_hi = (unsigned short*)carveT((size_t)NEV*128*128*2);
  unsigned short* hs_lo = (unsigned short*)carveT((size_t)NEV*128*128*2);
  unsigned short* wo_hi = (unsigned short*)carveT((size_t)8*1024*128*2);
  unsigned short* wo_lo = (unsigned short*)carveT((size_t)8*1024*128*2);

  __half2* X = (__half2*)(base + off);
  size_t rem = (ws_size > off) ? (ws_size - off) : 0;
  int C = (int)(rem / ((size_t)MFT*4));     // chunk size in PAIRS (fp16 X)
  if (C > NPAIR) C = NPAIR;
  if (C < 1) C = 1;

  k_params<<<NEV, 64, 0, stream>>>(voice, cpc, amps, room, rmix, times,
                                   vidx, cpidx, ridx, shf, m0, m1, amp);
  k_w512<<<2, 256, 0, stream>>>(w512g);
  k_mred<<<dim3(128, 8), 64, 0, stream>>>(w_ih, w_in, mred);
  k_topk<<<NEV, 256, 0, stream>>>(cp_tab, cpidx, ctrl);
  k_rnn<<<NEV, 512, 0, stream>>>(ctrl, mred, w_hh, vidx, hs_hi, hs_lo);
  k_wsplit<<<(8*1024*128)/256, 256, 0, stream>>>(w_out, wo_hi, wo_lo, 8*1024*128);
  k_gemm_mfma<<<dim3(8, NEV), 256, 0, stream>>>(hs_hi, hs_lo, wo_hi, wo_lo, vidx, sig);

  // verb spectra: unpacked forward pipeline (must run after k_gemm_mfma —
  // temporaries above alias this region)
  k_passA<<<dim3(64, 16), 256, 0, stream>>>(verbs, spec, w512g);
  k_passBv<<<dim3(64, 16), 256, 0, stream>>>(spec, w512g);

  // main conv: 2 real events packed per complex FFT pipeline
  // (no d_out memset needed — passC2's wrap-zero writes cover [0, shift))
  for (int p0 = 0; p0 < NPAIR; p0 += C) {
    int cp = (NPAIR - p0 < C) ? (NPAIR - p0) : C;
    k_passA2<<<dim3(64, cp), 256, 0, stream>>>(sig + (size_t)p0*2*NSMP, X, w512g);
    k_passB2<<<dim3(64, cp), 256, 0, stream>>>(X, spec, w512g, ridx, m0, m1, amp, 2*p0);
    k_passC2<<<dim3(64, cp), 256, 0, stream>>>(X, out, w512g, shf, 2*p0);
  }
}

// Round 17
// 388.037 us; speedup vs baseline: 1.1766x; 1.0293x over previous
//
#include <hip/hip_runtime.h>
#include <hip/hip_fp16.h>
#include <math.h>

namespace {

constexpr int NSMP = 131072;   // n_samples
constexpr int NEV  = 128;      // B*E events
constexpr int NPAIR = NEV/2;   // packed complex pipelines
constexpr int MFT  = 262144;   // 2*NS FFT size = 512*512
constexpr int COLS = 8;        // cols per pass A/C block
constexpr int ROWS = 8;        // rows per pass B block
constexpr int RST  = 576;      // padded row stride (pass B): pidx(511)=574 < 576
constexpr int CST  = 578;      // padded col stride (pass A/C)

typedef __attribute__((ext_vector_type(8))) short short8;
typedef __attribute__((ext_vector_type(4))) float f32x4;

__device__ __forceinline__ float2 cadd(float2 a, float2 b){ return make_float2(a.x+b.x, a.y+b.y); }
__device__ __forceinline__ float2 csub(float2 a, float2 b){ return make_float2(a.x-b.x, a.y-b.y); }
__device__ __forceinline__ float2 cmul(float2 a, float2 b){ return make_float2(a.x*b.x - a.y*b.y, a.x*b.y + a.y*b.x); }
__device__ __forceinline__ float2 cmulc(float2 a, float2 b){ return make_float2(a.x*b.x + a.y*b.y, a.y*b.x - a.x*b.y); }
__device__ __forceinline__ int rev3(int x){ return ((x&7)<<6) | (x&56) | (x>>6); }  // base-8 digit reversal, 9 bits
// bank-conflict-breaking pad: one extra float2 per 8 (stage3 32-way -> 4-way)
__device__ __forceinline__ int pidx(int i){ return i + (i>>3); }

// fp16 pack/unpack for the global spectral intermediates (compute stays fp32)
__device__ __forceinline__ __half2 pkh(float2 v){ return __floats2half2_rn(v.x, v.y); }
__device__ __forceinline__ float2 uph(__half2 h){ return __half22float2(h); }

// computed big twiddle: W_MFT^idx = (cos, sin) of -2*pi*idx/MFT
__device__ __forceinline__ float2 wtw(int idx) {
  float ang = (float)idx * (-6.283185307179586f / (float)MFT);
  float sn, cs;
  __sincosf(ang, &sn, &cs);
  return make_float2(cs, sn);
}

// round-to-nearest-even f32 -> bf16 (values here are always finite)
__device__ __forceinline__ unsigned short f2bf(float x) {
  unsigned u = __float_as_uint(x);
  unsigned r = (u + 0x7FFFu + ((u >> 16) & 1u)) >> 16;
  return (unsigned short)r;
}
__device__ __forceinline__ float bf2f(unsigned short h) {
  return __uint_as_float(((unsigned)h) << 16);
}

// 8-point DFT: out[k] = sum_j in[j] * exp(SGN*2*pi*i*j*k/8)
template<int SGN>
__device__ __forceinline__ void fft8v(float2* u) {
  const float S2 = 0.70710678118654752440f;
  float2 a0 = cadd(u[0], u[4]), a1 = csub(u[0], u[4]);
  float2 a2 = cadd(u[2], u[6]), a3 = csub(u[2], u[6]);
  float2 b0 = cadd(u[1], u[5]), b1 = csub(u[1], u[5]);
  float2 b2 = cadd(u[3], u[7]), b3 = csub(u[3], u[7]);
  float2 a3r = (SGN < 0) ? make_float2(a3.y, -a3.x) : make_float2(-a3.y, a3.x);
  float2 b3r = (SGN < 0) ? make_float2(b3.y, -b3.x) : make_float2(-b3.y, b3.x);
  float2 E0 = cadd(a0, a2), E2 = csub(a0, a2);
  float2 E1 = cadd(a1, a3r), E3 = csub(a1, a3r);
  float2 O0 = cadd(b0, b2), O2 = csub(b0, b2);
  float2 O1 = cadd(b1, b3r), O3 = csub(b1, b3r);
  const float sg = (SGN < 0) ? -1.f : 1.f;
  O1 = cmul(O1, make_float2(S2, sg*S2));
  O2 = (SGN < 0) ? make_float2(O2.y, -O2.x) : make_float2(-O2.y, O2.x);
  O3 = cmul(O3, make_float2(-S2, sg*S2));
  u[0] = cadd(E0, O0); u[4] = csub(E0, O0);
  u[1] = cadd(E1, O1); u[5] = csub(E1, O1);
  u[2] = cadd(E2, O2); u[6] = csub(E2, O2);
  u[3] = cadd(E3, O3); u[7] = csub(E3, O3);
}

// Stages 2+3 of the forward 512-pt DIF (shared by full and zero-padded heads).
__device__ __forceinline__ void fft512_fwd_tail(float2* X, int lane, const float2* w512) {
  float2 u[8];
  {
    int b = (lane>>3)<<6, m = lane&7;
    #pragma unroll
    for (int j = 0; j < 8; ++j) u[j] = X[pidx(b + (j<<3) + m)];
    fft8v<-1>(u);
    #pragma unroll
    for (int r = 1; r < 8; ++r) u[r] = cmul(u[r], w512[((m*r)<<3) & 511]);
    #pragma unroll
    for (int r = 0; r < 8; ++r) X[pidx(b + (r<<3) + m)] = u[r];
  }
  {
    int c = lane<<3;
    #pragma unroll
    for (int j = 0; j < 8; ++j) u[j] = X[pidx(c + j)];
    fft8v<-1>(u);
    #pragma unroll
    for (int r = 0; r < 8; ++r) X[pidx(c + r)] = u[r];
  }
}

// In-place 512-pt forward DIF (natural in -> base-8 digit-reversed out).
// Wave-private LDS region -> barrier-free inside.
__device__ void fft512_fwd(float2* X, int lane, const float2* w512) {
  float2 u[8];
  #pragma unroll
  for (int j = 0; j < 8; ++j) u[j] = X[pidx((j<<6) + lane)];
  fft8v<-1>(u);
  #pragma unroll
  for (int r = 1; r < 8; ++r) u[r] = cmul(u[r], w512[(lane*r) & 511]);
  #pragma unroll
  for (int r = 0; r < 8; ++r) X[pidx((r<<6) + lane)] = u[r];
  fft512_fwd_tail(X, lane, w512);
}

// Zero-padded variant: elements 256..511 are known zero (never read).
__device__ void fft512_fwd_zpad(float2* X, int lane, const float2* w512) {
  const float S2 = 0.70710678118654752440f;
  float2 u[8];
  #pragma unroll
  for (int j = 0; j < 4; ++j) u[j] = X[pidx((j<<6) + lane)];
  {
    float2 a0 = u[0], a1 = u[0], a2 = u[2], a3 = u[2];
    float2 b0 = u[1], b1 = u[1], b2 = u[3], b3 = u[3];
    float2 a3r = make_float2(a3.y, -a3.x);
    float2 b3r = make_float2(b3.y, -b3.x);
    float2 E0 = cadd(a0, a2), E2 = csub(a0, a2);
    float2 E1 = cadd(a1, a3r), E3 = csub(a1, a3r);
    float2 O0 = cadd(b0, b2), O2 = csub(b0, b2);
    float2 O1 = cadd(b1, b3r), O3 = csub(b1, b3r);
    O1 = cmul(O1, make_float2(S2, -S2));
    O2 = make_float2(O2.y, -O2.x);
    O3 = cmul(O3, make_float2(-S2, -S2));
    u[0] = cadd(E0, O0); u[4] = csub(E0, O0);
    u[1] = cadd(E1, O1); u[5] = csub(E1, O1);
    u[2] = cadd(E2, O2); u[6] = csub(E2, O2);
    u[3] = cadd(E3, O3); u[7] = csub(E3, O3);
  }
  #pragma unroll
  for (int r = 1; r < 8; ++r) u[r] = cmul(u[r], w512[(lane*r) & 511]);
  #pragma unroll
  for (int r = 0; r < 8; ++r) X[pidx((r<<6) + lane)] = u[r];
  fft512_fwd_tail(X, lane, w512);
}

// Stages 1+2 of the inverse (shared by full and truncated-output variants).
__device__ __forceinline__ void fft512_inv_head(float2* X, int lane, const float2* w512) {
  float2 u[8];
  {
    int c = lane<<3;
    #pragma unroll
    for (int r = 0; r < 8; ++r) u[r] = X[pidx(c + r)];
    fft8v<1>(u);
    #pragma unroll
    for (int j = 0; j < 8; ++j) X[pidx(c + j)] = u[j];
  }
  {
    int b = (lane>>3)<<6, m = lane&7;
    #pragma unroll
    for (int r = 0; r < 8; ++r) u[r] = X[pidx(b + (r<<3) + m)];
    #pragma unroll
    for (int r = 1; r < 8; ++r) u[r] = cmulc(u[r], w512[((m*r)<<3) & 511]);
    fft8v<1>(u);
    #pragma unroll
    for (int j = 0; j < 8; ++j) X[pidx(b + (j<<3) + m)] = u[j];
  }
}

// In-place 512-pt inverse: digit-reversed in -> natural out. Unnormalized.
__device__ void fft512_inv(float2* X, int lane, const float2* w512) {
  fft512_inv_head(X, lane, w512);
  float2 u[8];
  #pragma unroll
  for (int r = 0; r < 8; ++r) u[r] = X[pidx((r<<6) + lane)];
  #pragma unroll
  for (int r = 1; r < 8; ++r) u[r] = cmulc(u[r], w512[(lane*r) & 511]);
  fft8v<1>(u);
  #pragma unroll
  for (int j = 0; j < 8; ++j) X[pidx((j<<6) + lane)] = u[j];
}

// Truncated-output variant: only natural outputs 0..255 are consumed.
__device__ void fft512_inv_trunc(float2* X, int lane, const float2* w512) {
  fft512_inv_head(X, lane, w512);
  float2 u[8];
  #pragma unroll
  for (int r = 0; r < 8; ++r) u[r] = X[pidx((r<<6) + lane)];
  #pragma unroll
  for (int r = 1; r < 8; ++r) u[r] = cmulc(u[r], w512[(lane*r) & 511]);
  fft8v<1>(u);
  #pragma unroll
  for (int j = 0; j < 4; ++j) X[pidx((j<<6) + lane)] = u[j];
}

// -------- per-event scalar params (argmaxes, softmax mix, |amp|) --------
__global__ void k_params(const float* __restrict__ voice, const float* __restrict__ cpc,
                         const float* __restrict__ amps, const float* __restrict__ room,
                         const float* __restrict__ rmix, const float* __restrict__ times,
                         int* __restrict__ vidx, int* __restrict__ cpidx, int* __restrict__ ridx,
                         int* __restrict__ shiftA, float* __restrict__ m0, float* __restrict__ m1,
                         float* __restrict__ amp) {
  int n = blockIdx.x, t = threadIdx.x;
  if (t == 0) {
    const float* p = voice + n*8; int bi = 0; float bv = p[0];
    for (int i = 1; i < 8; ++i) if (p[i] > bv) { bv = p[i]; bi = i; }
    vidx[n] = bi;
  } else if (t == 1) {
    const float* p = cpc + n*512; int bi = 0; float bv = p[0];
    for (int i = 1; i < 512; ++i) if (p[i] > bv) { bv = p[i]; bi = i; }
    cpidx[n] = bi;
  } else if (t == 2) {
    const float* p = room + n*16; int bi = 0; float bv = p[0];
    for (int i = 1; i < 16; ++i) if (p[i] > bv) { bv = p[i]; bi = i; }
    ridx[n] = bi;
  } else if (t == 3) {
    const float* p = times + n*128; int bi = 0; float bv = p[0];
    for (int i = 1; i < 128; ++i) if (p[i] > bv) { bv = p[i]; bi = i; }
    shiftA[n] = bi * 1024;
  } else if (t == 4) {
    float a = rmix[n*2], b = rmix[n*2+1];
    float mx = fmaxf(a, b);
    float ea = __expf(a - mx), eb = __expf(b - mx);
    float inv = 1.f / (ea + eb);
    m0[n] = ea * inv; m1[n] = eb * inv;
    amp[n] = fabsf(amps[n]);
  }
}

// -------- compact 512-pt twiddle table: w512g[i] = exp(-2 pi i/512 * i) --------
__global__ void k_w512(float2* __restrict__ w512g) {
  int i = blockIdx.x * blockDim.x + threadIdx.x;
  if (i < 512) {
    double a = -2.0 * 3.14159265358979323846 * (double)(i * 512) / (double)MFT;
    w512g[i] = make_float2((float)cos(a), (float)sin(a));
  }
}

// -------- M[v] = w_ih[v] @ w_in[v]  -> [8][128][16] --------
__global__ void k_mred(const float* __restrict__ w_ih, const float* __restrict__ w_in,
                       float* __restrict__ mred) {
  int h = blockIdx.x, v = blockIdx.y, t = threadIdx.x;
  const float* ih = w_ih + ((size_t)v*128 + h)*1024;
  const float* wi = w_in + (size_t)v*1024*16;
  float acc[16];
  #pragma unroll
  for (int c = 0; c < 16; ++c) acc[c] = 0.f;
  for (int w = t; w < 1024; w += 64) {
    float a = ih[w];
    const float4* wr = (const float4*)(wi + (size_t)w*16);
    float4 q0 = wr[0], q1 = wr[1], q2 = wr[2], q3 = wr[3];
    acc[0] += a*q0.x; acc[1] += a*q0.y; acc[2] += a*q0.z; acc[3] += a*q0.w;
    acc[4] += a*q1.x; acc[5] += a*q1.y; acc[6] += a*q1.z; acc[7] += a*q1.w;
    acc[8] += a*q2.x; acc[9] += a*q2.y; acc[10]+= a*q2.z; acc[11]+= a*q2.w;
    acc[12]+= a*q3.x; acc[13]+= a*q3.y; acc[14]+= a*q3.z; acc[15]+= a*q3.w;
  }
  #pragma unroll
  for (int c = 0; c < 16; ++c) {
    float s = acc[c];
    for (int o = 32; o > 0; o >>= 1) s += __shfl_down(s, o);
    if (t == 0) mred[((size_t)v*128 + h)*16 + c] = s;
  }
}

// -------- exact top-128 of selected cp_table row (2048 vals), relu, ties by lowest index --------
__global__ __launch_bounds__(256) void k_topk(const float* __restrict__ cp_table,
                                              const int* __restrict__ cpidx,
                                              float* __restrict__ ctrl) {
  __shared__ int redw[4];
  __shared__ int scanbuf[256];
  int n = blockIdx.x, t = threadIdx.x;
  const float* row = cp_table + (size_t)cpidx[n]*2048;
  float f[8]; unsigned v[8];
  #pragma unroll
  for (int i = 0; i < 8; ++i) { f[i] = row[t*8 + i]; v[i] = __float_as_uint(f[i]); }
  int lane = t & 63, wid = t >> 6;
  unsigned thr = 0;
  for (int b = 31; b >= 0; --b) {  // values are >=0, bit pattern is order-preserving
    unsigned cand = thr | (1u << b);
    int c = 0;
    #pragma unroll
    for (int i = 0; i < 8; ++i) c += (v[i] >= cand);
    for (int o = 32; o > 0; o >>= 1) c += __shfl_down(c, o);
    if (lane == 0) redw[wid] = c;
    __syncthreads();
    int tot = redw[0] + redw[1] + redw[2] + redw[3];
    if (tot >= 128) thr = cand;
    __syncthreads();
  }
  int g = 0, eq = 0;
  #pragma unroll
  for (int i = 0; i < 8; ++i) { g += (v[i] > thr); eq += (v[i] == thr); }
  int gw = g;
  for (int o = 32; o > 0; o >>= 1) gw += __shfl_down(gw, o);
  if (lane == 0) redw[wid] = gw;
  scanbuf[t] = eq;
  __syncthreads();
  int G = redw[0] + redw[1] + redw[2] + redw[3];
  int extra = 128 - G;
  int incl = eq;
  for (int o = 1; o < 256; o <<= 1) {
    int add = (t >= o) ? scanbuf[t - o] : 0;
    __syncthreads();
    incl += add;
    scanbuf[t] = incl;
    __syncthreads();
  }
  int rank = incl - eq;
  float* outp = ctrl + (size_t)n*2048;
  #pragma unroll
  for (int i = 0; i < 8; ++i) {
    bool keep = (v[i] > thr) || ((v[i] == thr) && (rank < extra));
    if (v[i] == thr) rank++;
    outp[t*8 + i] = keep ? fmaxf(f[i], 0.f) : 0.f;
  }
}

// -------- 128-step tanh RNN, one block per event --------
__global__ __launch_bounds__(512) void k_rnn(const float* __restrict__ ctrl,
                                             const float* __restrict__ mred,
                                             const float* __restrict__ w_hh,
                                             const int* __restrict__ vidx,
                                             unsigned short* __restrict__ hs_hi,
                                             unsigned short* __restrict__ hs_lo) {
  __shared__ __align__(16) float h_s[2][128];
  __shared__ float ctrl_s[2048];
  __shared__ float cin_s[128*128];   // cin[st][i] = sum_c M[i][c]*ctrl[c][st]
  int n = blockIdx.x, t = threadIdx.x;
  int i = t >> 2, s = t & 3;
  int v = vidx[n];
  int rot = s << 1;

  // Whh quarter into VGPRs, pre-rotated: whh[j] pairs with h slice elem (j+rot)&7
  const float4* whhrow = (const float4*)(w_hh + ((size_t)v*128 + i)*128 + 32*s);
  float4 whh[8];
  #pragma unroll
  for (int j = 0; j < 8; ++j) whh[j] = whhrow[(j + rot) & 7];

  for (int k = t; k < 2048; k += 512) ctrl_s[k] = ctrl[(size_t)n*2048 + k];
  if (s == 0) { h_s[0][i] = 0.f; }
  __syncthreads();

  // precompute cin[st][i] for all steps (parallel, off the critical path)
  {
    int ii = t & 127, stq = t >> 7;   // thread -> output ii, step-quarter stq
    const float4* mrow = (const float4*)(mred + ((size_t)v*128 + ii)*16);
    float4 m0q = mrow[0], m1q = mrow[1], m2q = mrow[2], m3q = mrow[3];
    #pragma unroll 4
    for (int st0 = 0; st0 < 32; ++st0) {
      int st = stq*32 + st0;
      float a = 0.f, b = 0.f;
      a += m0q.x*ctrl_s[(0<<7)+st];  b += m0q.y*ctrl_s[(1<<7)+st];
      a += m0q.z*ctrl_s[(2<<7)+st];  b += m0q.w*ctrl_s[(3<<7)+st];
      a += m1q.x*ctrl_s[(4<<7)+st];  b += m1q.y*ctrl_s[(5<<7)+st];
      a += m1q.z*ctrl_s[(6<<7)+st];  b += m1q.w*ctrl_s[(7<<7)+st];
      a += m2q.x*ctrl_s[(8<<7)+st];  b += m2q.y*ctrl_s[(9<<7)+st];
      a += m2q.z*ctrl_s[(10<<7)+st]; b += m2q.w*ctrl_s[(11<<7)+st];
      a += m3q.x*ctrl_s[(12<<7)+st]; b += m3q.y*ctrl_s[(13<<7)+st];
      a += m3q.z*ctrl_s[(14<<7)+st]; b += m3q.w*ctrl_s[(15<<7)+st];
      cin_s[(st<<7) + ii] = a + b;
    }
  }
  __syncthreads();

  unsigned short* hi_out = hs_hi + (size_t)n*16384;
  unsigned short* lo_out = hs_lo + (size_t)n*16384;
  int p = 0;
  for (int grp = 0; grp < 16; ++grp) {
    unsigned short hbuf[8];
    #pragma unroll
    for (int k = 0; k < 8; ++k) {
      int st = grp*8 + k;
      const float4* hp = (const float4*)(&h_s[p][0]) + 8*s;
      float cin = cin_s[(st<<7) + i];
      float a0 = 0.f, a1 = 0.f;
      #pragma unroll
      for (int j = 0; j < 8; ++j) {
        float4 h4 = hp[(j + rot) & 7];   // rotated LDS read (conflict-free)
        float4 w4 = whh[j];              // static register index
        if (j & 1) a1 += w4.x*h4.x + w4.y*h4.y + w4.z*h4.z + w4.w*h4.w;
        else       a0 += w4.x*h4.x + w4.y*h4.y + w4.z*h4.z + w4.w*h4.w;
      }
      float acc = a0 + a1;
      acc += __shfl_xor(acc, 1);
      acc += __shfl_xor(acc, 2);
      acc += cin;
      float ax = fabsf(acc);
      float e = __expf(2.f*ax);
      float hn = copysignf(1.f - 2.f/(e + 1.f), acc);  // tanh, stable both tails
      unsigned short h = f2bf(hn);
      if (s == 0) {
        h_s[p^1][i] = hn;
        hbuf[k] = h;
      } else if (s == 1) {
        hbuf[k] = f2bf(hn - bf2f(h));
      }
      __syncthreads();
      p ^= 1;
    }
    // batched global stores — drained at the next group's first barrier
    if (s == 0) {
      #pragma unroll
      for (int k = 0; k < 8; ++k) hi_out[((grp*8 + k)<<7) + i] = hbuf[k];
    } else if (s == 1) {
      #pragma unroll
      for (int k = 0; k < 8; ++k) lo_out[((grp*8 + k)<<7) + i] = hbuf[k];
    }
  }
}

// -------- split w_out into bf16 hi/lo --------
__global__ void k_wsplit(const float* __restrict__ w, unsigned short* __restrict__ hi,
                         unsigned short* __restrict__ lo, int nelem) {
  int i = blockIdx.x * blockDim.x + threadIdx.x;
  if (i < nelem) {
    float x = w[i];
    unsigned short h = f2bf(x);
    hi[i] = h;
    lo[i] = f2bf(x - bf2f(h));
  }
}

// -------- sig = sin(hs @ w_out^T) via split-bf16 MFMA; fp16 output --------
__global__ __launch_bounds__(256) void k_gemm_mfma(
    const unsigned short* __restrict__ hs_hi, const unsigned short* __restrict__ hs_lo,
    const unsigned short* __restrict__ wo_hi, const unsigned short* __restrict__ wo_lo,
    const int* __restrict__ vidx, __half* __restrict__ sig) {
  int n = blockIdx.y;
  int v = vidx[n];
  int t = threadIdx.x;
  int lane = t & 63, wave = t >> 6;
  int wm = wave >> 1, wn = wave & 1;
  int m_base = wm * 64;
  int n_base = blockIdx.x * 128 + wn * 64;
  int lrow = lane & 15;
  int lk = (lane >> 4) << 3;

  const unsigned short* Ah = hs_hi + (size_t)n * 16384;
  const unsigned short* Al = hs_lo + (size_t)n * 16384;
  const unsigned short* Bh = wo_hi + (size_t)v * 131072;
  const unsigned short* Bl = wo_lo + (size_t)v * 131072;

  f32x4 acc[4][4];
  #pragma unroll
  for (int i = 0; i < 4; ++i)
    #pragma unroll
    for (int j = 0; j < 4; ++j) acc[i][j] = (f32x4){0.f, 0.f, 0.f, 0.f};

  #pragma unroll
  for (int ks = 0; ks < 128; ks += 32) {
    short8 ah[4], al[4], bh[4], bl[4];
    #pragma unroll
    for (int mt = 0; mt < 4; ++mt) {
      size_t o = (size_t)(m_base + mt*16 + lrow) * 128 + ks + lk;
      ah[mt] = *(const short8*)(Ah + o);
      al[mt] = *(const short8*)(Al + o);
    }
    #pragma unroll
    for (int nt = 0; nt < 4; ++nt) {
      size_t o = (size_t)(n_base + nt*16 + lrow) * 128 + ks + lk;
      bh[nt] = *(const short8*)(Bh + o);
      bl[nt] = *(const short8*)(Bl + o);
    }
    #pragma unroll
    for (int mt = 0; mt < 4; ++mt)
      #pragma unroll
      for (int nt = 0; nt < 4; ++nt) {
        acc[mt][nt] = __builtin_amdgcn_mfma_f32_16x16x32_bf16(ah[mt], bh[nt], acc[mt][nt], 0, 0, 0);
        acc[mt][nt] = __builtin_amdgcn_mfma_f32_16x16x32_bf16(ah[mt], bl[nt], acc[mt][nt], 0, 0, 0);
        acc[mt][nt] = __builtin_amdgcn_mfma_f32_16x16x32_bf16(al[mt], bh[nt], acc[mt][nt], 0, 0, 0);
      }
  }

  // C/D layout: col = lane&15, row = (lane>>4)*4 + reg
  __half* dst = sig + (size_t)n * NSMP;
  int drow = (lane >> 4) << 2, dcol = lane & 15;
  #pragma unroll
  for (int mt = 0; mt < 4; ++mt)
    #pragma unroll
    for (int nt = 0; nt < 4; ++nt)
      #pragma unroll
      for (int r = 0; r < 4; ++r) {
        int m = m_base + mt*16 + drow + r;
        int nn = n_base + nt*16 + dcol;
        dst[(size_t)m * 1024 + nn] = __float2half(__sinf(acc[mt][nt][r]));
      }
}

// -------- FFT pass A (real, unpacked — verbs): column FFT-512 over n2 --------
__global__ __launch_bounds__(256) void k_passA(const float* __restrict__ in,
                                               __half2* __restrict__ outb,
                                               const float2* __restrict__ w512g) {
  __shared__ float2 w512[512];
  __shared__ float2 tile[COLS*CST];
  int t = threadIdx.x;
  for (int i = t; i < 512; i += 256) w512[i] = w512g[i];
  const float* src = in + (size_t)blockIdx.y * NSMP;
  __half2* dst = outb + (size_t)blockIdx.y * MFT;
  int c0 = blockIdx.x * COLS;
  for (int i = t; i < 256*COLS; i += 256) {   // stage only nonzero lower half
    int cc = i & (COLS-1), n2 = i >> 3;
    tile[cc*CST + pidx(n2)] = make_float2(src[c0 + cc + (n2<<9)], 0.f);
  }
  __syncthreads();
  int wid = t >> 6, lane = t & 63;
  #pragma unroll
  for (int g = 0; g < COLS/4; ++g)
    fft512_fwd_zpad(&tile[((g<<2) + wid)*CST], lane, w512);
  __syncthreads();
  for (int i = t; i < 512*COLS; i += 256) {
    int cc = i & (COLS-1), q = i >> 3;
    dst[c0 + cc + (q<<9)] = pkh(tile[cc*CST + pidx(q)]);
  }
}

// -------- FFT pass B forward-only (verb spectra) --------
// Twiddle by per-thread recurrence: thread owns 16 consecutive n1 of one row.
__global__ __launch_bounds__(256) void k_passBv(__half2* __restrict__ Xb,
                                                const float2* __restrict__ w512g) {
  __shared__ float2 w512[512];
  __shared__ float2 rows[ROWS*RST];
  int t = threadIdx.x;
  for (int i = t; i < 512; i += 256) w512[i] = w512g[i];
  __half2* Xe = Xb + (size_t)blockIdx.y * MFT;
  int q0 = blockIdx.x * ROWS;
  {
    int r = t >> 5, seg = t & 31;
    int q = q0 + r;
    int k2 = rev3(q);
    int n1b = seg << 4;
    float2 w = wtw((n1b * k2) & (MFT-1));
    float2 ws = wtw(k2);
    const __half2* xrow = Xe + (size_t)q*512 + n1b;
    float2* drow = rows + r*RST;
    #pragma unroll
    for (int m = 0; m < 16; ++m) {
      drow[pidx(n1b + m)] = cmul(uph(xrow[m]), w);
      w = cmul(w, ws);
    }
  }
  __syncthreads();
  int wid = t >> 6, lane = t & 63;
  #pragma unroll
  for (int g = 0; g < ROWS/4; ++g)
    fft512_fwd(&rows[((g<<2)+wid)*RST], lane, w512);
  __syncthreads();
  for (int i = t; i < ROWS*512; i += 256) {
    int r = i >> 9, n1 = i & 511;
    Xe[(size_t)(q0 + r)*512 + n1] = pkh(rows[r*RST + pidx(n1)]);
  }
}

// ======== packed (2 real events per complex FFT) conv pipeline ========

// pass A: z = sig[2p] + i*sig[2p+1], column FFT-512 (upper half zero-padded)
__global__ __launch_bounds__(256) void k_passA2(const __half* __restrict__ in,
                                                __half2* __restrict__ outb,
                                                const float2* __restrict__ w512g) {
  __shared__ float2 w512[512];
  __shared__ float2 tile[COLS*CST];
  int t = threadIdx.x;
  for (int i = t; i < 512; i += 256) w512[i] = w512g[i];
  const __half* src = in + (size_t)blockIdx.y * 2 * NSMP;
  __half2* dst = outb + (size_t)blockIdx.y * MFT;
  int c0 = blockIdx.x * COLS;
  for (int i = t; i < 256*COLS; i += 256) {   // stage only nonzero lower half
    int cc = i & (COLS-1), n2 = i >> 3;
    int o = c0 + cc + (n2<<9);
    tile[cc*CST + pidx(n2)] = make_float2(__half2float(src[o]), __half2float(src[o + NSMP]));
  }
  __syncthreads();
  int wid = t >> 6, lane = t & 63;
  #pragma unroll
  for (int g = 0; g < COLS/4; ++g)
    fft512_fwd_zpad(&tile[((g<<2) + wid)*CST], lane, w512);
  __syncthreads();
  for (int i = t; i < 512*COLS; i += 256) {
    int cc = i & (COLS-1), q = i >> 3;
    dst[c0 + cc + (q<<9)] = pkh(tile[cc*CST + pidx(q)]);
  }
}

// pass B: row FFT of conjugate-paired rows, Hermitian split, per-event reverb
// multiply, recombine, inverse row FFT. Block = 4 row-pair slots.
// Twiddles via per-thread recurrence (16 consecutive n1 per thread per row).
__global__ __launch_bounds__(256) void k_passB2(__half2* __restrict__ Xb,
                                                const __half2* __restrict__ spec,
                                                const float2* __restrict__ w512g,
                                                const int* __restrict__ ridx,
                                                const float* __restrict__ m0a,
                                                const float* __restrict__ m1a,
                                                const float* __restrict__ ampa,
                                                int e0) {
  __shared__ float2 w512[512];
  __shared__ float2 rows[ROWS*RST];
  int t = threadIdx.x;
  for (int i = t; i < 512; i += 256) w512[i] = w512g[i];
  __half2* Xe = Xb + (size_t)blockIdx.y * MFT;
  int bx = blockIdx.x;
  bool last = (bx == 63);

  // row geometry for this thread (8 rows x 32 segments of 16)
  int r8 = t >> 5, seg = t & 31;
  int s8 = r8 >> 1, which8 = r8 & 1;
  int j8 = bx*4 + s8;
  int k2t = (j8 == 255) ? (which8 ? 256 : 0) : (which8 ? 511 - j8 : j8 + 1);
  int qt = rev3(k2t);
  int n1b = seg << 4;
  float2 wst = wtw(k2t);

  // load + forward twiddle (recurrence: 1 base sincos + 15 cmuls per thread)
  {
    float2 w = wtw((n1b * k2t) & (MFT-1));
    const __half2* xrow = Xe + (size_t)qt*512 + n1b;
    float2* drow = rows + r8*RST;
    #pragma unroll
    for (int m = 0; m < 16; ++m) {
      drow[pidx(n1b + m)] = cmul(uph(xrow[m]), w);
      w = cmul(w, wst);
    }
  }
  __syncthreads();
  int wid = t >> 6, lane = t & 63;
  #pragma unroll
  for (int g = 0; g < ROWS/4; ++g)
    fft512_fwd(&rows[((g<<2)+wid)*RST], lane, w512);
  __syncthreads();

  // per-event reverb responses
  int na = e0 + 2*blockIdx.y, nb = na + 1;
  float inv = 1.f/(float)MFT;
  float sa0 = ampa[na]*m0a[na]*inv, sa1 = ampa[na]*m1a[na]*inv;
  float sb0 = ampa[nb]*m0a[nb]*inv, sb1 = ampa[nb]*m1a[nb]*inv;
  const __half2* spa = spec + (size_t)ridx[na]*MFT;
  const __half2* spb = spec + (size_t)ridx[nb]*MFT;

  auto combine = [&](int rA, int pA, int rB, int pB, int qA) {
    float2 P = rows[rA*RST + pidx(pA)];
    float2 Q = rows[rB*RST + pidx(pB)];
    float2 A = make_float2(0.5f*(P.x + Q.x), 0.5f*(P.y - Q.y));   // spectrum of event a at k
    float2 Bv = make_float2(0.5f*(P.y + Q.y), 0.5f*(Q.x - P.x));  // spectrum of event b at k
    float2 Va = uph(spa[(size_t)qA*512 + pA]);
    float2 Vb = uph(spb[(size_t)qA*512 + pA]);
    float2 Ga = make_float2(sa0*Va.x + sa1, sa0*Va.y);
    float2 Gb = make_float2(sb0*Vb.x + sb1, sb0*Vb.y);
    float2 Ya = cmul(A, Ga);
    float2 Yb = cmul(Bv, Gb);
    rows[rA*RST + pidx(pA)] = make_float2(Ya.x - Yb.y, Ya.y + Yb.x);    // Zout(k)  = Ya + i*Yb
    rows[rB*RST + pidx(pB)] = make_float2(Ya.x + Yb.y, Yb.x - Ya.y);    // Zout(-k) = conj(Ya)+i*conj(Yb)
  };

  int ncomb = last ? 1536 : 2048;
  for (int i = t; i < ncomb; i += 256) {
    int s = i >> 9, p = i & 511;
    int j = bx*4 + s;
    combine(2*s, p, 2*s + 1, p ^ 511, rev3(j + 1));
  }
  if (last) {
    // row 6: k2=0 (q=0), self-paired with pperm = rev3((512-rev3(p))&511)
    for (int p = t; p < 512; p += 256) {
      int pp = rev3((512 - rev3(p)) & 511);
      if (p <= pp) combine(6, p, 6, pp, 0);
    }
    // row 7: k2=256 (q=4), self-paired with pperm = p^511
    if (t < 256) combine(7, t, 7, t ^ 511, 4);
  }
  __syncthreads();

  #pragma unroll
  for (int g = 0; g < ROWS/4; ++g)
    fft512_inv(&rows[((g<<2)+wid)*RST], lane, w512);
  __syncthreads();

  // store + conjugate twiddle (same recurrence)
  {
    float2 w = wtw((n1b * k2t) & (MFT-1));
    __half2* xrow = Xe + (size_t)qt*512 + n1b;
    const float2* srow = rows + r8*RST;
    #pragma unroll
    for (int m = 0; m < 16; ++m) {
      xrow[m] = pkh(cmulc(srow[pidx(n1b + m)], w));
      w = cmul(w, wst);
    }
  }
}

// pass C: inverse column FFT (truncated — only n2<256 consumed);
// Re -> event 2p (shift a), Im -> event 2p+1 (shift b).
// Wrapped positions (o >= NSMP) write ZERO at o-NSMP — this zero-fills
// exactly [0, shift) so no d_out memset is needed.
__global__ __launch_bounds__(256) void k_passC2(const __half2* __restrict__ Xb,
                                                float* __restrict__ dout,
                                                const float2* __restrict__ w512g,
                                                const int* __restrict__ shiftA,
                                                int e0) {
  __shared__ float2 w512[512];
  __shared__ float2 tile[COLS*CST];
  int t = threadIdx.x;
  for (int i = t; i < 512; i += 256) w512[i] = w512g[i];
  const __half2* Xe = Xb + (size_t)blockIdx.y * MFT;
  int c0 = blockIdx.x * COLS;
  for (int i = t; i < 512*COLS; i += 256) {
    int cc = i & (COLS-1), q = i >> 3;
    tile[cc*CST + pidx(q)] = uph(Xe[c0 + cc + ((size_t)q<<9)]);
  }
  __syncthreads();
  int wid = t >> 6, lane = t & 63;
  #pragma unroll
  for (int g = 0; g < COLS/4; ++g)
    fft512_inv_trunc(&tile[((g<<2) + wid)*CST], lane, w512);
  __syncthreads();
  int na = e0 + 2*blockIdx.y, nb = na + 1;
  int sha = shiftA[na], shb = shiftA[nb];
  float* dpa = dout + (size_t)na*NSMP;
  float* dpb = dout + (size_t)nb*NSMP;
  for (int i = t; i < 256*COLS; i += 256) {   // only p < NS needed (n2 < 256)
    int cc = i & (COLS-1), n2 = i >> 3;
    int p = c0 + cc + (n2<<9);
    float2 y = tile[cc*CST + pidx(n2)];
    int oa = p + sha;
    if (oa < NSMP) dpa[oa] = y.x; else dpa[oa - NSMP] = 0.f;
    int ob = p + shb;
    if (ob < NSMP) dpb[ob] = y.y; else dpb[ob - NSMP] = 0.f;
  }
}

} // namespace

extern "C" void kernel_launch(void* const* d_in, const int* in_sizes, int n_in,
                              void* d_out, int out_size, void* d_ws, size_t ws_size,
                              hipStream_t stream) {
  (void)in_sizes; (void)n_in; (void)out_size;
  const float* voice  = (const float*)d_in[0];
  const float* cpc    = (const float*)d_in[1];
  const float* amps   = (const float*)d_in[2];
  const float* room   = (const float*)d_in[3];
  const float* rmix   = (const float*)d_in[4];
  const float* times  = (const float*)d_in[5];
  const float* cp_tab = (const float*)d_in[6];
  const float* verbs  = (const float*)d_in[7];
  const float* w_in   = (const float*)d_in[8];
  const float* w_ih   = (const float*)d_in[9];
  const float* w_hh   = (const float*)d_in[10];
  const float* w_out  = (const float*)d_in[11];
  float* out = (float*)d_out;

  char* base = (char*)d_ws;
  size_t off = 0;
  auto carve = [&](size_t bytes) -> void* {
    void* p = base + off;
    off = (off + bytes + 255) & ~(size_t)255;
    return p;
  };
  __half*  sig   = (__half*) carve((size_t)NEV*NSMP*2);   // 32 MB (fp16 signal)
  float2*  w512g = (float2*) carve((size_t)512*8);        // 4 KB compact twiddles
  __half2* spec  = (__half2*)carve((size_t)16*MFT*4);     // 16 MB (verb spectra, fp16)
  int*   vidx  = (int*)  carve(NEV*4);
  int*   cpidx = (int*)  carve(NEV*4);
  int*   ridx  = (int*)  carve(NEV*4);
  int*   shf   = (int*)  carve(NEV*4);
  float* m0    = (float*)carve(NEV*4);
  float* m1    = (float*)carve(NEV*4);
  float* amp   = (float*)carve(NEV*4);

  // GEMM-phase temporaries alias the spec region (13.3 MB < 16 MB); verb
  // spectra are computed AFTER k_gemm_mfma, when these are all dead.
  size_t toff = (size_t)((char*)spec - base);
  auto carveT = [&](size_t bytes) -> void* {
    void* p = base + toff;
    toff = (toff + bytes + 255) & ~(size_t)255;
    return p;
  };
  float*          mred  = (float*)         carveT((size_t)8*128*16*4);
  float*          ctrl  = (float*)         carveT((size_t)NEV*2048*4);
  unsigned short* hs_hi = (unsigned short*)carveT((size_t)NEV*128*128*2);
  unsigned short* hs_lo = (unsigned short*)carveT((size_t)NEV*128*128*2);
  unsigned short* wo_hi = (unsigned short*)carveT((size_t)8*1024*128*2);
  unsigned short* wo_lo = (unsigned short*)carveT((size_t)8*1024*128*2);

  __half2* X = (__half2*)(base + off);
  size_t rem = (ws_size > off) ? (ws_size - off) : 0;
  int C = (int)(rem / ((size_t)MFT*4));     // chunk size in PAIRS (fp16 X)
  if (C > NPAIR) C = NPAIR;
  if (C < 1) C = 1;

  k_params<<<NEV, 64, 0, stream>>>(voice, cpc, amps, room, rmix, times,
                                   vidx, cpidx, ridx, shf, m0, m1, amp);
  k_w512<<<2, 256, 0, stream>>>(w512g);
  k_mred<<<dim3(128, 8), 64, 0, stream>>>(w_ih, w_in, mred);
  k_topk<<<NEV, 256, 0, stream>>>(cp_tab, cpidx, ctrl);
  k_rnn<<<NEV, 512, 0, stream>>>(ctrl, mred, w_hh, vidx, hs_hi, hs_lo);
  k_wsplit<<<(8*1024*128)/256, 256, 0, stream>>>(w_out, wo_hi, wo_lo, 8*1024*128);
  k_gemm_mfma<<<dim3(8, NEV), 256, 0, stream>>>(hs_hi, hs_lo, wo_hi, wo_lo, vidx, sig);

  // verb spectra: unpacked forward pipeline (must run after k_gemm_mfma —
  // temporaries above alias this region)
  k_passA<<<dim3(64, 16), 256, 0, stream>>>(verbs, spec, w512g);
  k_passBv<<<dim3(64, 16), 256, 0, stream>>>(spec, w512g);

  // main conv: 2 real events packed per complex FFT pipeline
  // (no d_out memset needed — passC2's wrap-zero writes cover [0, shift))
  for (int p0 = 0; p0 < NPAIR; p0 += C) {
    int cp = (NPAIR - p0 < C) ? (NPAIR - p0) : C;
    k_passA2<<<dim3(64, cp), 256, 0, stream>>>(sig + (size_t)p0*2*NSMP, X, w512g);
    k_passB2<<<dim3(64, cp), 256, 0, stream>>>(X, spec, w512g, ridx, m0, m1, amp, 2*p0);
    k_passC2<<<dim3(64, cp), 256, 0, stream>>>(X, out, w512g, shf, 2*p0);
  }
}

// Round 18
// 383.948 us; speedup vs baseline: 1.1892x; 1.0106x over previous
//
#include <hip/hip_runtime.h>
#include <hip/hip_fp16.h>
#include <math.h>

namespace {

constexpr int NSMP = 131072;   // n_samples
constexpr int NEV  = 128;      // B*E events
constexpr int NPAIR = NEV/2;   // packed complex pipelines
constexpr int MFT  = 262144;   // 2*NS FFT size = 512*512
constexpr int COLS = 8;        // cols per pass A/C block
constexpr int ROWS = 8;        // rows per pass B block
constexpr int RST  = 576;      // padded row stride (pass B): pidx(511)=574 < 576
constexpr int CST  = 578;      // padded col stride (pass A/C)

typedef __attribute__((ext_vector_type(8))) short short8;
typedef __attribute__((ext_vector_type(4))) float f32x4;

__device__ __forceinline__ float2 cadd(float2 a, float2 b){ return make_float2(a.x+b.x, a.y+b.y); }
__device__ __forceinline__ float2 csub(float2 a, float2 b){ return make_float2(a.x-b.x, a.y-b.y); }
__device__ __forceinline__ float2 cmul(float2 a, float2 b){ return make_float2(a.x*b.x - a.y*b.y, a.x*b.y + a.y*b.x); }
__device__ __forceinline__ float2 cmulc(float2 a, float2 b){ return make_float2(a.x*b.x + a.y*b.y, a.y*b.x - a.x*b.y); }
__device__ __forceinline__ int rev3(int x){ return ((x&7)<<6) | (x&56) | (x>>6); }  // base-8 digit reversal, 9 bits
// bank-conflict-breaking pad: one extra float2 per 8 (stage3 32-way -> 4-way)
__device__ __forceinline__ int pidx(int i){ return i + (i>>3); }

// fp16 pack/unpack for the global spectral intermediates (compute stays fp32)
__device__ __forceinline__ __half2 pkh(float2 v){ return __floats2half2_rn(v.x, v.y); }
__device__ __forceinline__ float2 uph(__half2 h){ return __half22float2(h); }

// computed big twiddle: W_MFT^idx = (cos, sin) of -2*pi*idx/MFT
__device__ __forceinline__ float2 wtw(int idx) {
  float ang = (float)idx * (-6.283185307179586f / (float)MFT);
  float sn, cs;
  __sincosf(ang, &sn, &cs);
  return make_float2(cs, sn);
}

// half-size 512-pt twiddle table lookup: W512^(k+256) = -W512^k.
// w256s holds entries 0..255; sign flip is 2 full-rate VALU ops.
__device__ __forceinline__ float2 w512at(const float2* w256s, int idx) {
  float2 v = w256s[idx & 255];
  float s = (idx & 256) ? -1.f : 1.f;
  return make_float2(v.x * s, v.y * s);
}

// round-to-nearest-even f32 -> bf16 (values here are always finite)
__device__ __forceinline__ unsigned short f2bf(float x) {
  unsigned u = __float_as_uint(x);
  unsigned r = (u + 0x7FFFu + ((u >> 16) & 1u)) >> 16;
  return (unsigned short)r;
}
__device__ __forceinline__ float bf2f(unsigned short h) {
  return __uint_as_float(((unsigned)h) << 16);
}

// 8-point DFT: out[k] = sum_j in[j] * exp(SGN*2*pi*i*j*k/8)
template<int SGN>
__device__ __forceinline__ void fft8v(float2* u) {
  const float S2 = 0.70710678118654752440f;
  float2 a0 = cadd(u[0], u[4]), a1 = csub(u[0], u[4]);
  float2 a2 = cadd(u[2], u[6]), a3 = csub(u[2], u[6]);
  float2 b0 = cadd(u[1], u[5]), b1 = csub(u[1], u[5]);
  float2 b2 = cadd(u[3], u[7]), b3 = csub(u[3], u[7]);
  float2 a3r = (SGN < 0) ? make_float2(a3.y, -a3.x) : make_float2(-a3.y, a3.x);
  float2 b3r = (SGN < 0) ? make_float2(b3.y, -b3.x) : make_float2(-b3.y, b3.x);
  float2 E0 = cadd(a0, a2), E2 = csub(a0, a2);
  float2 E1 = cadd(a1, a3r), E3 = csub(a1, a3r);
  float2 O0 = cadd(b0, b2), O2 = csub(b0, b2);
  float2 O1 = cadd(b1, b3r), O3 = csub(b1, b3r);
  const float sg = (SGN < 0) ? -1.f : 1.f;
  O1 = cmul(O1, make_float2(S2, sg*S2));
  O2 = (SGN < 0) ? make_float2(O2.y, -O2.x) : make_float2(-O2.y, O2.x);
  O3 = cmul(O3, make_float2(-S2, sg*S2));
  u[0] = cadd(E0, O0); u[4] = csub(E0, O0);
  u[1] = cadd(E1, O1); u[5] = csub(E1, O1);
  u[2] = cadd(E2, O2); u[6] = csub(E2, O2);
  u[3] = cadd(E3, O3); u[7] = csub(E3, O3);
}

// Stages 2+3 of the forward 512-pt DIF (shared by full and zero-padded heads).
__device__ __forceinline__ void fft512_fwd_tail(float2* X, int lane, const float2* w256s) {
  float2 u[8];
  {
    int b = (lane>>3)<<6, m = lane&7;
    #pragma unroll
    for (int j = 0; j < 8; ++j) u[j] = X[pidx(b + (j<<3) + m)];
    fft8v<-1>(u);
    #pragma unroll
    for (int r = 1; r < 8; ++r) u[r] = cmul(u[r], w512at(w256s, ((m*r)<<3) & 511));
    #pragma unroll
    for (int r = 0; r < 8; ++r) X[pidx(b + (r<<3) + m)] = u[r];
  }
  {
    int c = lane<<3;
    #pragma unroll
    for (int j = 0; j < 8; ++j) u[j] = X[pidx(c + j)];
    fft8v<-1>(u);
    #pragma unroll
    for (int r = 0; r < 8; ++r) X[pidx(c + r)] = u[r];
  }
}

// In-place 512-pt forward DIF (natural in -> base-8 digit-reversed out).
// Wave-private LDS region -> barrier-free inside.
__device__ void fft512_fwd(float2* X, int lane, const float2* w256s) {
  float2 u[8];
  #pragma unroll
  for (int j = 0; j < 8; ++j) u[j] = X[pidx((j<<6) + lane)];
  fft8v<-1>(u);
  #pragma unroll
  for (int r = 1; r < 8; ++r) u[r] = cmul(u[r], w512at(w256s, (lane*r) & 511));
  #pragma unroll
  for (int r = 0; r < 8; ++r) X[pidx((r<<6) + lane)] = u[r];
  fft512_fwd_tail(X, lane, w256s);
}

// Zero-padded variant: elements 256..511 are known zero (never read).
__device__ void fft512_fwd_zpad(float2* X, int lane, const float2* w256s) {
  const float S2 = 0.70710678118654752440f;
  float2 u[8];
  #pragma unroll
  for (int j = 0; j < 4; ++j) u[j] = X[pidx((j<<6) + lane)];
  {
    float2 a0 = u[0], a1 = u[0], a2 = u[2], a3 = u[2];
    float2 b0 = u[1], b1 = u[1], b2 = u[3], b3 = u[3];
    float2 a3r = make_float2(a3.y, -a3.x);
    float2 b3r = make_float2(b3.y, -b3.x);
    float2 E0 = cadd(a0, a2), E2 = csub(a0, a2);
    float2 E1 = cadd(a1, a3r), E3 = csub(a1, a3r);
    float2 O0 = cadd(b0, b2), O2 = csub(b0, b2);
    float2 O1 = cadd(b1, b3r), O3 = csub(b1, b3r);
    O1 = cmul(O1, make_float2(S2, -S2));
    O2 = make_float2(O2.y, -O2.x);
    O3 = cmul(O3, make_float2(-S2, -S2));
    u[0] = cadd(E0, O0); u[4] = csub(E0, O0);
    u[1] = cadd(E1, O1); u[5] = csub(E1, O1);
    u[2] = cadd(E2, O2); u[6] = csub(E2, O2);
    u[3] = cadd(E3, O3); u[7] = csub(E3, O3);
  }
  #pragma unroll
  for (int r = 1; r < 8; ++r) u[r] = cmul(u[r], w512at(w256s, (lane*r) & 511));
  #pragma unroll
  for (int r = 0; r < 8; ++r) X[pidx((r<<6) + lane)] = u[r];
  fft512_fwd_tail(X, lane, w256s);
}

// Stages 1+2 of the inverse (shared by full and truncated-output variants).
__device__ __forceinline__ void fft512_inv_head(float2* X, int lane, const float2* w256s) {
  float2 u[8];
  {
    int c = lane<<3;
    #pragma unroll
    for (int r = 0; r < 8; ++r) u[r] = X[pidx(c + r)];
    fft8v<1>(u);
    #pragma unroll
    for (int j = 0; j < 8; ++j) X[pidx(c + j)] = u[j];
  }
  {
    int b = (lane>>3)<<6, m = lane&7;
    #pragma unroll
    for (int r = 0; r < 8; ++r) u[r] = X[pidx(b + (r<<3) + m)];
    #pragma unroll
    for (int r = 1; r < 8; ++r) u[r] = cmulc(u[r], w512at(w256s, ((m*r)<<3) & 511));
    fft8v<1>(u);
    #pragma unroll
    for (int j = 0; j < 8; ++j) X[pidx(b + (j<<3) + m)] = u[j];
  }
}

// In-place 512-pt inverse: digit-reversed in -> natural out. Unnormalized.
__device__ void fft512_inv(float2* X, int lane, const float2* w256s) {
  fft512_inv_head(X, lane, w256s);
  float2 u[8];
  #pragma unroll
  for (int r = 0; r < 8; ++r) u[r] = X[pidx((r<<6) + lane)];
  #pragma unroll
  for (int r = 1; r < 8; ++r) u[r] = cmulc(u[r], w512at(w256s, (lane*r) & 511));
  fft8v<1>(u);
  #pragma unroll
  for (int j = 0; j < 8; ++j) X[pidx((j<<6) + lane)] = u[j];
}

// Truncated-output variant: only natural outputs 0..255 are consumed.
__device__ void fft512_inv_trunc(float2* X, int lane, const float2* w256s) {
  fft512_inv_head(X, lane, w256s);
  float2 u[8];
  #pragma unroll
  for (int r = 0; r < 8; ++r) u[r] = X[pidx((r<<6) + lane)];
  #pragma unroll
  for (int r = 1; r < 8; ++r) u[r] = cmulc(u[r], w512at(w256s, (lane*r) & 511));
  fft8v<1>(u);
  #pragma unroll
  for (int j = 0; j < 4; ++j) X[pidx((j<<6) + lane)] = u[j];
}

// -------- per-event scalar params (argmaxes, softmax mix, |amp|) --------
__global__ void k_params(const float* __restrict__ voice, const float* __restrict__ cpc,
                         const float* __restrict__ amps, const float* __restrict__ room,
                         const float* __restrict__ rmix, const float* __restrict__ times,
                         int* __restrict__ vidx, int* __restrict__ cpidx, int* __restrict__ ridx,
                         int* __restrict__ shiftA, float* __restrict__ m0, float* __restrict__ m1,
                         float* __restrict__ amp) {
  int n = blockIdx.x, t = threadIdx.x;
  if (t == 0) {
    const float* p = voice + n*8; int bi = 0; float bv = p[0];
    for (int i = 1; i < 8; ++i) if (p[i] > bv) { bv = p[i]; bi = i; }
    vidx[n] = bi;
  } else if (t == 1) {
    const float* p = cpc + n*512; int bi = 0; float bv = p[0];
    for (int i = 1; i < 512; ++i) if (p[i] > bv) { bv = p[i]; bi = i; }
    cpidx[n] = bi;
  } else if (t == 2) {
    const float* p = room + n*16; int bi = 0; float bv = p[0];
    for (int i = 1; i < 16; ++i) if (p[i] > bv) { bv = p[i]; bi = i; }
    ridx[n] = bi;
  } else if (t == 3) {
    const float* p = times + n*128; int bi = 0; float bv = p[0];
    for (int i = 1; i < 128; ++i) if (p[i] > bv) { bv = p[i]; bi = i; }
    shiftA[n] = bi * 1024;
  } else if (t == 4) {
    float a = rmix[n*2], b = rmix[n*2+1];
    float mx = fmaxf(a, b);
    float ea = __expf(a - mx), eb = __expf(b - mx);
    float inv = 1.f / (ea + eb);
    m0[n] = ea * inv; m1[n] = eb * inv;
    amp[n] = fabsf(amps[n]);
  }
}

// -------- compact 256-entry 512-pt twiddle table (half, via W^(k+256)=-W^k) --------
__global__ void k_w512(float2* __restrict__ w512g) {
  int i = blockIdx.x * blockDim.x + threadIdx.x;
  if (i < 256) {
    double a = -2.0 * 3.14159265358979323846 * (double)(i * 512) / (double)MFT;
    w512g[i] = make_float2((float)cos(a), (float)sin(a));
  }
}

// -------- M[v] = w_ih[v] @ w_in[v]  -> [8][128][16] --------
__global__ void k_mred(const float* __restrict__ w_ih, const float* __restrict__ w_in,
                       float* __restrict__ mred) {
  int h = blockIdx.x, v = blockIdx.y, t = threadIdx.x;
  const float* ih = w_ih + ((size_t)v*128 + h)*1024;
  const float* wi = w_in + (size_t)v*1024*16;
  float acc[16];
  #pragma unroll
  for (int c = 0; c < 16; ++c) acc[c] = 0.f;
  for (int w = t; w < 1024; w += 64) {
    float a = ih[w];
    const float4* wr = (const float4*)(wi + (size_t)w*16);
    float4 q0 = wr[0], q1 = wr[1], q2 = wr[2], q3 = wr[3];
    acc[0] += a*q0.x; acc[1] += a*q0.y; acc[2] += a*q0.z; acc[3] += a*q0.w;
    acc[4] += a*q1.x; acc[5] += a*q1.y; acc[6] += a*q1.z; acc[7] += a*q1.w;
    acc[8] += a*q2.x; acc[9] += a*q2.y; acc[10]+= a*q2.z; acc[11]+= a*q2.w;
    acc[12]+= a*q3.x; acc[13]+= a*q3.y; acc[14]+= a*q3.z; acc[15]+= a*q3.w;
  }
  #pragma unroll
  for (int c = 0; c < 16; ++c) {
    float s = acc[c];
    for (int o = 32; o > 0; o >>= 1) s += __shfl_down(s, o);
    if (t == 0) mred[((size_t)v*128 + h)*16 + c] = s;
  }
}

// -------- exact top-128 of selected cp_table row (2048 vals), relu, ties by lowest index --------
__global__ __launch_bounds__(256) void k_topk(const float* __restrict__ cp_table,
                                              const int* __restrict__ cpidx,
                                              float* __restrict__ ctrl) {
  __shared__ int redw[4];
  __shared__ int scanbuf[256];
  int n = blockIdx.x, t = threadIdx.x;
  const float* row = cp_table + (size_t)cpidx[n]*2048;
  float f[8]; unsigned v[8];
  #pragma unroll
  for (int i = 0; i < 8; ++i) { f[i] = row[t*8 + i]; v[i] = __float_as_uint(f[i]); }
  int lane = t & 63, wid = t >> 6;
  unsigned thr = 0;
  for (int b = 31; b >= 0; --b) {  // values are >=0, bit pattern is order-preserving
    unsigned cand = thr | (1u << b);
    int c = 0;
    #pragma unroll
    for (int i = 0; i < 8; ++i) c += (v[i] >= cand);
    for (int o = 32; o > 0; o >>= 1) c += __shfl_down(c, o);
    if (lane == 0) redw[wid] = c;
    __syncthreads();
    int tot = redw[0] + redw[1] + redw[2] + redw[3];
    if (tot >= 128) thr = cand;
    __syncthreads();
  }
  int g = 0, eq = 0;
  #pragma unroll
  for (int i = 0; i < 8; ++i) { g += (v[i] > thr); eq += (v[i] == thr); }
  int gw = g;
  for (int o = 32; o > 0; o >>= 1) gw += __shfl_down(gw, o);
  if (lane == 0) redw[wid] = gw;
  scanbuf[t] = eq;
  __syncthreads();
  int G = redw[0] + redw[1] + redw[2] + redw[3];
  int extra = 128 - G;
  int incl = eq;
  for (int o = 1; o < 256; o <<= 1) {
    int add = (t >= o) ? scanbuf[t - o] : 0;
    __syncthreads();
    incl += add;
    scanbuf[t] = incl;
    __syncthreads();
  }
  int rank = incl - eq;
  float* outp = ctrl + (size_t)n*2048;
  #pragma unroll
  for (int i = 0; i < 8; ++i) {
    bool keep = (v[i] > thr) || ((v[i] == thr) && (rank < extra));
    if (v[i] == thr) rank++;
    outp[t*8 + i] = keep ? fmaxf(f[i], 0.f) : 0.f;
  }
}

// -------- 128-step tanh RNN, one block per event --------
__global__ __launch_bounds__(512) void k_rnn(const float* __restrict__ ctrl,
                                             const float* __restrict__ mred,
                                             const float* __restrict__ w_hh,
                                             const int* __restrict__ vidx,
                                             unsigned short* __restrict__ hs_hi,
                                             unsigned short* __restrict__ hs_lo) {
  __shared__ __align__(16) float h_s[2][128];
  __shared__ float ctrl_s[2048];
  __shared__ float cin_s[128*128];   // cin[st][i] = sum_c M[i][c]*ctrl[c][st]
  int n = blockIdx.x, t = threadIdx.x;
  int i = t >> 2, s = t & 3;
  int v = vidx[n];
  int rot = s << 1;

  // Whh quarter into VGPRs, pre-rotated: whh[j] pairs with h slice elem (j+rot)&7
  const float4* whhrow = (const float4*)(w_hh + ((size_t)v*128 + i)*128 + 32*s);
  float4 whh[8];
  #pragma unroll
  for (int j = 0; j < 8; ++j) whh[j] = whhrow[(j + rot) & 7];

  for (int k = t; k < 2048; k += 512) ctrl_s[k] = ctrl[(size_t)n*2048 + k];
  if (s == 0) { h_s[0][i] = 0.f; }
  __syncthreads();

  // precompute cin[st][i] for all steps (parallel, off the critical path)
  {
    int ii = t & 127, stq = t >> 7;   // thread -> output ii, step-quarter stq
    const float4* mrow = (const float4*)(mred + ((size_t)v*128 + ii)*16);
    float4 m0q = mrow[0], m1q = mrow[1], m2q = mrow[2], m3q = mrow[3];
    #pragma unroll 4
    for (int st0 = 0; st0 < 32; ++st0) {
      int st = stq*32 + st0;
      float a = 0.f, b = 0.f;
      a += m0q.x*ctrl_s[(0<<7)+st];  b += m0q.y*ctrl_s[(1<<7)+st];
      a += m0q.z*ctrl_s[(2<<7)+st];  b += m0q.w*ctrl_s[(3<<7)+st];
      a += m1q.x*ctrl_s[(4<<7)+st];  b += m1q.y*ctrl_s[(5<<7)+st];
      a += m1q.z*ctrl_s[(6<<7)+st];  b += m1q.w*ctrl_s[(7<<7)+st];
      a += m2q.x*ctrl_s[(8<<7)+st];  b += m2q.y*ctrl_s[(9<<7)+st];
      a += m2q.z*ctrl_s[(10<<7)+st]; b += m2q.w*ctrl_s[(11<<7)+st];
      a += m3q.x*ctrl_s[(12<<7)+st]; b += m3q.y*ctrl_s[(13<<7)+st];
      a += m3q.z*ctrl_s[(14<<7)+st]; b += m3q.w*ctrl_s[(15<<7)+st];
      cin_s[(st<<7) + ii] = a + b;
    }
  }
  __syncthreads();

  unsigned short* hi_out = hs_hi + (size_t)n*16384;
  unsigned short* lo_out = hs_lo + (size_t)n*16384;
  int p = 0;
  for (int grp = 0; grp < 16; ++grp) {
    unsigned short hbuf[8];
    #pragma unroll
    for (int k = 0; k < 8; ++k) {
      int st = grp*8 + k;
      const float4* hp = (const float4*)(&h_s[p][0]) + 8*s;
      float cin = cin_s[(st<<7) + i];
      float a0 = 0.f, a1 = 0.f;
      #pragma unroll
      for (int j = 0; j < 8; ++j) {
        float4 h4 = hp[(j + rot) & 7];   // rotated LDS read (conflict-free)
        float4 w4 = whh[j];              // static register index
        if (j & 1) a1 += w4.x*h4.x + w4.y*h4.y + w4.z*h4.z + w4.w*h4.w;
        else       a0 += w4.x*h4.x + w4.y*h4.y + w4.z*h4.z + w4.w*h4.w;
      }
      float acc = a0 + a1;
      acc += __shfl_xor(acc, 1);
      acc += __shfl_xor(acc, 2);
      acc += cin;
      float ax = fabsf(acc);
      float e = __expf(2.f*ax);
      float hn = copysignf(1.f - 2.f/(e + 1.f), acc);  // tanh, stable both tails
      unsigned short h = f2bf(hn);
      if (s == 0) {
        h_s[p^1][i] = hn;
        hbuf[k] = h;
      } else if (s == 1) {
        hbuf[k] = f2bf(hn - bf2f(h));
      }
      __syncthreads();
      p ^= 1;
    }
    // batched global stores — drained at the next group's first barrier
    if (s == 0) {
      #pragma unroll
      for (int k = 0; k < 8; ++k) hi_out[((grp*8 + k)<<7) + i] = hbuf[k];
    } else if (s == 1) {
      #pragma unroll
      for (int k = 0; k < 8; ++k) lo_out[((grp*8 + k)<<7) + i] = hbuf[k];
    }
  }
}

// -------- split w_out into bf16 hi/lo --------
__global__ void k_wsplit(const float* __restrict__ w, unsigned short* __restrict__ hi,
                         unsigned short* __restrict__ lo, int nelem) {
  int i = blockIdx.x * blockDim.x + threadIdx.x;
  if (i < nelem) {
    float x = w[i];
    unsigned short h = f2bf(x);
    hi[i] = h;
    lo[i] = f2bf(x - bf2f(h));
  }
}

// -------- sig = sin(hs @ w_out^T) via split-bf16 MFMA; fp16 output --------
__global__ __launch_bounds__(256) void k_gemm_mfma(
    const unsigned short* __restrict__ hs_hi, const unsigned short* __restrict__ hs_lo,
    const unsigned short* __restrict__ wo_hi, const unsigned short* __restrict__ wo_lo,
    const int* __restrict__ vidx, __half* __restrict__ sig) {
  int n = blockIdx.y;
  int v = vidx[n];
  int t = threadIdx.x;
  int lane = t & 63, wave = t >> 6;
  int wm = wave >> 1, wn = wave & 1;
  int m_base = wm * 64;
  int n_base = blockIdx.x * 128 + wn * 64;
  int lrow = lane & 15;
  int lk = (lane >> 4) << 3;

  const unsigned short* Ah = hs_hi + (size_t)n * 16384;
  const unsigned short* Al = hs_lo + (size_t)n * 16384;
  const unsigned short* Bh = wo_hi + (size_t)v * 131072;
  const unsigned short* Bl = wo_lo + (size_t)v * 131072;

  f32x4 acc[4][4];
  #pragma unroll
  for (int i = 0; i < 4; ++i)
    #pragma unroll
    for (int j = 0; j < 4; ++j) acc[i][j] = (f32x4){0.f, 0.f, 0.f, 0.f};

  #pragma unroll
  for (int ks = 0; ks < 128; ks += 32) {
    short8 ah[4], al[4], bh[4], bl[4];
    #pragma unroll
    for (int mt = 0; mt < 4; ++mt) {
      size_t o = (size_t)(m_base + mt*16 + lrow) * 128 + ks + lk;
      ah[mt] = *(const short8*)(Ah + o);
      al[mt] = *(const short8*)(Al + o);
    }
    #pragma unroll
    for (int nt = 0; nt < 4; ++nt) {
      size_t o = (size_t)(n_base + nt*16 + lrow) * 128 + ks + lk;
      bh[nt] = *(const short8*)(Bh + o);
      bl[nt] = *(const short8*)(Bl + o);
    }
    #pragma unroll
    for (int mt = 0; mt < 4; ++mt)
      #pragma unroll
      for (int nt = 0; nt < 4; ++nt) {
        acc[mt][nt] = __builtin_amdgcn_mfma_f32_16x16x32_bf16(ah[mt], bh[nt], acc[mt][nt], 0, 0, 0);
        acc[mt][nt] = __builtin_amdgcn_mfma_f32_16x16x32_bf16(ah[mt], bl[nt], acc[mt][nt], 0, 0, 0);
        acc[mt][nt] = __builtin_amdgcn_mfma_f32_16x16x32_bf16(al[mt], bh[nt], acc[mt][nt], 0, 0, 0);
      }
  }

  // C/D layout: col = lane&15, row = (lane>>4)*4 + reg
  __half* dst = sig + (size_t)n * NSMP;
  int drow = (lane >> 4) << 2, dcol = lane & 15;
  #pragma unroll
  for (int mt = 0; mt < 4; ++mt)
    #pragma unroll
    for (int nt = 0; nt < 4; ++nt)
      #pragma unroll
      for (int r = 0; r < 4; ++r) {
        int m = m_base + mt*16 + drow + r;
        int nn = n_base + nt*16 + dcol;
        dst[(size_t)m * 1024 + nn] = __float2half(__sinf(acc[mt][nt][r]));
      }
}

// -------- FFT pass A (real, unpacked — verbs): column FFT-512 over n2 --------
__global__ __launch_bounds__(256) void k_passA(const float* __restrict__ in,
                                               __half2* __restrict__ outb,
                                               const float2* __restrict__ w512g) {
  __shared__ float2 w256s[256];
  __shared__ float2 tile[COLS*CST];
  int t = threadIdx.x;
  if (t < 256) w256s[t] = w512g[t];
  const float* src = in + (size_t)blockIdx.y * NSMP;
  __half2* dst = outb + (size_t)blockIdx.y * MFT;
  int c0 = blockIdx.x * COLS;
  for (int i = t; i < 256*COLS; i += 256) {   // stage only nonzero lower half
    int cc = i & (COLS-1), n2 = i >> 3;
    tile[cc*CST + pidx(n2)] = make_float2(src[c0 + cc + (n2<<9)], 0.f);
  }
  __syncthreads();
  int wid = t >> 6, lane = t & 63;
  #pragma unroll
  for (int g = 0; g < COLS/4; ++g)
    fft512_fwd_zpad(&tile[((g<<2) + wid)*CST], lane, w256s);
  __syncthreads();
  for (int i = t; i < 512*COLS; i += 256) {
    int cc = i & (COLS-1), q = i >> 3;
    dst[c0 + cc + (q<<9)] = pkh(tile[cc*CST + pidx(q)]);
  }
}

// -------- FFT pass B forward-only (verb spectra) --------
// Twiddle by per-thread recurrence: thread owns 16 consecutive n1 of one row.
__global__ __launch_bounds__(256) void k_passBv(__half2* __restrict__ Xb,
                                                const float2* __restrict__ w512g) {
  __shared__ float2 w256s[256];
  __shared__ float2 rows[ROWS*RST];
  int t = threadIdx.x;
  if (t < 256) w256s[t] = w512g[t];
  __half2* Xe = Xb + (size_t)blockIdx.y * MFT;
  int q0 = blockIdx.x * ROWS;
  {
    int r = t >> 5, seg = t & 31;
    int q = q0 + r;
    int k2 = rev3(q);
    int n1b = seg << 4;
    float2 w = wtw((n1b * k2) & (MFT-1));
    float2 ws = wtw(k2);
    const __half2* xrow = Xe + (size_t)q*512 + n1b;
    float2* drow = rows + r*RST;
    #pragma unroll
    for (int m = 0; m < 16; ++m) {
      drow[pidx(n1b + m)] = cmul(uph(xrow[m]), w);
      w = cmul(w, ws);
    }
  }
  __syncthreads();
  int wid = t >> 6, lane = t & 63;
  #pragma unroll
  for (int g = 0; g < ROWS/4; ++g)
    fft512_fwd(&rows[((g<<2)+wid)*RST], lane, w256s);
  __syncthreads();
  for (int i = t; i < ROWS*512; i += 256) {
    int r = i >> 9, n1 = i & 511;
    Xe[(size_t)(q0 + r)*512 + n1] = pkh(rows[r*RST + pidx(n1)]);
  }
}

// ======== packed (2 real events per complex FFT) conv pipeline ========

// pass A: z = sig[2p] + i*sig[2p+1], column FFT-512 (upper half zero-padded)
__global__ __launch_bounds__(256) void k_passA2(const __half* __restrict__ in,
                                                __half2* __restrict__ outb,
                                                const float2* __restrict__ w512g) {
  __shared__ float2 w256s[256];
  __shared__ float2 tile[COLS*CST];
  int t = threadIdx.x;
  if (t < 256) w256s[t] = w512g[t];
  const __half* src = in + (size_t)blockIdx.y * 2 * NSMP;
  __half2* dst = outb + (size_t)blockIdx.y * MFT;
  int c0 = blockIdx.x * COLS;
  for (int i = t; i < 256*COLS; i += 256) {   // stage only nonzero lower half
    int cc = i & (COLS-1), n2 = i >> 3;
    int o = c0 + cc + (n2<<9);
    tile[cc*CST + pidx(n2)] = make_float2(__half2float(src[o]), __half2float(src[o + NSMP]));
  }
  __syncthreads();
  int wid = t >> 6, lane = t & 63;
  #pragma unroll
  for (int g = 0; g < COLS/4; ++g)
    fft512_fwd_zpad(&tile[((g<<2) + wid)*CST], lane, w256s);
  __syncthreads();
  for (int i = t; i < 512*COLS; i += 256) {
    int cc = i & (COLS-1), q = i >> 3;
    dst[c0 + cc + (q<<9)] = pkh(tile[cc*CST + pidx(q)]);
  }
}

// pass B: row FFT of conjugate-paired rows, Hermitian split, per-event reverb
// multiply, recombine, inverse row FFT. Block = 4 row-pair slots.
// Twiddles via per-thread recurrence (16 consecutive n1 per thread per row).
__global__ __launch_bounds__(256) void k_passB2(__half2* __restrict__ Xb,
                                                const __half2* __restrict__ spec,
                                                const float2* __restrict__ w512g,
                                                const int* __restrict__ ridx,
                                                const float* __restrict__ m0a,
                                                const float* __restrict__ m1a,
                                                const float* __restrict__ ampa,
                                                int e0) {
  __shared__ float2 w256s[256];
  __shared__ float2 rows[ROWS*RST];
  int t = threadIdx.x;
  if (t < 256) w256s[t] = w512g[t];
  __half2* Xe = Xb + (size_t)blockIdx.y * MFT;
  int bx = blockIdx.x;
  bool last = (bx == 63);

  // row geometry for this thread (8 rows x 32 segments of 16)
  int r8 = t >> 5, seg = t & 31;
  int s8 = r8 >> 1, which8 = r8 & 1;
  int j8 = bx*4 + s8;
  int k2t = (j8 == 255) ? (which8 ? 256 : 0) : (which8 ? 511 - j8 : j8 + 1);
  int qt = rev3(k2t);
  int n1b = seg << 4;
  float2 wst = wtw(k2t);

  // load + forward twiddle (recurrence: 1 base sincos + 15 cmuls per thread)
  {
    float2 w = wtw((n1b * k2t) & (MFT-1));
    const __half2* xrow = Xe + (size_t)qt*512 + n1b;
    float2* drow = rows + r8*RST;
    #pragma unroll
    for (int m = 0; m < 16; ++m) {
      drow[pidx(n1b + m)] = cmul(uph(xrow[m]), w);
      w = cmul(w, wst);
    }
  }
  __syncthreads();
  int wid = t >> 6, lane = t & 63;
  #pragma unroll
  for (int g = 0; g < ROWS/4; ++g)
    fft512_fwd(&rows[((g<<2)+wid)*RST], lane, w256s);
  __syncthreads();

  // per-event reverb responses
  int na = e0 + 2*blockIdx.y, nb = na + 1;
  float inv = 1.f/(float)MFT;
  float sa0 = ampa[na]*m0a[na]*inv, sa1 = ampa[na]*m1a[na]*inv;
  float sb0 = ampa[nb]*m0a[nb]*inv, sb1 = ampa[nb]*m1a[nb]*inv;
  const __half2* spa = spec + (size_t)ridx[na]*MFT;
  const __half2* spb = spec + (size_t)ridx[nb]*MFT;

  auto combine = [&](int rA, int pA, int rB, int pB, int qA) {
    float2 P = rows[rA*RST + pidx(pA)];
    float2 Q = rows[rB*RST + pidx(pB)];
    float2 A = make_float2(0.5f*(P.x + Q.x), 0.5f*(P.y - Q.y));   // spectrum of event a at k
    float2 Bv = make_float2(0.5f*(P.y + Q.y), 0.5f*(Q.x - P.x));  // spectrum of event b at k
    float2 Va = uph(spa[(size_t)qA*512 + pA]);
    float2 Vb = uph(spb[(size_t)qA*512 + pA]);
    float2 Ga = make_float2(sa0*Va.x + sa1, sa0*Va.y);
    float2 Gb = make_float2(sb0*Vb.x + sb1, sb0*Vb.y);
    float2 Ya = cmul(A, Ga);
    float2 Yb = cmul(Bv, Gb);
    rows[rA*RST + pidx(pA)] = make_float2(Ya.x - Yb.y, Ya.y + Yb.x);    // Zout(k)  = Ya + i*Yb
    rows[rB*RST + pidx(pB)] = make_float2(Ya.x + Yb.y, Yb.x - Ya.y);    // Zout(-k) = conj(Ya)+i*conj(Yb)
  };

  int ncomb = last ? 1536 : 2048;
  for (int i = t; i < ncomb; i += 256) {
    int s = i >> 9, p = i & 511;
    int j = bx*4 + s;
    combine(2*s, p, 2*s + 1, p ^ 511, rev3(j + 1));
  }
  if (last) {
    // row 6: k2=0 (q=0), self-paired with pperm = rev3((512-rev3(p))&511)
    for (int p = t; p < 512; p += 256) {
      int pp = rev3((512 - rev3(p)) & 511);
      if (p <= pp) combine(6, p, 6, pp, 0);
    }
    // row 7: k2=256 (q=4), self-paired with pperm = p^511
    if (t < 256) combine(7, t, 7, t ^ 511, 4);
  }
  __syncthreads();

  #pragma unroll
  for (int g = 0; g < ROWS/4; ++g)
    fft512_inv(&rows[((g<<2)+wid)*RST], lane, w256s);
  __syncthreads();

  // store + conjugate twiddle (same recurrence)
  {
    float2 w = wtw((n1b * k2t) & (MFT-1));
    __half2* xrow = Xe + (size_t)qt*512 + n1b;
    const float2* srow = rows + r8*RST;
    #pragma unroll
    for (int m = 0; m < 16; ++m) {
      xrow[m] = pkh(cmulc(srow[pidx(n1b + m)], w));
      w = cmul(w, wst);
    }
  }
}

// pass C: inverse column FFT (truncated — only n2<256 consumed);
// Re -> event 2p (shift a), Im -> event 2p+1 (shift b).
// Wrapped positions (o >= NSMP) write ZERO at o-NSMP — this zero-fills
// exactly [0, shift) so no d_out memset is needed.
__global__ __launch_bounds__(256) void k_passC2(const __half2* __restrict__ Xb,
                                                float* __restrict__ dout,
                                                const float2* __restrict__ w512g,
                                                const int* __restrict__ shiftA,
                                                int e0) {
  __shared__ float2 w256s[256];
  __shared__ float2 tile[COLS*CST];
  int t = threadIdx.x;
  if (t < 256) w256s[t] = w512g[t];
  const __half2* Xe = Xb + (size_t)blockIdx.y * MFT;
  int c0 = blockIdx.x * COLS;
  for (int i = t; i < 512*COLS; i += 256) {
    int cc = i & (COLS-1), q = i >> 3;
    tile[cc*CST + pidx(q)] = uph(Xe[c0 + cc + ((size_t)q<<9)]);
  }
  __syncthreads();
  int wid = t >> 6, lane = t & 63;
  #pragma unroll
  for (int g = 0; g < COLS/4; ++g)
    fft512_inv_trunc(&tile[((g<<2) + wid)*CST], lane, w256s);
  __syncthreads();
  int na = e0 + 2*blockIdx.y, nb = na + 1;
  int sha = shiftA[na], shb = shiftA[nb];
  float* dpa = dout + (size_t)na*NSMP;
  float* dpb = dout + (size_t)nb*NSMP;
  for (int i = t; i < 256*COLS; i += 256) {   // only p < NS needed (n2 < 256)
    int cc = i & (COLS-1), n2 = i >> 3;
    int p = c0 + cc + (n2<<9);
    float2 y = tile[cc*CST + pidx(n2)];
    int oa = p + sha;
    if (oa < NSMP) dpa[oa] = y.x; else dpa[oa - NSMP] = 0.f;
    int ob = p + shb;
    if (ob < NSMP) dpb[ob] = y.y; else dpb[ob - NSMP] = 0.f;
  }
}

} // namespace

extern "C" void kernel_launch(void* const* d_in, const int* in_sizes, int n_in,
                              void* d_out, int out_size, void* d_ws, size_t ws_size,
                              hipStream_t stream) {
  (void)in_sizes; (void)n_in; (void)out_size;
  const float* voice  = (const float*)d_in[0];
  const float* cpc    = (const float*)d_in[1];
  const float* amps   = (const float*)d_in[2];
  const float* room   = (const float*)d_in[3];
  const float* rmix   = (const float*)d_in[4];
  const float* times  = (const float*)d_in[5];
  const float* cp_tab = (const float*)d_in[6];
  const float* verbs  = (const float*)d_in[7];
  const float* w_in   = (const float*)d_in[8];
  const float* w_ih   = (const float*)d_in[9];
  const float* w_hh   = (const float*)d_in[10];
  const float* w_out  = (const float*)d_in[11];
  float* out = (float*)d_out;

  char* base = (char*)d_ws;
  size_t off = 0;
  auto carve = [&](size_t bytes) -> void* {
    void* p = base + off;
    off = (off + bytes + 255) & ~(size_t)255;
    return p;
  };
  __half*  sig   = (__half*) carve((size_t)NEV*NSMP*2);   // 32 MB (fp16 signal)
  float2*  w512g = (float2*) carve((size_t)256*8);        // 2 KB compact twiddles (half table)
  __half2* spec  = (__half2*)carve((size_t)16*MFT*4);     // 16 MB (verb spectra, fp16)
  int*   vidx  = (int*)  carve(NEV*4);
  int*   cpidx = (int*)  carve(NEV*4);
  int*   ridx  = (int*)  carve(NEV*4);
  int*   shf   = (int*)  carve(NEV*4);
  float* m0    = (float*)carve(NEV*4);
  float* m1    = (float*)carve(NEV*4);
  float* amp   = (float*)carve(NEV*4);

  // GEMM-phase temporaries alias the spec region (13.3 MB < 16 MB); verb
  // spectra are computed AFTER k_gemm_mfma, when these are all dead.
  size_t toff = (size_t)((char*)spec - base);
  auto carveT = [&](size_t bytes) -> void* {
    void* p = base + toff;
    toff = (toff + bytes + 255) & ~(size_t)255;
    return p;
  };
  float*          mred  = (float*)         carveT((size_t)8*128*16*4);
  float*          ctrl  = (float*)         carveT((size_t)NEV*2048*4);
  unsigned short* hs_hi = (unsigned short*)carveT((size_t)NEV*128*128*2);
  unsigned short* hs_lo = (unsigned short*)carveT((size_t)NEV*128*128*2);
  unsigned short* wo_hi = (unsigned short*)carveT((size_t)8*1024*128*2);
  unsigned short* wo_lo = (unsigned short*)carveT((size_t)8*1024*128*2);

  __half2* X = (__half2*)(base + off);
  size_t rem = (ws_size > off) ? (ws_size - off) : 0;
  int C = (int)(rem / ((size_t)MFT*4));     // chunk size in PAIRS (fp16 X)
  if (C > NPAIR) C = NPAIR;
  if (C < 1) C = 1;

  k_params<<<NEV, 64, 0, stream>>>(voice, cpc, amps, room, rmix, times,
                                   vidx, cpidx, ridx, shf, m0, m1, amp);
  k_w512<<<1, 256, 0, stream>>>(w512g);
  k_mred<<<dim3(128, 8), 64, 0, stream>>>(w_ih, w_in, mred);
  k_topk<<<NEV, 256, 0, stream>>>(cp_tab, cpidx, ctrl);
  k_rnn<<<NEV, 512, 0, stream>>>(ctrl, mred, w_hh, vidx, hs_hi, hs_lo);
  k_wsplit<<<(8*1024*128)/256, 256, 0, stream>>>(w_out, wo_hi, wo_lo, 8*1024*128);
  k_gemm_mfma<<<dim3(8, NEV), 256, 0, stream>>>(hs_hi, hs_lo, wo_hi, wo_lo, vidx, sig);

  // verb spectra: unpacked forward pipeline (must run after k_gemm_mfma —
  // temporaries above alias this region)
  k_passA<<<dim3(64, 16), 256, 0, stream>>>(verbs, spec, w512g);
  k_passBv<<<dim3(64, 16), 256, 0, stream>>>(spec, w512g);

  // main conv: 2 real events packed per complex FFT pipeline
  // (no d_out memset needed — passC2's wrap-zero writes cover [0, shift))
  for (int p0 = 0; p0 < NPAIR; p0 += C) {
    int cp = (NPAIR - p0 < C) ? (NPAIR - p0) : C;
    k_passA2<<<dim3(64, cp), 256, 0, stream>>>(sig + (size_t)p0*2*NSMP, X, w512g);
    k_passB2<<<dim3(64, cp), 256, 0, stream>>>(X, spec, w512g, ridx, m0, m1, amp, 2*p0);
    k_passC2<<<dim3(64, cp), 256, 0, stream>>>(X, out, w512g, shf, 2*p0);
  }
}